// Round 1
// baseline (3865.596 us; speedup 1.0000x reference)
//
#include <hip/hip_runtime.h>
#include <hip/hip_bf16.h>

#define DIM 128
#define BN_EPS 1e-5f

// ---------------- edge scatter: agg[dst] += x[src] ----------------
__global__ __launch_bounds__(256) void scatter_kernel(
    const float* __restrict__ X, const int* __restrict__ src,
    const int* __restrict__ dst, float* __restrict__ agg, int E)
{
    int idx = blockIdx.x * 256 + threadIdx.x;
    if (idx >= E * 32) return;
    int e  = idx >> 5;
    int c4 = idx & 31;
    int s = src[e];
    int d = dst[e];
    float4 v = ((const float4*)(X + (size_t)s * DIM))[c4];
    float* p = agg + (size_t)d * DIM + c4 * 4;
    atomicAdd(p + 0, v.x);
    atomicAdd(p + 1, v.y);
    atomicAdd(p + 2, v.z);
    atomicAdd(p + 3, v.w);
}

// ---------------- GEMM: C = relu((A [+A2]) @ W + b), K=N=128 ----------------
// block: 256 threads, 64-row tile. thread: cols c0=(t&31)*4, rows r0=(t>>5)*8
template <bool ADD>
__global__ __launch_bounds__(256) void gemm_relu_kernel(
    const float* __restrict__ A, const float* __restrict__ A2,
    const float* __restrict__ W, const float* __restrict__ bias,
    float* __restrict__ C, int M)
{
    __shared__ float As[64][DIM];
    int t  = threadIdx.x;
    int m0 = blockIdx.x * 64;

    // stage 64x128 A tile (coalesced), zero-fill tail rows
    int k4    = t & 31;
    int rbase = t >> 5;
#pragma unroll
    for (int p = 0; p < 8; ++p) {
        int r  = rbase + p * 8;
        int gm = m0 + r;
        float4 v = make_float4(0.f, 0.f, 0.f, 0.f);
        if (gm < M) {
            v = ((const float4*)(A + (size_t)gm * DIM))[k4];
            if (ADD) {
                float4 u = ((const float4*)(A2 + (size_t)gm * DIM))[k4];
                v.x += u.x; v.y += u.y; v.z += u.z; v.w += u.w;
            }
        }
        *((float4*)&As[r][k4 * 4]) = v;
    }
    __syncthreads();

    int c0 = (t & 31) * 4;
    int r0 = (t >> 5) * 8;
    float4 bv = ((const float4*)bias)[t & 31];
    float acc[8][4];
#pragma unroll
    for (int i = 0; i < 8; ++i) {
        acc[i][0] = bv.x; acc[i][1] = bv.y; acc[i][2] = bv.z; acc[i][3] = bv.w;
    }

    for (int k = 0; k < DIM; k += 4) {
        float4 w0 = *(const float4*)&W[(k + 0) * DIM + c0];
        float4 w1 = *(const float4*)&W[(k + 1) * DIM + c0];
        float4 w2 = *(const float4*)&W[(k + 2) * DIM + c0];
        float4 w3 = *(const float4*)&W[(k + 3) * DIM + c0];
#pragma unroll
        for (int i = 0; i < 8; ++i) {
            float4 a = *(const float4*)&As[r0 + i][k];
            acc[i][0] += a.x * w0.x + a.y * w1.x + a.z * w2.x + a.w * w3.x;
            acc[i][1] += a.x * w0.y + a.y * w1.y + a.z * w2.y + a.w * w3.y;
            acc[i][2] += a.x * w0.z + a.y * w1.z + a.z * w2.z + a.w * w3.z;
            acc[i][3] += a.x * w0.w + a.y * w1.w + a.z * w2.w + a.w * w3.w;
        }
    }

#pragma unroll
    for (int i = 0; i < 8; ++i) {
        int gm = m0 + r0 + i;
        if (gm < M) {
            float4 o;
            o.x = fmaxf(acc[i][0], 0.f);
            o.y = fmaxf(acc[i][1], 0.f);
            o.z = fmaxf(acc[i][2], 0.f);
            o.w = fmaxf(acc[i][3], 0.f);
            ((float4*)(C + (size_t)gm * DIM))[c0 >> 2] = o;
        }
    }
}

// ---------------- column stats: sums[c], sqsums[c] over M rows ----------------
__global__ __launch_bounds__(256) void colstats_kernel(
    const float* __restrict__ R, int M,
    float* __restrict__ sums, float* __restrict__ sqsums)
{
    const int RPB = 128;
    int t    = threadIdx.x;
    int col  = t & 127;
    int rh   = t >> 7; // 0 or 1
    int base = blockIdx.x * RPB;
    int end  = base + RPB;
    if (end > M) end = M;
    float s = 0.f, ss = 0.f;
    for (int r = base + rh; r < end; r += 2) {
        float v = R[(size_t)r * DIM + col];
        s += v;
        ss += v * v;
    }
    __shared__ float ls[256], lss[256];
    ls[t] = s; lss[t] = ss;
    __syncthreads();
    if (t < 128) {
        s  = ls[t] + ls[t + 128];
        ss = lss[t] + lss[t + 128];
        atomicAdd(&sums[col], s);
        atomicAdd(&sqsums[col], ss);
    }
}

// ---------------- BN apply: O = gamma*(R-m)*rsqrt(v+eps)+beta ----------------
__global__ __launch_bounds__(256) void bn_apply_kernel(
    const float* __restrict__ R, float* __restrict__ O,
    const float* __restrict__ sums, const float* __restrict__ sqsums,
    const float* __restrict__ gamma, const float* __restrict__ beta, int M)
{
    int idx = blockIdx.x * 256 + threadIdx.x; // over M*32 float4s
    if (idx >= M * 32) return;
    int c4 = idx & 31;
    float invM = 1.0f / (float)M;
    float4 v = ((const float4*)R)[idx];
    float o[4] = {v.x, v.y, v.z, v.w};
#pragma unroll
    for (int j = 0; j < 4; ++j) {
        int c = c4 * 4 + j;
        float m   = sums[c] * invM;
        float var = sqsums[c] * invM - m * m;
        float sc  = gamma[c] * rsqrtf(var + BN_EPS);
        o[j] = sc * (o[j] - m) + beta[c];
    }
    float4 ov = make_float4(o[0], o[1], o[2], o[3]);
    ((float4*)O)[idx] = ov;
}

// ---------------- w = sigmoid(x @ sw_w + sw_b), 32 lanes/node ----------------
__global__ __launch_bounds__(256) void weigh_kernel(
    const float* __restrict__ X, const float* __restrict__ sw_w,
    const float* __restrict__ sw_b, float* __restrict__ w, int N)
{
    int gid  = blockIdx.x * 256 + threadIdx.x;
    int node = gid >> 5;
    int l    = gid & 31;
    if (node >= N) return;
    float4 v  = ((const float4*)(X + (size_t)node * DIM))[l];
    float4 sw = ((const float4*)sw_w)[l];
    float d = v.x * sw.x + v.y * sw.y + v.z * sw.z + v.w * sw.w;
#pragma unroll
    for (int off = 16; off > 0; off >>= 1)
        d += __shfl_down(d, off, 32);
    if (l == 0)
        w[node] = 1.0f / (1.0f + expf(-(d + sw_b[0])));
}

// ---- noisy = (1-w)*x ; slots[batch[n]] += w*x (atomic) ----
__global__ __launch_bounds__(256) void split_kernel(
    const float* __restrict__ X, const float* __restrict__ w,
    const int* __restrict__ batch, float* __restrict__ noisy,
    float* __restrict__ slots, int N)
{
    int idx = blockIdx.x * 256 + threadIdx.x; // over N*32 float4s
    if (idx >= N * 32) return;
    int node = idx >> 5;
    int c4   = idx & 31;
    float wn = w[node];
    int   g  = batch[node];
    float4 v = ((const float4*)X)[idx];
    float4 nv = make_float4((1.f - wn) * v.x, (1.f - wn) * v.y,
                            (1.f - wn) * v.z, (1.f - wn) * v.w);
    ((float4*)noisy)[idx] = nv;
    float* sp = slots + (size_t)g * DIM + c4 * 4;
    atomicAdd(sp + 0, wn * v.x);
    atomicAdd(sp + 1, wn * v.y);
    atomicAdd(sp + 2, wn * v.z);
    atomicAdd(sp + 3, wn * v.w);
}

extern "C" void kernel_launch(void* const* d_in, const int* in_sizes, int n_in,
                              void* d_out, int out_size, void* d_ws, size_t ws_size,
                              hipStream_t stream)
{
    const float* x      = (const float*)d_in[0];
    const int*   src    = (const int*)d_in[1];
    const int*   dst    = (const int*)d_in[2];
    const int*   batch  = (const int*)d_in[3];
    const float* cw1    = (const float*)d_in[5];
    const float* cb1    = (const float*)d_in[6];
    const float* cw2    = (const float*)d_in[7];
    const float* cb2    = (const float*)d_in[8];
    const float* bng    = (const float*)d_in[9];
    const float* bnb    = (const float*)d_in[10];
    const float* sw_w   = (const float*)d_in[11];
    const float* sw_b   = (const float*)d_in[12];
    const float* nmu_w  = (const float*)d_in[13];
    const float* nmu_b  = (const float*)d_in[14];
    const float* nlv_w  = (const float*)d_in[15];
    const float* nlv_b  = (const float*)d_in[16];
    const float* gmu_w  = (const float*)d_in[17];
    const float* gmu_b  = (const float*)d_in[18];
    const float* glv_w  = (const float*)d_in[19];
    const float* glv_b  = (const float*)d_in[20];
    const float* hgam   = (const float*)d_in[21];
    const float* hbet   = (const float*)d_in[22];

    const int N = in_sizes[0] / DIM;
    const int E = in_sizes[1];
    const int G = (out_size / DIM - 2 * N) / 2;

    float* out0 = (float*)d_out;                       // node_mu   [N,128]
    float* out1 = out0 + (size_t)N * DIM;              // node_lv   [N,128]
    float* out2 = out1 + (size_t)N * DIM;              // graph_mu  [G,128]
    float* out3 = out2 + (size_t)G * DIM;              // graph_lv  [G,128]

    // workspace layout
    float* xb    = (float*)d_ws;                       // [N,128]
    float* agg   = xb + (size_t)N * DIM;               // [N,128]  (also reused as r)
    float* h1    = agg + (size_t)N * DIM;              // [N,128]  (also noisy)
    float* wbuf  = h1 + (size_t)N * DIM;               // [N]
    float* slots = wbuf + N;                           // [G,128]
    float* stats = slots + (size_t)G * DIM;            // [256]: sums | sqsums
    float* sums   = stats;
    float* sqsums = stats + DIM;

    const int gemm_blocks_N = (N + 63) / 64;
    const int gemm_blocks_G = (G + 63) / 64;
    const int stat_blocks_N = (N + 127) / 128;
    const int stat_blocks_G = (G + 127) / 128;
    const int elem_blocks_N = (N * 32 + 255) / 256;
    const int scat_blocks   = (E * 32 + 255) / 256;

    const float* xin = x;
    for (int l = 0; l < 3; ++l) {
        const float* W1 = cw1 + (size_t)l * DIM * DIM;
        const float* B1 = cb1 + (size_t)l * DIM;
        const float* W2 = cw2 + (size_t)l * DIM * DIM;
        const float* B2 = cb2 + (size_t)l * DIM;
        const float* G1 = bng + (size_t)l * DIM;
        const float* Be = bnb + (size_t)l * DIM;

        hipMemsetAsync(agg, 0, (size_t)N * DIM * sizeof(float), stream);
        scatter_kernel<<<scat_blocks, 256, 0, stream>>>(xin, src, dst, agg, E);
        // h1 = relu((x+agg)@W1 + b1)
        gemm_relu_kernel<true><<<gemm_blocks_N, 256, 0, stream>>>(xin, agg, W1, B1, h1, N);
        // r = relu(h1@W2 + b2) -> reuse agg buffer
        gemm_relu_kernel<false><<<gemm_blocks_N, 256, 0, stream>>>(h1, nullptr, W2, B2, agg, N);
        hipMemsetAsync(stats, 0, 2 * DIM * sizeof(float), stream);
        colstats_kernel<<<stat_blocks_N, 256, 0, stream>>>(agg, N, sums, sqsums);
        bn_apply_kernel<<<elem_blocks_N, 256, 0, stream>>>(agg, xb, sums, sqsums, G1, Be, N);
        xin = xb;
    }

    // summary weighter
    weigh_kernel<<<elem_blocks_N, 256, 0, stream>>>(xb, sw_w, sw_b, wbuf, N);
    hipMemsetAsync(slots, 0, (size_t)G * DIM * sizeof(float), stream);
    // noisy -> h1, slots += w*x
    split_kernel<<<elem_blocks_N, 256, 0, stream>>>(xb, wbuf, batch, h1, slots, N);

    // node_mu head
    gemm_relu_kernel<false><<<gemm_blocks_N, 256, 0, stream>>>(h1, nullptr, nmu_w, nmu_b, out0, N);
    hipMemsetAsync(stats, 0, 2 * DIM * sizeof(float), stream);
    colstats_kernel<<<stat_blocks_N, 256, 0, stream>>>(out0, N, sums, sqsums);
    bn_apply_kernel<<<elem_blocks_N, 256, 0, stream>>>(out0, out0, sums, sqsums,
                                                       hgam + 0 * DIM, hbet + 0 * DIM, N);
    // node_logvar head
    gemm_relu_kernel<false><<<gemm_blocks_N, 256, 0, stream>>>(h1, nullptr, nlv_w, nlv_b, out1, N);
    hipMemsetAsync(stats, 0, 2 * DIM * sizeof(float), stream);
    colstats_kernel<<<stat_blocks_N, 256, 0, stream>>>(out1, N, sums, sqsums);
    bn_apply_kernel<<<elem_blocks_N, 256, 0, stream>>>(out1, out1, sums, sqsums,
                                                       hgam + 1 * DIM, hbet + 1 * DIM, N);
    // graph_mu head
    gemm_relu_kernel<false><<<gemm_blocks_G, 256, 0, stream>>>(slots, nullptr, gmu_w, gmu_b, out2, G);
    hipMemsetAsync(stats, 0, 2 * DIM * sizeof(float), stream);
    colstats_kernel<<<stat_blocks_G, 256, 0, stream>>>(out2, G, sums, sqsums);
    bn_apply_kernel<<<(G * 32 + 255) / 256, 256, 0, stream>>>(out2, out2, sums, sqsums,
                                                              hgam + 2 * DIM, hbet + 2 * DIM, G);
    // graph_logvar head
    gemm_relu_kernel<false><<<gemm_blocks_G, 256, 0, stream>>>(slots, nullptr, glv_w, glv_b, out3, G);
    hipMemsetAsync(stats, 0, 2 * DIM * sizeof(float), stream);
    colstats_kernel<<<stat_blocks_G, 256, 0, stream>>>(out3, G, sums, sqsums);
    bn_apply_kernel<<<(G * 32 + 255) / 256, 256, 0, stream>>>(out3, out3, sums, sqsums,
                                                              hgam + 3 * DIM, hbet + 3 * DIM, G);
}

// Round 2
// 918.358 us; speedup vs baseline: 4.2092x; 4.2092x over previous
//
#include <hip/hip_runtime.h>
#include <hip/hip_bf16.h>

#define DIM 128
#define BN_EPS 1e-5f

// ---------------- CSR build ----------------
__global__ __launch_bounds__(256) void hist_kernel(
    const int* __restrict__ dst, int* __restrict__ deg, int E)
{
    int e = blockIdx.x * 256 + threadIdx.x;
    if (e < E) atomicAdd(&deg[dst[e]], 1);
}

// blockwise inclusive scan (256 elems/block)
__global__ __launch_bounds__(256) void scan1_kernel(
    const int* __restrict__ deg, int* __restrict__ iscan,
    int* __restrict__ bsum, int N)
{
    __shared__ int s[256];
    int t = threadIdx.x;
    int i = blockIdx.x * 256 + t;
    int v = (i < N) ? deg[i] : 0;
    s[t] = v;
    __syncthreads();
#pragma unroll
    for (int off = 1; off < 256; off <<= 1) {
        int u = (t >= off) ? s[t - off] : 0;
        __syncthreads();
        s[t] += u;
        __syncthreads();
    }
    if (i < N) iscan[i] = s[t];
    if (t == 255) bsum[blockIdx.x] = s[255];
}

// single-block scan of block sums -> exclusive offsets (nb <= 256)
__global__ __launch_bounds__(256) void scan2_kernel(int* __restrict__ bsum, int nb)
{
    __shared__ int s[256];
    int t = threadIdx.x;
    int v = (t < nb) ? bsum[t] : 0;
    s[t] = v;
    __syncthreads();
#pragma unroll
    for (int off = 1; off < 256; off <<= 1) {
        int u = (t >= off) ? s[t - off] : 0;
        __syncthreads();
        s[t] += u;
        __syncthreads();
    }
    if (t < nb) bsum[t] = s[t] - v; // exclusive
}

__global__ __launch_bounds__(256) void scan3_kernel(
    const int* __restrict__ iscan, const int* __restrict__ bsum,
    const int* __restrict__ deg, int* __restrict__ row_ptr,
    int* __restrict__ cur, int N)
{
    int i = blockIdx.x * 256 + threadIdx.x;
    if (i < N) {
        int inc = iscan[i] + bsum[i >> 8];
        row_ptr[i + 1] = inc;
        cur[i] = inc - deg[i];
    }
    if (i == 0) row_ptr[0] = 0;
}

__global__ __launch_bounds__(256) void fill_kernel(
    const int* __restrict__ src, const int* __restrict__ dst,
    int* __restrict__ cur, int* __restrict__ eidx, int E)
{
    int e = blockIdx.x * 256 + threadIdx.x;
    if (e < E) {
        int pos = atomicAdd(&cur[dst[e]], 1);
        eidx[pos] = src[e];
    }
}

// ---------------- gather: agg[n] = x[n] + sum_{e: dst=n} x[src_e] ----------------
__global__ __launch_bounds__(256) void gather_kernel(
    const float* __restrict__ X, const int* __restrict__ row_ptr,
    const int* __restrict__ eidx, float* __restrict__ agg, int N)
{
    int gid  = blockIdx.x * 256 + threadIdx.x;
    int node = gid >> 5;
    int c4   = gid & 31;
    if (node >= N) return;
    int b  = row_ptr[node];
    int en = row_ptr[node + 1];
    float4 acc = ((const float4*)(X + (size_t)node * DIM))[c4];
    for (int e = b; e < en; ++e) {
        int s = eidx[e];
        float4 v = ((const float4*)(X + (size_t)s * DIM))[c4];
        acc.x += v.x; acc.y += v.y; acc.z += v.z; acc.w += v.w;
    }
    ((float4*)(agg + (size_t)node * DIM))[c4] = acc;
}

// ---------------- GEMM: C = relu(A @ W + b), K=N=128 ----------------
__global__ __launch_bounds__(256) void gemm_relu_kernel(
    const float* __restrict__ A, const float* __restrict__ W,
    const float* __restrict__ bias, float* __restrict__ C, int M)
{
    __shared__ float As[64][DIM];
    int t  = threadIdx.x;
    int m0 = blockIdx.x * 64;

    int k4    = t & 31;
    int rbase = t >> 5;
#pragma unroll
    for (int p = 0; p < 8; ++p) {
        int r  = rbase + p * 8;
        int gm = m0 + r;
        float4 v = make_float4(0.f, 0.f, 0.f, 0.f);
        if (gm < M) v = ((const float4*)(A + (size_t)gm * DIM))[k4];
        *((float4*)&As[r][k4 * 4]) = v;
    }
    __syncthreads();

    int c0 = (t & 31) * 4;
    int r0 = (t >> 5) * 8;
    float4 bv = ((const float4*)bias)[t & 31];
    float acc[8][4];
#pragma unroll
    for (int i = 0; i < 8; ++i) {
        acc[i][0] = bv.x; acc[i][1] = bv.y; acc[i][2] = bv.z; acc[i][3] = bv.w;
    }

    for (int k = 0; k < DIM; k += 4) {
        float4 w0 = *(const float4*)&W[(k + 0) * DIM + c0];
        float4 w1 = *(const float4*)&W[(k + 1) * DIM + c0];
        float4 w2 = *(const float4*)&W[(k + 2) * DIM + c0];
        float4 w3 = *(const float4*)&W[(k + 3) * DIM + c0];
#pragma unroll
        for (int i = 0; i < 8; ++i) {
            float4 a = *(const float4*)&As[r0 + i][k];
            acc[i][0] += a.x * w0.x + a.y * w1.x + a.z * w2.x + a.w * w3.x;
            acc[i][1] += a.x * w0.y + a.y * w1.y + a.z * w2.y + a.w * w3.y;
            acc[i][2] += a.x * w0.z + a.y * w1.z + a.z * w2.z + a.w * w3.z;
            acc[i][3] += a.x * w0.w + a.y * w1.w + a.z * w2.w + a.w * w3.w;
        }
    }

#pragma unroll
    for (int i = 0; i < 8; ++i) {
        int gm = m0 + r0 + i;
        if (gm < M) {
            float4 o;
            o.x = fmaxf(acc[i][0], 0.f);
            o.y = fmaxf(acc[i][1], 0.f);
            o.z = fmaxf(acc[i][2], 0.f);
            o.w = fmaxf(acc[i][3], 0.f);
            ((float4*)(C + (size_t)gm * DIM))[c0 >> 2] = o;
        }
    }
}

// ---------------- column stats ----------------
__global__ __launch_bounds__(256) void colstats_kernel(
    const float* __restrict__ R, int M,
    float* __restrict__ sums, float* __restrict__ sqsums)
{
    const int RPB = 128;
    int t    = threadIdx.x;
    int col  = t & 127;
    int rh   = t >> 7;
    int base = blockIdx.x * RPB;
    int end  = base + RPB;
    if (end > M) end = M;
    float s = 0.f, ss = 0.f;
    for (int r = base + rh; r < end; r += 2) {
        float v = R[(size_t)r * DIM + col];
        s += v;
        ss += v * v;
    }
    __shared__ float ls[256], lss[256];
    ls[t] = s; lss[t] = ss;
    __syncthreads();
    if (t < 128) {
        s  = ls[t] + ls[t + 128];
        ss = lss[t] + lss[t + 128];
        atomicAdd(&sums[col], s);
        atomicAdd(&sqsums[col], ss);
    }
}

// ---------------- BN apply ----------------
__global__ __launch_bounds__(256) void bn_apply_kernel(
    const float* __restrict__ R, float* __restrict__ O,
    const float* __restrict__ sums, const float* __restrict__ sqsums,
    const float* __restrict__ gamma, const float* __restrict__ beta, int M)
{
    int idx = blockIdx.x * 256 + threadIdx.x;
    if (idx >= M * 32) return;
    int c4 = idx & 31;
    float invM = 1.0f / (float)M;
    float4 v = ((const float4*)R)[idx];
    float o[4] = {v.x, v.y, v.z, v.w};
#pragma unroll
    for (int j = 0; j < 4; ++j) {
        int c = c4 * 4 + j;
        float m   = sums[c] * invM;
        float var = sqsums[c] * invM - m * m;
        float sc  = gamma[c] * rsqrtf(var + BN_EPS);
        o[j] = sc * (o[j] - m) + beta[c];
    }
    ((float4*)O)[idx] = make_float4(o[0], o[1], o[2], o[3]);
}

// ---------------- w = sigmoid(x @ sw_w + sw_b) ----------------
__global__ __launch_bounds__(256) void weigh_kernel(
    const float* __restrict__ X, const float* __restrict__ sw_w,
    const float* __restrict__ sw_b, float* __restrict__ w, int N)
{
    int gid  = blockIdx.x * 256 + threadIdx.x;
    int node = gid >> 5;
    int l    = gid & 31;
    if (node >= N) return;
    float4 v  = ((const float4*)(X + (size_t)node * DIM))[l];
    float4 sw = ((const float4*)sw_w)[l];
    float d = v.x * sw.x + v.y * sw.y + v.z * sw.z + v.w * sw.w;
#pragma unroll
    for (int off = 16; off > 0; off >>= 1)
        d += __shfl_down(d, off, 32);
    if (l == 0)
        w[node] = 1.0f / (1.0f + expf(-(d + sw_b[0])));
}

// ---- noisy = (1-w)*x ; slots[g] += w*x, segmented over sorted batch ----
__global__ __launch_bounds__(256) void split_seg_kernel(
    const float* __restrict__ X, const float* __restrict__ w,
    const int* __restrict__ batch, float* __restrict__ noisy,
    float* __restrict__ slots, int N)
{
    int t    = threadIdx.x;
    int c    = t & 127;
    int half = t >> 7;
    int r0   = blockIdx.x * 128;
    int rend = r0 + 128;
    if (rend > N) rend = N;
    int curg = -1;
    float acc = 0.f;
    for (int r = r0 + half; r < rend; r += 2) {
        float xv = X[(size_t)r * DIM + c];
        float wv = w[r];
        noisy[(size_t)r * DIM + c] = (1.f - wv) * xv;
        int g = batch[r];
        if (g != curg) {
            if (curg >= 0) atomicAdd(&slots[(size_t)curg * DIM + c], acc);
            curg = g;
            acc = 0.f;
        }
        acc += wv * xv;
    }
    if (curg >= 0) atomicAdd(&slots[(size_t)curg * DIM + c], acc);
}

extern "C" void kernel_launch(void* const* d_in, const int* in_sizes, int n_in,
                              void* d_out, int out_size, void* d_ws, size_t ws_size,
                              hipStream_t stream)
{
    const float* x      = (const float*)d_in[0];
    const int*   src    = (const int*)d_in[1];
    const int*   dst    = (const int*)d_in[2];
    const int*   batch  = (const int*)d_in[3];
    const float* cw1    = (const float*)d_in[5];
    const float* cb1    = (const float*)d_in[6];
    const float* cw2    = (const float*)d_in[7];
    const float* cb2    = (const float*)d_in[8];
    const float* bng    = (const float*)d_in[9];
    const float* bnb    = (const float*)d_in[10];
    const float* sw_w   = (const float*)d_in[11];
    const float* sw_b   = (const float*)d_in[12];
    const float* nmu_w  = (const float*)d_in[13];
    const float* nmu_b  = (const float*)d_in[14];
    const float* nlv_w  = (const float*)d_in[15];
    const float* nlv_b  = (const float*)d_in[16];
    const float* gmu_w  = (const float*)d_in[17];
    const float* gmu_b  = (const float*)d_in[18];
    const float* glv_w  = (const float*)d_in[19];
    const float* glv_b  = (const float*)d_in[20];
    const float* hgam   = (const float*)d_in[21];
    const float* hbet   = (const float*)d_in[22];

    const int N = in_sizes[0] / DIM;
    const int E = in_sizes[1];
    const int G = (out_size / DIM - 2 * N) / 2;

    float* out0 = (float*)d_out;
    float* out1 = out0 + (size_t)N * DIM;
    float* out2 = out1 + (size_t)N * DIM;
    float* out3 = out2 + (size_t)G * DIM;

    // workspace layout
    float* xb    = (float*)d_ws;                        // [N,128]
    float* agg   = xb + (size_t)N * DIM;                // [N,128] (also r)
    float* h1    = agg + (size_t)N * DIM;               // [N,128] (also noisy)
    float* wbuf  = h1 + (size_t)N * DIM;                // [N]
    float* slots = wbuf + N;                            // [G,128]
    float* stats = slots + (size_t)G * DIM;             // [256]
    float* sums   = stats;
    float* sqsums = stats + DIM;
    int* row_ptr = (int*)(stats + 2 * DIM);             // [N+1]
    int* eidx    = row_ptr + (N + 2);                   // [E]
    // CSR-build temps overlaid in h1 (h1 first written after CSR build)
    int* deg   = (int*)h1;                              // [N]
    int* iscan = deg + N;                               // [N]
    int* bsum  = iscan + N;                             // [256]
    int* cur   = bsum + 256;                            // [N]

    const int gemm_blocks_N = (N + 63) / 64;
    const int gemm_blocks_G = (G + 63) / 64;
    const int stat_blocks_N = (N + 127) / 128;
    const int stat_blocks_G = (G + 127) / 128;
    const int elem_blocks_N = (N * 32 + 255) / 256;
    const int edge_blocks   = (E + 255) / 256;
    const int scan_blocks   = (N + 255) / 256;

    // ---- build CSR (once per call, reused for all 3 layers) ----
    hipMemsetAsync(deg, 0, (size_t)N * sizeof(int), stream);
    hist_kernel<<<edge_blocks, 256, 0, stream>>>(dst, deg, E);
    scan1_kernel<<<scan_blocks, 256, 0, stream>>>(deg, iscan, bsum, N);
    scan2_kernel<<<1, 256, 0, stream>>>(bsum, scan_blocks);
    scan3_kernel<<<scan_blocks, 256, 0, stream>>>(iscan, bsum, deg, row_ptr, cur, N);
    fill_kernel<<<edge_blocks, 256, 0, stream>>>(src, dst, cur, eidx, E);

    const float* xin = x;
    for (int l = 0; l < 3; ++l) {
        const float* W1 = cw1 + (size_t)l * DIM * DIM;
        const float* B1 = cb1 + (size_t)l * DIM;
        const float* W2 = cw2 + (size_t)l * DIM * DIM;
        const float* B2 = cb2 + (size_t)l * DIM;
        const float* G1 = bng + (size_t)l * DIM;
        const float* Be = bnb + (size_t)l * DIM;

        // agg = x + sum_{in-edges} x[src]
        gather_kernel<<<elem_blocks_N, 256, 0, stream>>>(xin, row_ptr, eidx, agg, N);
        // h1 = relu(agg@W1 + b1)
        gemm_relu_kernel<<<gemm_blocks_N, 256, 0, stream>>>(agg, W1, B1, h1, N);
        // r = relu(h1@W2 + b2) -> reuse agg
        gemm_relu_kernel<<<gemm_blocks_N, 256, 0, stream>>>(h1, W2, B2, agg, N);
        hipMemsetAsync(stats, 0, 2 * DIM * sizeof(float), stream);
        colstats_kernel<<<stat_blocks_N, 256, 0, stream>>>(agg, N, sums, sqsums);
        bn_apply_kernel<<<elem_blocks_N, 256, 0, stream>>>(agg, xb, sums, sqsums, G1, Be, N);
        xin = xb;
    }

    weigh_kernel<<<elem_blocks_N, 256, 0, stream>>>(xb, sw_w, sw_b, wbuf, N);
    hipMemsetAsync(slots, 0, (size_t)G * DIM * sizeof(float), stream);
    split_seg_kernel<<<(N + 127) / 128, 256, 0, stream>>>(xb, wbuf, batch, h1, slots, N);

    // node_mu
    gemm_relu_kernel<<<gemm_blocks_N, 256, 0, stream>>>(h1, nmu_w, nmu_b, out0, N);
    hipMemsetAsync(stats, 0, 2 * DIM * sizeof(float), stream);
    colstats_kernel<<<stat_blocks_N, 256, 0, stream>>>(out0, N, sums, sqsums);
    bn_apply_kernel<<<elem_blocks_N, 256, 0, stream>>>(out0, out0, sums, sqsums,
                                                       hgam + 0 * DIM, hbet + 0 * DIM, N);
    // node_logvar
    gemm_relu_kernel<<<gemm_blocks_N, 256, 0, stream>>>(h1, nlv_w, nlv_b, out1, N);
    hipMemsetAsync(stats, 0, 2 * DIM * sizeof(float), stream);
    colstats_kernel<<<stat_blocks_N, 256, 0, stream>>>(out1, N, sums, sqsums);
    bn_apply_kernel<<<elem_blocks_N, 256, 0, stream>>>(out1, out1, sums, sqsums,
                                                       hgam + 1 * DIM, hbet + 1 * DIM, N);
    // graph_mu
    gemm_relu_kernel<<<gemm_blocks_G, 256, 0, stream>>>(slots, gmu_w, gmu_b, out2, G);
    hipMemsetAsync(stats, 0, 2 * DIM * sizeof(float), stream);
    colstats_kernel<<<stat_blocks_G, 256, 0, stream>>>(out2, G, sums, sqsums);
    bn_apply_kernel<<<(G * 32 + 255) / 256, 256, 0, stream>>>(out2, out2, sums, sqsums,
                                                              hgam + 2 * DIM, hbet + 2 * DIM, G);
    // graph_logvar
    gemm_relu_kernel<<<gemm_blocks_G, 256, 0, stream>>>(slots, glv_w, glv_b, out3, G);
    hipMemsetAsync(stats, 0, 2 * DIM * sizeof(float), stream);
    colstats_kernel<<<stat_blocks_G, 256, 0, stream>>>(out3, G, sums, sqsums);
    bn_apply_kernel<<<(G * 32 + 255) / 256, 256, 0, stream>>>(out3, out3, sums, sqsums,
                                                              hgam + 3 * DIM, hbet + 3 * DIM, G);
}

// Round 4
// 909.763 us; speedup vs baseline: 4.2490x; 1.0094x over previous
//
#include <hip/hip_runtime.h>
#include <hip/hip_bf16.h>

#define DIM 128
#define BN_EPS 1e-5f

typedef unsigned short ushortT;
typedef __attribute__((ext_vector_type(8))) short short8;
typedef __attribute__((ext_vector_type(4))) float floatx4;

__device__ __forceinline__ ushortT f2bf(float f) {
    unsigned x = __float_as_uint(f);
    unsigned r = (x + 0x7fff + ((x >> 16) & 1)) >> 16;
    return (ushortT)r;
}

// ---------------- CSR build ----------------
__global__ __launch_bounds__(256) void hist_kernel(
    const int* __restrict__ dst, int* __restrict__ deg, int E)
{
    int e = blockIdx.x * 256 + threadIdx.x;
    if (e < E) atomicAdd(&deg[dst[e]], 1);
}

__global__ __launch_bounds__(256) void scan1_kernel(
    const int* __restrict__ deg, int* __restrict__ iscan,
    int* __restrict__ bsum, int N)
{
    __shared__ int s[256];
    int t = threadIdx.x;
    int i = blockIdx.x * 256 + t;
    int v = (i < N) ? deg[i] : 0;
    s[t] = v;
    __syncthreads();
#pragma unroll
    for (int off = 1; off < 256; off <<= 1) {
        int u = (t >= off) ? s[t - off] : 0;
        __syncthreads();
        s[t] += u;
        __syncthreads();
    }
    if (i < N) iscan[i] = s[t];
    if (t == 255) bsum[blockIdx.x] = s[255];
}

__global__ __launch_bounds__(256) void scan2_kernel(int* __restrict__ bsum, int nb)
{
    __shared__ int s[256];
    int t = threadIdx.x;
    int v = (t < nb) ? bsum[t] : 0;
    s[t] = v;
    __syncthreads();
#pragma unroll
    for (int off = 1; off < 256; off <<= 1) {
        int u = (t >= off) ? s[t - off] : 0;
        __syncthreads();
        s[t] += u;
        __syncthreads();
    }
    if (t < nb) bsum[t] = s[t] - v; // exclusive
}

__global__ __launch_bounds__(256) void scan3_kernel(
    const int* __restrict__ iscan, const int* __restrict__ bsum,
    const int* __restrict__ deg, int* __restrict__ row_ptr,
    int* __restrict__ cur, int N)
{
    int i = blockIdx.x * 256 + threadIdx.x;
    if (i < N) {
        int inc = iscan[i] + bsum[i >> 8];
        row_ptr[i + 1] = inc;
        cur[i] = inc - deg[i];
    }
    if (i == 0) row_ptr[0] = 0;
}

__global__ __launch_bounds__(256) void fill_kernel(
    const int* __restrict__ src, const int* __restrict__ dst,
    int* __restrict__ cur, int* __restrict__ eidx, int E)
{
    int e = blockIdx.x * 256 + threadIdx.x;
    if (e < E) {
        int pos = atomicAdd(&cur[dst[e]], 1);
        eidx[pos] = src[e];
    }
}

// ---- weights -> transposed bf16 hi/lo planes. mats 0-2: cw1, 3-5: cw2, 6: nmu, 7: nlv ----
__global__ __launch_bounds__(256) void convw_kernel(
    const float* __restrict__ cw1, const float* __restrict__ cw2,
    const float* __restrict__ nmu, const float* __restrict__ nlv,
    ushortT* __restrict__ whi, ushortT* __restrict__ wlo)
{
    int tid = blockIdx.x * 256 + threadIdx.x; // 8*16384
    int mat = tid >> 14;
    int i   = tid & 16383;
    int n = i >> 7, k = i & 127;
    const float* Wm = (mat < 3) ? cw1 + (size_t)mat * 16384
                    : (mat < 6) ? cw2 + (size_t)(mat - 3) * 16384
                    : (mat == 6) ? nmu : nlv;
    float w = Wm[k * DIM + n];
    unsigned u = __float_as_uint(w);
    float rem = w - __uint_as_float(u & 0xffff0000u);
    whi[(size_t)mat * 16384 + i] = (ushortT)(u >> 16);
    wlo[(size_t)mat * 16384 + i] = f2bf(rem);
}

// ---- gather + folded BN affine (fp32): agg[n] = sc*(r[n]+Sum r[src]) + cnt*sh ----
__global__ __launch_bounds__(256) void gather_kernel(
    const float* __restrict__ R, const int* __restrict__ row_ptr,
    const int* __restrict__ eidx,
    const float* __restrict__ ssum, const float* __restrict__ ssq,
    const float* __restrict__ gamma, const float* __restrict__ beta,
    float* __restrict__ agg, int N, float invM)
{
    int gid  = blockIdx.x * 256 + threadIdx.x;
    int node = gid >> 5;
    int c4   = gid & 31;
    if (node >= N) return;
    int b = row_ptr[node];
    int e = row_ptr[node + 1];
    float4 acc = ((const float4*)(R + (size_t)node * DIM))[c4];
    for (int i = b; i < e; ++i) {
        int s = eidx[i];
        float4 v = ((const float4*)(R + (size_t)s * DIM))[c4];
        acc.x += v.x; acc.y += v.y; acc.z += v.z; acc.w += v.w;
    }
    if (ssum) {
        float cnt = (float)(e - b + 1);
        int c0 = c4 * 4;
        float4 sm = *(const float4*)(ssum + c0);
        float4 sq = *(const float4*)(ssq + c0);
        float4 gm = *(const float4*)(gamma + c0);
        float4 bt = *(const float4*)(beta + c0);
        float m0 = sm.x * invM, m1 = sm.y * invM, m2 = sm.z * invM, m3 = sm.w * invM;
        float s0 = gm.x * rsqrtf(sq.x * invM - m0 * m0 + BN_EPS);
        float s1 = gm.y * rsqrtf(sq.y * invM - m1 * m1 + BN_EPS);
        float s2 = gm.z * rsqrtf(sq.z * invM - m2 * m2 + BN_EPS);
        float s3 = gm.w * rsqrtf(sq.w * invM - m3 * m3 + BN_EPS);
        acc.x = s0 * acc.x + cnt * (bt.x - s0 * m0);
        acc.y = s1 * acc.y + cnt * (bt.y - s1 * m1);
        acc.z = s2 * acc.z + cnt * (bt.z - s2 * m2);
        acc.w = s3 * acc.w + cnt * (bt.w - s3 * m3);
    }
    ((float4*)(agg + (size_t)node * DIM))[c4] = acc;
}

// ---- MFMA split GEMM: C = relu(A@W + b), A fp32 -> (ahi,alo) bf16, W as hi/lo planes.
//      3-term product: hi*hi + lo*hi + hi*lo (near-fp32). Optional fused column stats. ----
template <int STATS>
__global__ __launch_bounds__(256) void mfma_gemm_split_kernel(
    const float* __restrict__ A, const ushortT* __restrict__ Whi,
    const ushortT* __restrict__ Wlo, const float* __restrict__ bias,
    float* __restrict__ C, float* __restrict__ ssum, float* __restrict__ ssq, int M)
{
    __shared__ float ls[DIM], lsq[DIM];
    int t    = threadIdx.x;
    int wave = t >> 6;
    int lane = t & 63;
    int quad = lane >> 4;
    int l16  = lane & 15;
    int m0   = blockIdx.x * 64 + wave * 16;
    int arow = m0 + l16;

    if (STATS) {
        if (t < DIM) { ls[t] = 0.f; lsq[t] = 0.f; }
        __syncthreads();
    }

    floatx4 acc[8];
#pragma unroll
    for (int i = 0; i < 8; ++i) acc[i] = (floatx4){0.f, 0.f, 0.f, 0.f};

#pragma unroll
    for (int ks = 0; ks < 4; ++ks) {
        int k0 = ks * 32 + quad * 8;
        short8 ahi = {0,0,0,0,0,0,0,0};
        short8 alo = {0,0,0,0,0,0,0,0};
        if (arow < M) {
            float av[8];
            *(float4*)&av[0] = *(const float4*)(A + (size_t)arow * DIM + k0);
            *(float4*)&av[4] = *(const float4*)(A + (size_t)arow * DIM + k0 + 4);
#pragma unroll
            for (int j = 0; j < 8; ++j) {
                unsigned u = __float_as_uint(av[j]);
                ahi[j] = (short)(u >> 16);
                float rem = av[j] - __uint_as_float(u & 0xffff0000u);
                alo[j] = (short)f2bf(rem);
            }
        }
#pragma unroll
        for (int nt = 0; nt < 8; ++nt) {
            const size_t woff = (size_t)(nt * 16 + l16) * DIM + k0;
            short8 bhi = *(const short8*)(Whi + woff);
            short8 blo = *(const short8*)(Wlo + woff);
            acc[nt] = __builtin_amdgcn_mfma_f32_16x16x32_bf16(ahi, bhi, acc[nt], 0, 0, 0);
            acc[nt] = __builtin_amdgcn_mfma_f32_16x16x32_bf16(alo, bhi, acc[nt], 0, 0, 0);
            acc[nt] = __builtin_amdgcn_mfma_f32_16x16x32_bf16(ahi, blo, acc[nt], 0, 0, 0);
        }
    }

#pragma unroll
    for (int nt = 0; nt < 8; ++nt) {
        int col = nt * 16 + l16;
        float bcol = bias[col];
        float s = 0.f, sq = 0.f;
#pragma unroll
        for (int r = 0; r < 4; ++r) {
            int gr = m0 + quad * 4 + r;
            if (gr < M) {
                float v = fmaxf(acc[nt][r] + bcol, 0.f);
                C[(size_t)gr * DIM + col] = v;
                s += v;
                sq += v * v;
            }
        }
        if (STATS) {
            s  += __shfl_xor(s, 16);  s  += __shfl_xor(s, 32);
            sq += __shfl_xor(sq, 16); sq += __shfl_xor(sq, 32);
            if (quad == 0) {
                atomicAdd(&ls[col], s);
                atomicAdd(&lsq[col], sq);
            }
        }
    }
    if (STATS) {
        __syncthreads();
        if (t < DIM) {
            atomicAdd(&ssum[t], ls[t]);
            atomicAdd(&ssq[t], lsq[t]);
        }
    }
}

// ---------------- fp32 GEMM (graph heads, M small) ----------------
__global__ __launch_bounds__(256) void gemm_relu_f32_kernel(
    const float* __restrict__ A, const float* __restrict__ W,
    const float* __restrict__ bias, float* __restrict__ C, int M)
{
    __shared__ float As[64][DIM];
    int t  = threadIdx.x;
    int m0 = blockIdx.x * 64;
    int k4    = t & 31;
    int rbase = t >> 5;
#pragma unroll
    for (int p = 0; p < 8; ++p) {
        int r  = rbase + p * 8;
        int gm = m0 + r;
        float4 v = make_float4(0.f, 0.f, 0.f, 0.f);
        if (gm < M) v = ((const float4*)(A + (size_t)gm * DIM))[k4];
        *((float4*)&As[r][k4 * 4]) = v;
    }
    __syncthreads();
    int c0 = (t & 31) * 4;
    int r0 = (t >> 5) * 8;
    float4 bv = ((const float4*)bias)[t & 31];
    float acc[8][4];
#pragma unroll
    for (int i = 0; i < 8; ++i) {
        acc[i][0] = bv.x; acc[i][1] = bv.y; acc[i][2] = bv.z; acc[i][3] = bv.w;
    }
    for (int k = 0; k < DIM; k += 4) {
        float4 w0 = *(const float4*)&W[(k + 0) * DIM + c0];
        float4 w1 = *(const float4*)&W[(k + 1) * DIM + c0];
        float4 w2 = *(const float4*)&W[(k + 2) * DIM + c0];
        float4 w3 = *(const float4*)&W[(k + 3) * DIM + c0];
#pragma unroll
        for (int i = 0; i < 8; ++i) {
            float4 a = *(const float4*)&As[r0 + i][k];
            acc[i][0] += a.x * w0.x + a.y * w1.x + a.z * w2.x + a.w * w3.x;
            acc[i][1] += a.x * w0.y + a.y * w1.y + a.z * w2.y + a.w * w3.y;
            acc[i][2] += a.x * w0.z + a.y * w1.z + a.z * w2.z + a.w * w3.z;
            acc[i][3] += a.x * w0.w + a.y * w1.w + a.z * w2.w + a.w * w3.w;
        }
    }
#pragma unroll
    for (int i = 0; i < 8; ++i) {
        int gm = m0 + r0 + i;
        if (gm < M) {
            float4 o;
            o.x = fmaxf(acc[i][0], 0.f);
            o.y = fmaxf(acc[i][1], 0.f);
            o.z = fmaxf(acc[i][2], 0.f);
            o.w = fmaxf(acc[i][3], 0.f);
            ((float4*)(C + (size_t)gm * DIM))[c0 >> 2] = o;
        }
    }
}

__global__ __launch_bounds__(256) void colstats_kernel(
    const float* __restrict__ R, int M,
    float* __restrict__ sums, float* __restrict__ sqsums)
{
    const int RPB = 128;
    int t    = threadIdx.x;
    int col  = t & 127;
    int rh   = t >> 7;
    int base = blockIdx.x * RPB;
    int end  = base + RPB;
    if (end > M) end = M;
    float s = 0.f, ss = 0.f;
    for (int r = base + rh; r < end; r += 2) {
        float v = R[(size_t)r * DIM + col];
        s += v;
        ss += v * v;
    }
    __shared__ float lsx[256], lssx[256];
    lsx[t] = s; lssx[t] = ss;
    __syncthreads();
    if (t < 128) {
        s  = lsx[t] + lsx[t + 128];
        ss = lssx[t] + lssx[t + 128];
        atomicAdd(&sums[col], s);
        atomicAdd(&sqsums[col], ss);
    }
}

__global__ __launch_bounds__(256) void bn_apply_kernel(
    const float* __restrict__ R, float* __restrict__ O,
    const float* __restrict__ sums, const float* __restrict__ sqsums,
    const float* __restrict__ gamma, const float* __restrict__ beta, int M)
{
    int idx = blockIdx.x * 256 + threadIdx.x;
    if (idx >= M * 32) return;
    int c4 = idx & 31;
    float invM = 1.0f / (float)M;
    float4 v = ((const float4*)R)[idx];
    float o[4] = {v.x, v.y, v.z, v.w};
#pragma unroll
    for (int j = 0; j < 4; ++j) {
        int c = c4 * 4 + j;
        float m   = sums[c] * invM;
        float var = sqsums[c] * invM - m * m;
        float sc  = gamma[c] * rsqrtf(var + BN_EPS);
        o[j] = sc * (o[j] - m) + beta[c];
    }
    ((float4*)O)[idx] = make_float4(o[0], o[1], o[2], o[3]);
}

// ---- w = sigmoid(bn(r) @ sw_w + sw_b), BN folded in (fp32) ----
__global__ __launch_bounds__(256) void weigh_kernel(
    const float* __restrict__ R,
    const float* __restrict__ ssum, const float* __restrict__ ssq,
    const float* __restrict__ gamma, const float* __restrict__ beta,
    const float* __restrict__ sw_w, const float* __restrict__ sw_b,
    float* __restrict__ wbuf, int N, float invM)
{
    int gid  = blockIdx.x * 256 + threadIdx.x;
    int node = gid >> 5;
    int l    = gid & 31;
    if (node >= N) return;
    int c0 = l * 4;
    float4 rv = ((const float4*)(R + (size_t)node * DIM))[l];
    float4 sm = *(const float4*)(ssum + c0);
    float4 sq = *(const float4*)(ssq + c0);
    float4 gm = *(const float4*)(gamma + c0);
    float4 bt = *(const float4*)(beta + c0);
    float4 sw = *(const float4*)(sw_w + c0);
    float m0 = sm.x * invM, m1 = sm.y * invM, m2 = sm.z * invM, m3 = sm.w * invM;
    float v0 = gm.x * rsqrtf(sq.x * invM - m0 * m0 + BN_EPS) * (rv.x - m0) + bt.x;
    float v1 = gm.y * rsqrtf(sq.y * invM - m1 * m1 + BN_EPS) * (rv.y - m1) + bt.y;
    float v2 = gm.z * rsqrtf(sq.z * invM - m2 * m2 + BN_EPS) * (rv.z - m2) + bt.z;
    float v3 = gm.w * rsqrtf(sq.w * invM - m3 * m3 + BN_EPS) * (rv.w - m3) + bt.w;
    float d = v0 * sw.x + v1 * sw.y + v2 * sw.z + v3 * sw.w;
#pragma unroll
    for (int off = 16; off > 0; off >>= 1)
        d += __shfl_down(d, off, 32);
    if (l == 0)
        wbuf[node] = 1.0f / (1.0f + expf(-(d + sw_b[0])));
}

// ---- noisy = (1-w)*bn(r); slots[g] += w*bn(r), segmented (sorted batch), fp32 ----
__global__ __launch_bounds__(256) void split_seg_kernel(
    const float* __restrict__ R, const float* __restrict__ wbuf,
    const int* __restrict__ batch,
    const float* __restrict__ ssum, const float* __restrict__ ssq,
    const float* __restrict__ gamma, const float* __restrict__ beta,
    float* __restrict__ noisy, float* __restrict__ slots, int N, float invM)
{
    int t    = threadIdx.x;
    int c    = t & 127;
    int half = t >> 7;
    int r0   = blockIdx.x * 128;
    int rend = r0 + 128;
    if (rend > N) rend = N;
    float m   = ssum[c] * invM;
    float var = ssq[c] * invM - m * m;
    float sc  = gamma[c] * rsqrtf(var + BN_EPS);
    float sh  = beta[c] - sc * m;
    int curg = -1;
    float acc = 0.f;
    for (int r = r0 + half; r < rend; r += 2) {
        float xv = sc * R[(size_t)r * DIM + c] + sh;
        float w  = wbuf[r];
        noisy[(size_t)r * DIM + c] = (1.f - w) * xv;
        int g = batch[r];
        if (g != curg) {
            if (curg >= 0) atomicAdd(&slots[(size_t)curg * DIM + c], acc);
            curg = g;
            acc = 0.f;
        }
        acc += w * xv;
    }
    if (curg >= 0) atomicAdd(&slots[(size_t)curg * DIM + c], acc);
}

extern "C" void kernel_launch(void* const* d_in, const int* in_sizes, int n_in,
                              void* d_out, int out_size, void* d_ws, size_t ws_size,
                              hipStream_t stream)
{
    const float* x      = (const float*)d_in[0];
    const int*   src    = (const int*)d_in[1];
    const int*   dst    = (const int*)d_in[2];
    const int*   batch  = (const int*)d_in[3];
    const float* cw1    = (const float*)d_in[5];
    const float* cb1    = (const float*)d_in[6];
    const float* cw2    = (const float*)d_in[7];
    const float* cb2    = (const float*)d_in[8];
    const float* bng    = (const float*)d_in[9];
    const float* bnb    = (const float*)d_in[10];
    const float* sw_w   = (const float*)d_in[11];
    const float* sw_b   = (const float*)d_in[12];
    const float* nmu_w  = (const float*)d_in[13];
    const float* nmu_b  = (const float*)d_in[14];
    const float* nlv_w  = (const float*)d_in[15];
    const float* nlv_b  = (const float*)d_in[16];
    const float* gmu_w  = (const float*)d_in[17];
    const float* gmu_b  = (const float*)d_in[18];
    const float* glv_w  = (const float*)d_in[19];
    const float* glv_b  = (const float*)d_in[20];
    const float* hgam   = (const float*)d_in[21];
    const float* hbet   = (const float*)d_in[22];

    const int N = in_sizes[0] / DIM;
    const int E = in_sizes[1];
    const int G = (out_size / DIM - 2 * N) / 2;

    float* out0 = (float*)d_out;
    float* out1 = out0 + (size_t)N * DIM;
    float* out2 = out1 + (size_t)N * DIM;
    float* out3 = out2 + (size_t)G * DIM;

    // ---- workspace layout ----
    char* wp = (char*)d_ws;
    auto alloc = [&](size_t bytes) {
        char* p = wp;
        wp += (bytes + 255) & ~(size_t)255;
        return p;
    };
    float* agg   = (float*)alloc((size_t)N * DIM * 4);   // gather out; later noisy
    float* h1    = (float*)alloc((size_t)N * DIM * 4);   // CSR temps overlaid pre-use
    float* rf    = (float*)alloc((size_t)N * DIM * 4);   // layer output (pre-BN)
    ushortT* whi = (ushortT*)alloc((size_t)8 * 16384 * 2);
    ushortT* wlo = (ushortT*)alloc((size_t)8 * 16384 * 2);
    float* slots = (float*)alloc((size_t)G * DIM * 4);
    float* stats = (float*)alloc((size_t)7 * 2 * DIM * 4);
    float* wbuf  = (float*)alloc((size_t)N * 4);
    int* row_ptr = (int*)alloc((size_t)(N + 2) * 4);
    int* eidx    = (int*)alloc((size_t)E * 4);
    // CSR temps overlay in h1 (h1 first written after CSR build)
    int* deg   = (int*)h1;
    int* iscan = deg + N;
    int* bsum  = iscan + N;
    int* cur   = bsum + 256;

    auto SS = [&](int i) { return stats + (size_t)i * 2 * DIM; };
    auto SQ = [&](int i) { return stats + (size_t)i * 2 * DIM + DIM; };

    const int edge_blocks = (E + 255) / 256;
    const int scan_blocks = (N + 255) / 256;
    const int gemm_blocks = (N + 63) / 64;
    const int g32_blocks  = (N * 32 + 255) / 256;
    const float invN = 1.0f / (float)N;

    hipMemsetAsync(stats, 0, (size_t)7 * 2 * DIM * 4, stream);
    hipMemsetAsync(slots, 0, (size_t)G * DIM * 4, stream);
    hipMemsetAsync(deg, 0, (size_t)N * 4, stream);

    convw_kernel<<<(8 * 16384) / 256, 256, 0, stream>>>(cw1, cw2, nmu_w, nlv_w, whi, wlo);

    hist_kernel<<<edge_blocks, 256, 0, stream>>>(dst, deg, E);
    scan1_kernel<<<scan_blocks, 256, 0, stream>>>(deg, iscan, bsum, N);
    scan2_kernel<<<1, 256, 0, stream>>>(bsum, scan_blocks);
    scan3_kernel<<<scan_blocks, 256, 0, stream>>>(iscan, bsum, deg, row_ptr, cur, N);
    fill_kernel<<<edge_blocks, 256, 0, stream>>>(src, dst, cur, eidx, E);

    const float* gin = x;
    for (int l = 0; l < 3; ++l) {
        const float* sums_prev = (l == 0) ? nullptr : SS(l - 1);
        const float* sq_prev   = (l == 0) ? nullptr : SQ(l - 1);
        const float* g_prev    = (l == 0) ? nullptr : bng + (size_t)(l - 1) * DIM;
        const float* b_prev    = (l == 0) ? nullptr : bnb + (size_t)(l - 1) * DIM;
        gather_kernel<<<g32_blocks, 256, 0, stream>>>(
            gin, row_ptr, eidx, sums_prev, sq_prev, g_prev, b_prev, agg, N, invN);
        mfma_gemm_split_kernel<0><<<gemm_blocks, 256, 0, stream>>>(
            agg, whi + (size_t)l * 16384, wlo + (size_t)l * 16384,
            cb1 + (size_t)l * DIM, h1, nullptr, nullptr, N);
        mfma_gemm_split_kernel<1><<<gemm_blocks, 256, 0, stream>>>(
            h1, whi + (size_t)(3 + l) * 16384, wlo + (size_t)(3 + l) * 16384,
            cb2 + (size_t)l * DIM, rf, SS(l), SQ(l), N);
        gin = rf;
    }

    // BN(layer2) folded into weigh/split
    weigh_kernel<<<g32_blocks, 256, 0, stream>>>(
        rf, SS(2), SQ(2), bng + 2 * DIM, bnb + 2 * DIM, sw_w, sw_b, wbuf, N, invN);
    split_seg_kernel<<<(N + 127) / 128, 256, 0, stream>>>(
        rf, wbuf, batch, SS(2), SQ(2), bng + 2 * DIM, bnb + 2 * DIM,
        agg /*noisy*/, slots, N, invN);

    // node heads: split MFMA GEMM with fused stats, then BN in place
    mfma_gemm_split_kernel<1><<<gemm_blocks, 256, 0, stream>>>(
        agg, whi + (size_t)6 * 16384, wlo + (size_t)6 * 16384, nmu_b, out0, SS(3), SQ(3), N);
    mfma_gemm_split_kernel<1><<<gemm_blocks, 256, 0, stream>>>(
        agg, whi + (size_t)7 * 16384, wlo + (size_t)7 * 16384, nlv_b, out1, SS(4), SQ(4), N);
    bn_apply_kernel<<<g32_blocks, 256, 0, stream>>>(
        out0, out0, SS(3), SQ(3), hgam + 0 * DIM, hbet + 0 * DIM, N);
    bn_apply_kernel<<<g32_blocks, 256, 0, stream>>>(
        out1, out1, SS(4), SQ(4), hgam + 1 * DIM, hbet + 1 * DIM, N);

    // graph heads (tiny, fp32)
    const int gemm_blocks_G = (G + 63) / 64;
    const int stat_blocks_G = (G + 127) / 128;
    gemm_relu_f32_kernel<<<gemm_blocks_G, 256, 0, stream>>>(slots, gmu_w, gmu_b, out2, G);
    colstats_kernel<<<stat_blocks_G, 256, 0, stream>>>(out2, G, SS(5), SQ(5));
    bn_apply_kernel<<<(G * 32 + 255) / 256, 256, 0, stream>>>(
        out2, out2, SS(5), SQ(5), hgam + 2 * DIM, hbet + 2 * DIM, G);
    gemm_relu_f32_kernel<<<gemm_blocks_G, 256, 0, stream>>>(slots, glv_w, glv_b, out3, G);
    colstats_kernel<<<stat_blocks_G, 256, 0, stream>>>(out3, G, SS(6), SQ(6));
    bn_apply_kernel<<<(G * 32 + 255) / 256, 256, 0, stream>>>(
        out3, out3, SS(6), SQ(6), hgam + 3 * DIM, hbet + 3 * DIM, G);
}

// Round 5
// 737.709 us; speedup vs baseline: 5.2400x; 1.2332x over previous
//
#include <hip/hip_runtime.h>
#include <hip/hip_bf16.h>

#define DIM 128
#define BN_EPS 1e-5f

typedef unsigned short ushortT;
typedef __attribute__((ext_vector_type(8))) short short8;
typedef __attribute__((ext_vector_type(4))) float floatx4;

__device__ __forceinline__ ushortT f2bf(float f) {
    unsigned x = __float_as_uint(f);
    unsigned r = (x + 0x7fff + ((x >> 16) & 1)) >> 16;
    return (ushortT)r;
}

// ---------------- CSR build ----------------
__global__ __launch_bounds__(256) void hist_kernel(
    const int* __restrict__ dst, int* __restrict__ deg, int E)
{
    int e = blockIdx.x * 256 + threadIdx.x;
    if (e < E) atomicAdd(&deg[dst[e]], 1);
}

__global__ __launch_bounds__(256) void scan1_kernel(
    const int* __restrict__ deg, int* __restrict__ iscan,
    int* __restrict__ bsum, int N)
{
    __shared__ int s[256];
    int t = threadIdx.x;
    int i = blockIdx.x * 256 + t;
    int v = (i < N) ? deg[i] : 0;
    s[t] = v;
    __syncthreads();
#pragma unroll
    for (int off = 1; off < 256; off <<= 1) {
        int u = (t >= off) ? s[t - off] : 0;
        __syncthreads();
        s[t] += u;
        __syncthreads();
    }
    if (i < N) iscan[i] = s[t];
    if (t == 255) bsum[blockIdx.x] = s[255];
}

__global__ __launch_bounds__(256) void scan2_kernel(int* __restrict__ bsum, int nb)
{
    __shared__ int s[256];
    int t = threadIdx.x;
    int v = (t < nb) ? bsum[t] : 0;
    s[t] = v;
    __syncthreads();
#pragma unroll
    for (int off = 1; off < 256; off <<= 1) {
        int u = (t >= off) ? s[t - off] : 0;
        __syncthreads();
        s[t] += u;
        __syncthreads();
    }
    if (t < nb) bsum[t] = s[t] - v; // exclusive
}

__global__ __launch_bounds__(256) void scan3_kernel(
    const int* __restrict__ iscan, const int* __restrict__ bsum,
    const int* __restrict__ deg, int* __restrict__ row_ptr,
    int* __restrict__ cur, int N)
{
    int i = blockIdx.x * 256 + threadIdx.x;
    if (i < N) {
        int inc = iscan[i] + bsum[i >> 8];
        row_ptr[i + 1] = inc;
        cur[i] = inc - deg[i];
    }
    if (i == 0) row_ptr[0] = 0;
}

__global__ __launch_bounds__(256) void fill_kernel(
    const int* __restrict__ src, const int* __restrict__ dst,
    int* __restrict__ cur, int* __restrict__ eidx, int E)
{
    int e = blockIdx.x * 256 + threadIdx.x;
    if (e < E) {
        int pos = atomicAdd(&cur[dst[e]], 1);
        eidx[pos] = src[e];
    }
}

// ---- weights -> transposed bf16 hi/lo planes.
//      mats 0-2: cw1, 3-5: cw2, 6: nmu, 7: nlv, 8: gmu, 9: glv ----
__global__ __launch_bounds__(256) void convw_kernel(
    const float* __restrict__ cw1, const float* __restrict__ cw2,
    const float* __restrict__ nmu, const float* __restrict__ nlv,
    const float* __restrict__ gmu, const float* __restrict__ glv,
    ushortT* __restrict__ whi, ushortT* __restrict__ wlo)
{
    int tid = blockIdx.x * 256 + threadIdx.x; // 10*16384
    int mat = tid >> 14;
    int i   = tid & 16383;
    int n = i >> 7, k = i & 127;
    const float* Wm = (mat < 3) ? cw1 + (size_t)mat * 16384
                    : (mat < 6) ? cw2 + (size_t)(mat - 3) * 16384
                    : (mat == 6) ? nmu : (mat == 7) ? nlv
                    : (mat == 8) ? gmu : glv;
    float w = Wm[k * DIM + n];
    unsigned u = __float_as_uint(w);
    float rem = w - __uint_as_float(u & 0xffff0000u);
    whi[(size_t)mat * 16384 + i] = (ushortT)(u >> 16);
    wlo[(size_t)mat * 16384 + i] = f2bf(rem);
}

// ---- gather + folded BN affine (fp32): agg[n] = sc*(r[n]+Sum r[src]) + cnt*sh ----
__global__ __launch_bounds__(256) void gather_kernel(
    const float* __restrict__ R, const int* __restrict__ row_ptr,
    const int* __restrict__ eidx,
    const float* __restrict__ ssum, const float* __restrict__ ssq,
    const float* __restrict__ gamma, const float* __restrict__ beta,
    float* __restrict__ agg, int N, float invM)
{
    int gid  = blockIdx.x * 256 + threadIdx.x;
    int node = gid >> 5;
    int c4   = gid & 31;
    if (node >= N) return;
    int b = row_ptr[node];
    int e = row_ptr[node + 1];
    float4 acc = ((const float4*)(R + (size_t)node * DIM))[c4];
    for (int i = b; i < e; ++i) {
        int s = eidx[i];
        float4 v = ((const float4*)(R + (size_t)s * DIM))[c4];
        acc.x += v.x; acc.y += v.y; acc.z += v.z; acc.w += v.w;
    }
    if (ssum) {
        float cnt = (float)(e - b + 1);
        int c0 = c4 * 4;
        float4 sm = *(const float4*)(ssum + c0);
        float4 sq = *(const float4*)(ssq + c0);
        float4 gm = *(const float4*)(gamma + c0);
        float4 bt = *(const float4*)(beta + c0);
        float m0 = sm.x * invM, m1 = sm.y * invM, m2 = sm.z * invM, m3 = sm.w * invM;
        float s0 = gm.x * rsqrtf(sq.x * invM - m0 * m0 + BN_EPS);
        float s1 = gm.y * rsqrtf(sq.y * invM - m1 * m1 + BN_EPS);
        float s2 = gm.z * rsqrtf(sq.z * invM - m2 * m2 + BN_EPS);
        float s3 = gm.w * rsqrtf(sq.w * invM - m3 * m3 + BN_EPS);
        acc.x = s0 * acc.x + cnt * (bt.x - s0 * m0);
        acc.y = s1 * acc.y + cnt * (bt.y - s1 * m1);
        acc.z = s2 * acc.z + cnt * (bt.z - s2 * m2);
        acc.w = s3 * acc.w + cnt * (bt.w - s3 * m3);
    }
    ((float4*)(agg + (size_t)node * DIM))[c4] = acc;
}

// ---- MFMA split GEMM: C = relu(A@W + b), near-fp32 via bf16 hi/lo (3 terms).
//      Block = 64 rows x 128 cols. Wave = 64 rows x 32 cols (4 M-tiles x 2 N-tiles):
//      B-frag loads amortized over 4 M-tiles, 8 independent accumulator chains. ----
template <int STATS>
__global__ __launch_bounds__(256) void mfma_gemm_split_kernel(
    const float* __restrict__ A, const ushortT* __restrict__ Whi,
    const ushortT* __restrict__ Wlo, const float* __restrict__ bias,
    float* __restrict__ C, float* __restrict__ ssum, float* __restrict__ ssq, int M)
{
    __shared__ float ls[DIM], lsq[DIM];
    int t     = threadIdx.x;
    int wave  = t >> 6;      // 0..3: column group of 32
    int lane  = t & 63;
    int quad  = lane >> 4;
    int l16   = lane & 15;
    int m0    = blockIdx.x * 64;
    int cbase = wave * 32;

    if (STATS) {
        if (t < DIM) { ls[t] = 0.f; lsq[t] = 0.f; }
        __syncthreads();
    }

    floatx4 acc[4][2];
#pragma unroll
    for (int mt = 0; mt < 4; ++mt)
#pragma unroll
        for (int nt = 0; nt < 2; ++nt)
            acc[mt][nt] = (floatx4){0.f, 0.f, 0.f, 0.f};

    for (int ks = 0; ks < 4; ++ks) {
        int k0 = ks * 32 + quad * 8;
        short8 bhi[2], blo[2];
#pragma unroll
        for (int nt = 0; nt < 2; ++nt) {
            const size_t woff = (size_t)(cbase + nt * 16 + l16) * DIM + k0;
            bhi[nt] = *(const short8*)(Whi + woff);
            blo[nt] = *(const short8*)(Wlo + woff);
        }
        short8 ahi[4], alo[4];
#pragma unroll
        for (int mt = 0; mt < 4; ++mt) {
            int row = m0 + mt * 16 + l16;
            ahi[mt] = (short8){0,0,0,0,0,0,0,0};
            alo[mt] = (short8){0,0,0,0,0,0,0,0};
            if (row < M) {
                float av[8];
                *(float4*)&av[0] = *(const float4*)(A + (size_t)row * DIM + k0);
                *(float4*)&av[4] = *(const float4*)(A + (size_t)row * DIM + k0 + 4);
#pragma unroll
                for (int j = 0; j < 8; ++j) {
                    unsigned u = __float_as_uint(av[j]);
                    ahi[mt][j] = (short)(u >> 16);
                    float rem = av[j] - __uint_as_float(u & 0xffff0000u);
                    alo[mt][j] = (short)f2bf(rem);
                }
            }
        }
#pragma unroll
        for (int mt = 0; mt < 4; ++mt)
#pragma unroll
            for (int nt = 0; nt < 2; ++nt) {
                acc[mt][nt] = __builtin_amdgcn_mfma_f32_16x16x32_bf16(ahi[mt], bhi[nt], acc[mt][nt], 0, 0, 0);
                acc[mt][nt] = __builtin_amdgcn_mfma_f32_16x16x32_bf16(alo[mt], bhi[nt], acc[mt][nt], 0, 0, 0);
                acc[mt][nt] = __builtin_amdgcn_mfma_f32_16x16x32_bf16(ahi[mt], blo[nt], acc[mt][nt], 0, 0, 0);
            }
    }

#pragma unroll
    for (int nt = 0; nt < 2; ++nt) {
        int col = cbase + nt * 16 + l16;
        float bcol = bias[col];
        float s = 0.f, sq = 0.f;
#pragma unroll
        for (int mt = 0; mt < 4; ++mt) {
#pragma unroll
            for (int r = 0; r < 4; ++r) {
                int gr = m0 + mt * 16 + quad * 4 + r;
                if (gr < M) {
                    float v = fmaxf(acc[mt][nt][r] + bcol, 0.f);
                    C[(size_t)gr * DIM + col] = v;
                    s += v;
                    sq += v * v;
                }
            }
        }
        if (STATS) {
            s  += __shfl_xor(s, 16);  s  += __shfl_xor(s, 32);
            sq += __shfl_xor(sq, 16); sq += __shfl_xor(sq, 32);
            if (quad == 0) {
                atomicAdd(&ls[col], s);
                atomicAdd(&lsq[col], sq);
            }
        }
    }
    if (STATS) {
        __syncthreads();
        if (t < DIM) {
            atomicAdd(&ssum[t], ls[t]);
            atomicAdd(&ssq[t], lsq[t]);
        }
    }
}

__global__ __launch_bounds__(256) void bn_apply_kernel(
    const float* __restrict__ R, float* __restrict__ O,
    const float* __restrict__ sums, const float* __restrict__ sqsums,
    const float* __restrict__ gamma, const float* __restrict__ beta, int M)
{
    int idx = blockIdx.x * 256 + threadIdx.x;
    if (idx >= M * 32) return;
    int c4 = idx & 31;
    float invM = 1.0f / (float)M;
    float4 v = ((const float4*)R)[idx];
    float o[4] = {v.x, v.y, v.z, v.w};
#pragma unroll
    for (int j = 0; j < 4; ++j) {
        int c = c4 * 4 + j;
        float m   = sums[c] * invM;
        float var = sqsums[c] * invM - m * m;
        float sc  = gamma[c] * rsqrtf(var + BN_EPS);
        o[j] = sc * (o[j] - m) + beta[c];
    }
    ((float4*)O)[idx] = make_float4(o[0], o[1], o[2], o[3]);
}

// ---- w = sigmoid(bn(r) @ sw_w + sw_b), BN folded in (fp32) ----
__global__ __launch_bounds__(256) void weigh_kernel(
    const float* __restrict__ R,
    const float* __restrict__ ssum, const float* __restrict__ ssq,
    const float* __restrict__ gamma, const float* __restrict__ beta,
    const float* __restrict__ sw_w, const float* __restrict__ sw_b,
    float* __restrict__ wbuf, int N, float invM)
{
    int gid  = blockIdx.x * 256 + threadIdx.x;
    int node = gid >> 5;
    int l    = gid & 31;
    if (node >= N) return;
    int c0 = l * 4;
    float4 rv = ((const float4*)(R + (size_t)node * DIM))[l];
    float4 sm = *(const float4*)(ssum + c0);
    float4 sq = *(const float4*)(ssq + c0);
    float4 gm = *(const float4*)(gamma + c0);
    float4 bt = *(const float4*)(beta + c0);
    float4 sw = *(const float4*)(sw_w + c0);
    float m0 = sm.x * invM, m1 = sm.y * invM, m2 = sm.z * invM, m3 = sm.w * invM;
    float v0 = gm.x * rsqrtf(sq.x * invM - m0 * m0 + BN_EPS) * (rv.x - m0) + bt.x;
    float v1 = gm.y * rsqrtf(sq.y * invM - m1 * m1 + BN_EPS) * (rv.y - m1) + bt.y;
    float v2 = gm.z * rsqrtf(sq.z * invM - m2 * m2 + BN_EPS) * (rv.z - m2) + bt.z;
    float v3 = gm.w * rsqrtf(sq.w * invM - m3 * m3 + BN_EPS) * (rv.w - m3) + bt.w;
    float d = v0 * sw.x + v1 * sw.y + v2 * sw.z + v3 * sw.w;
#pragma unroll
    for (int off = 16; off > 0; off >>= 1)
        d += __shfl_down(d, off, 32);
    if (l == 0)
        wbuf[node] = 1.0f / (1.0f + expf(-(d + sw_b[0])));
}

// ---- noisy = (1-w)*bn(r); slots[g] += w*bn(r), segmented (sorted batch), fp32 ----
__global__ __launch_bounds__(256) void split_seg_kernel(
    const float* __restrict__ R, const float* __restrict__ wbuf,
    const int* __restrict__ batch,
    const float* __restrict__ ssum, const float* __restrict__ ssq,
    const float* __restrict__ gamma, const float* __restrict__ beta,
    float* __restrict__ noisy, float* __restrict__ slots, int N, float invM)
{
    int t    = threadIdx.x;
    int c    = t & 127;
    int half = t >> 7;
    int r0   = blockIdx.x * 128;
    int rend = r0 + 128;
    if (rend > N) rend = N;
    float m   = ssum[c] * invM;
    float var = ssq[c] * invM - m * m;
    float sc  = gamma[c] * rsqrtf(var + BN_EPS);
    float sh  = beta[c] - sc * m;
    int curg = -1;
    float acc = 0.f;
    for (int r = r0 + half; r < rend; r += 2) {
        float xv = sc * R[(size_t)r * DIM + c] + sh;
        float w  = wbuf[r];
        noisy[(size_t)r * DIM + c] = (1.f - w) * xv;
        int g = batch[r];
        if (g != curg) {
            if (curg >= 0) atomicAdd(&slots[(size_t)curg * DIM + c], acc);
            curg = g;
            acc = 0.f;
        }
        acc += w * xv;
    }
    if (curg >= 0) atomicAdd(&slots[(size_t)curg * DIM + c], acc);
}

extern "C" void kernel_launch(void* const* d_in, const int* in_sizes, int n_in,
                              void* d_out, int out_size, void* d_ws, size_t ws_size,
                              hipStream_t stream)
{
    const float* x      = (const float*)d_in[0];
    const int*   src    = (const int*)d_in[1];
    const int*   dst    = (const int*)d_in[2];
    const int*   batch  = (const int*)d_in[3];
    const float* cw1    = (const float*)d_in[5];
    const float* cb1    = (const float*)d_in[6];
    const float* cw2    = (const float*)d_in[7];
    const float* cb2    = (const float*)d_in[8];
    const float* bng    = (const float*)d_in[9];
    const float* bnb    = (const float*)d_in[10];
    const float* sw_w   = (const float*)d_in[11];
    const float* sw_b   = (const float*)d_in[12];
    const float* nmu_w  = (const float*)d_in[13];
    const float* nmu_b  = (const float*)d_in[14];
    const float* nlv_w  = (const float*)d_in[15];
    const float* nlv_b  = (const float*)d_in[16];
    const float* gmu_w  = (const float*)d_in[17];
    const float* gmu_b  = (const float*)d_in[18];
    const float* glv_w  = (const float*)d_in[19];
    const float* glv_b  = (const float*)d_in[20];
    const float* hgam   = (const float*)d_in[21];
    const float* hbet   = (const float*)d_in[22];

    const int N = in_sizes[0] / DIM;
    const int E = in_sizes[1];
    const int G = (out_size / DIM - 2 * N) / 2;

    float* out0 = (float*)d_out;
    float* out1 = out0 + (size_t)N * DIM;
    float* out2 = out1 + (size_t)N * DIM;
    float* out3 = out2 + (size_t)G * DIM;

    // ---- workspace layout ----
    char* wp = (char*)d_ws;
    auto alloc = [&](size_t bytes) {
        char* p = wp;
        wp += (bytes + 255) & ~(size_t)255;
        return p;
    };
    float* agg   = (float*)alloc((size_t)N * DIM * 4);   // gather out; later noisy
    float* h1    = (float*)alloc((size_t)N * DIM * 4);   // CSR temps overlaid pre-use
    float* rf    = (float*)alloc((size_t)N * DIM * 4);   // layer output (pre-BN)
    ushortT* whi = (ushortT*)alloc((size_t)10 * 16384 * 2);
    ushortT* wlo = (ushortT*)alloc((size_t)10 * 16384 * 2);
    float* slots = (float*)alloc((size_t)G * DIM * 4);
    float* stats = (float*)alloc((size_t)7 * 2 * DIM * 4);
    float* wbuf  = (float*)alloc((size_t)N * 4);
    int* row_ptr = (int*)alloc((size_t)(N + 2) * 4);
    int* eidx    = (int*)alloc((size_t)E * 4);
    // CSR temps overlay in h1 (h1 first written after CSR build)
    int* deg   = (int*)h1;
    int* iscan = deg + N;
    int* bsum  = iscan + N;
    int* cur   = bsum + 256;

    auto SS = [&](int i) { return stats + (size_t)i * 2 * DIM; };
    auto SQ = [&](int i) { return stats + (size_t)i * 2 * DIM + DIM; };

    const int edge_blocks = (E + 255) / 256;
    const int scan_blocks = (N + 255) / 256;
    const int gemm_blocks = (N + 63) / 64;
    const int g32_blocks  = (N * 32 + 255) / 256;
    const float invN = 1.0f / (float)N;
    const float invG = 1.0f / (float)G;

    hipMemsetAsync(stats, 0, (size_t)7 * 2 * DIM * 4, stream);
    hipMemsetAsync(slots, 0, (size_t)G * DIM * 4, stream);
    hipMemsetAsync(deg, 0, (size_t)N * 4, stream);

    convw_kernel<<<(10 * 16384) / 256, 256, 0, stream>>>(
        cw1, cw2, nmu_w, nlv_w, gmu_w, glv_w, whi, wlo);

    hist_kernel<<<edge_blocks, 256, 0, stream>>>(dst, deg, E);
    scan1_kernel<<<scan_blocks, 256, 0, stream>>>(deg, iscan, bsum, N);
    scan2_kernel<<<1, 256, 0, stream>>>(bsum, scan_blocks);
    scan3_kernel<<<scan_blocks, 256, 0, stream>>>(iscan, bsum, deg, row_ptr, cur, N);
    fill_kernel<<<edge_blocks, 256, 0, stream>>>(src, dst, cur, eidx, E);

    const float* gin = x;
    for (int l = 0; l < 3; ++l) {
        const float* sums_prev = (l == 0) ? nullptr : SS(l - 1);
        const float* sq_prev   = (l == 0) ? nullptr : SQ(l - 1);
        const float* g_prev    = (l == 0) ? nullptr : bng + (size_t)(l - 1) * DIM;
        const float* b_prev    = (l == 0) ? nullptr : bnb + (size_t)(l - 1) * DIM;
        gather_kernel<<<g32_blocks, 256, 0, stream>>>(
            gin, row_ptr, eidx, sums_prev, sq_prev, g_prev, b_prev, agg, N, invN);
        mfma_gemm_split_kernel<0><<<gemm_blocks, 256, 0, stream>>>(
            agg, whi + (size_t)l * 16384, wlo + (size_t)l * 16384,
            cb1 + (size_t)l * DIM, h1, nullptr, nullptr, N);
        mfma_gemm_split_kernel<1><<<gemm_blocks, 256, 0, stream>>>(
            h1, whi + (size_t)(3 + l) * 16384, wlo + (size_t)(3 + l) * 16384,
            cb2 + (size_t)l * DIM, rf, SS(l), SQ(l), N);
        gin = rf;
    }

    // BN(layer2) folded into weigh/split
    weigh_kernel<<<g32_blocks, 256, 0, stream>>>(
        rf, SS(2), SQ(2), bng + 2 * DIM, bnb + 2 * DIM, sw_w, sw_b, wbuf, N, invN);
    split_seg_kernel<<<(N + 127) / 128, 256, 0, stream>>>(
        rf, wbuf, batch, SS(2), SQ(2), bng + 2 * DIM, bnb + 2 * DIM,
        agg /*noisy*/, slots, N, invN);

    // node heads: split MFMA GEMM with fused stats, then BN in place
    mfma_gemm_split_kernel<1><<<gemm_blocks, 256, 0, stream>>>(
        agg, whi + (size_t)6 * 16384, wlo + (size_t)6 * 16384, nmu_b, out0, SS(3), SQ(3), N);
    mfma_gemm_split_kernel<1><<<gemm_blocks, 256, 0, stream>>>(
        agg, whi + (size_t)7 * 16384, wlo + (size_t)7 * 16384, nlv_b, out1, SS(4), SQ(4), N);
    bn_apply_kernel<<<g32_blocks, 256, 0, stream>>>(
        out0, out0, SS(3), SQ(3), hgam + 0 * DIM, hbet + 0 * DIM, N);
    bn_apply_kernel<<<g32_blocks, 256, 0, stream>>>(
        out1, out1, SS(4), SQ(4), hgam + 1 * DIM, hbet + 1 * DIM, N);

    // graph heads: same MFMA kernel with fused stats (M = G)
    const int gemm_blocks_G = (G + 63) / 64;
    mfma_gemm_split_kernel<1><<<gemm_blocks_G, 256, 0, stream>>>(
        slots, whi + (size_t)8 * 16384, wlo + (size_t)8 * 16384, gmu_b, out2, SS(5), SQ(5), G);
    mfma_gemm_split_kernel<1><<<gemm_blocks_G, 256, 0, stream>>>(
        slots, whi + (size_t)9 * 16384, wlo + (size_t)9 * 16384, glv_b, out3, SS(6), SQ(6), G);
    bn_apply_kernel<<<(G * 32 + 255) / 256, 256, 0, stream>>>(
        out2, out2, SS(5), SQ(5), hgam + 2 * DIM, hbet + 2 * DIM, G);
    bn_apply_kernel<<<(G * 32 + 255) / 256, 256, 0, stream>>>(
        out3, out3, SS(6), SQ(6), hgam + 3 * DIM, hbet + 3 * DIM, G);
}

// Round 6
// 683.200 us; speedup vs baseline: 5.6581x; 1.0798x over previous
//
#include <hip/hip_runtime.h>
#include <hip/hip_bf16.h>

#define DIM 128
#define BN_EPS 1e-5f

typedef unsigned short ushortT;
typedef __attribute__((ext_vector_type(8))) short short8;
typedef __attribute__((ext_vector_type(4))) float floatx4;

__device__ __forceinline__ float bflo(unsigned u) { return __uint_as_float(u << 16); }
__device__ __forceinline__ float bfhi(unsigned u) { return __uint_as_float(u & 0xffff0000u); }
__device__ __forceinline__ float bf2f(ushortT h) { return __uint_as_float(((unsigned)h) << 16); }
__device__ __forceinline__ ushortT f2bf(float f) {
    unsigned x = __float_as_uint(f);
    unsigned r = (x + 0x7fff + ((x >> 16) & 1)) >> 16;
    return (ushortT)r;
}

// ---------------- CSR build ----------------
__global__ __launch_bounds__(256) void hist_kernel(
    const int* __restrict__ dst, int* __restrict__ deg, int E)
{
    int e = blockIdx.x * 256 + threadIdx.x;
    if (e < E) atomicAdd(&deg[dst[e]], 1);
}

__global__ __launch_bounds__(256) void scan1_kernel(
    const int* __restrict__ deg, int* __restrict__ iscan,
    int* __restrict__ bsum, int N)
{
    __shared__ int s[256];
    int t = threadIdx.x;
    int i = blockIdx.x * 256 + t;
    int v = (i < N) ? deg[i] : 0;
    s[t] = v;
    __syncthreads();
#pragma unroll
    for (int off = 1; off < 256; off <<= 1) {
        int u = (t >= off) ? s[t - off] : 0;
        __syncthreads();
        s[t] += u;
        __syncthreads();
    }
    if (i < N) iscan[i] = s[t];
    if (t == 255) bsum[blockIdx.x] = s[255];
}

__global__ __launch_bounds__(256) void scan2_kernel(int* __restrict__ bsum, int nb)
{
    __shared__ int s[256];
    int t = threadIdx.x;
    int v = (t < nb) ? bsum[t] : 0;
    s[t] = v;
    __syncthreads();
#pragma unroll
    for (int off = 1; off < 256; off <<= 1) {
        int u = (t >= off) ? s[t - off] : 0;
        __syncthreads();
        s[t] += u;
        __syncthreads();
    }
    if (t < nb) bsum[t] = s[t] - v; // exclusive
}

__global__ __launch_bounds__(256) void scan3_kernel(
    const int* __restrict__ iscan, const int* __restrict__ bsum,
    const int* __restrict__ deg, int* __restrict__ row_ptr,
    int* __restrict__ cur, int N)
{
    int i = blockIdx.x * 256 + threadIdx.x;
    if (i < N) {
        int inc = iscan[i] + bsum[i >> 8];
        row_ptr[i + 1] = inc;
        cur[i] = inc - deg[i];
    }
    if (i == 0) row_ptr[0] = 0;
}

__global__ __launch_bounds__(256) void fill_kernel(
    const int* __restrict__ src, const int* __restrict__ dst,
    int* __restrict__ cur, int* __restrict__ eidx, int E)
{
    int e = blockIdx.x * 256 + threadIdx.x;
    if (e < E) {
        int pos = atomicAdd(&cur[dst[e]], 1);
        eidx[pos] = src[e];
    }
}

// ---- weights -> transposed bf16 hi/lo planes.
//      mats 0-2: cw1, 3-5: cw2, 6: nmu, 7: nlv, 8: gmu, 9: glv ----
__global__ __launch_bounds__(256) void convw_kernel(
    const float* __restrict__ cw1, const float* __restrict__ cw2,
    const float* __restrict__ nmu, const float* __restrict__ nlv,
    const float* __restrict__ gmu, const float* __restrict__ glv,
    ushortT* __restrict__ whi, ushortT* __restrict__ wlo)
{
    int tid = blockIdx.x * 256 + threadIdx.x; // 10*16384
    int mat = tid >> 14;
    int i   = tid & 16383;
    int n = i >> 7, k = i & 127;
    const float* Wm = (mat < 3) ? cw1 + (size_t)mat * 16384
                    : (mat < 6) ? cw2 + (size_t)(mat - 3) * 16384
                    : (mat == 6) ? nmu : (mat == 7) ? nlv
                    : (mat == 8) ? gmu : glv;
    float w = Wm[k * DIM + n];
    ushortT h = f2bf(w);
    whi[(size_t)mat * 16384 + i] = h;
    wlo[(size_t)mat * 16384 + i] = f2bf(w - bf2f(h));
}

// ---- x fp32 -> bf16 plane ----
__global__ __launch_bounds__(256) void convx_kernel(
    const float* __restrict__ x, ushortT* __restrict__ xb, int n8)
{
    int i = blockIdx.x * 256 + threadIdx.x;
    if (i >= n8) return;
    const float4* xp = (const float4*)x;
    float4 a = xp[2 * i], b = xp[2 * i + 1];
    uint4 o;
    o.x = (unsigned)f2bf(a.x) | ((unsigned)f2bf(a.y) << 16);
    o.y = (unsigned)f2bf(a.z) | ((unsigned)f2bf(a.w) << 16);
    o.z = (unsigned)f2bf(b.x) | ((unsigned)f2bf(b.y) << 16);
    o.w = (unsigned)f2bf(b.z) | ((unsigned)f2bf(b.w) << 16);
    ((uint4*)xb)[i] = o;
}

// ---- gather (bf16 in) + folded BN affine; out = hi/lo bf16 planes ----
__global__ __launch_bounds__(256) void gather_kernel(
    const ushortT* __restrict__ Xb, const int* __restrict__ row_ptr,
    const int* __restrict__ eidx,
    const float* __restrict__ ssum, const float* __restrict__ ssq,
    const float* __restrict__ gamma, const float* __restrict__ beta,
    ushortT* __restrict__ aggHi, ushortT* __restrict__ aggLo, int N, float invM)
{
    int gid  = blockIdx.x * 256 + threadIdx.x;
    int node = gid >> 4;
    int lc   = gid & 15;   // 8 cols per lane
    if (node >= N) return;
    int b = row_ptr[node];
    int e = row_ptr[node + 1];
    float acc[8];
    uint4 u = *(const uint4*)(Xb + (size_t)node * DIM + lc * 8);
    acc[0] = bflo(u.x); acc[1] = bfhi(u.x);
    acc[2] = bflo(u.y); acc[3] = bfhi(u.y);
    acc[4] = bflo(u.z); acc[5] = bfhi(u.z);
    acc[6] = bflo(u.w); acc[7] = bfhi(u.w);
    for (int i = b; i < e; ++i) {
        int s = eidx[i];
        uint4 v = *(const uint4*)(Xb + (size_t)s * DIM + lc * 8);
        acc[0] += bflo(v.x); acc[1] += bfhi(v.x);
        acc[2] += bflo(v.y); acc[3] += bfhi(v.y);
        acc[4] += bflo(v.z); acc[5] += bfhi(v.z);
        acc[6] += bflo(v.w); acc[7] += bfhi(v.w);
    }
    if (ssum) {
        float cnt = (float)(e - b + 1);
        int c0 = lc * 8;
#pragma unroll
        for (int j = 0; j < 8; ++j) {
            int c = c0 + j;
            float m   = ssum[c] * invM;
            float var = ssq[c] * invM - m * m;
            float sc  = gamma[c] * rsqrtf(var + BN_EPS);
            acc[j] = sc * acc[j] + cnt * (beta[c] - sc * m);
        }
    }
    ushortT h[8], l[8];
#pragma unroll
    for (int j = 0; j < 8; ++j) {
        h[j] = f2bf(acc[j]);
        l[j] = f2bf(acc[j] - bf2f(h[j]));
    }
    uint4 hi, lo;
    hi.x = h[0] | ((unsigned)h[1] << 16); hi.y = h[2] | ((unsigned)h[3] << 16);
    hi.z = h[4] | ((unsigned)h[5] << 16); hi.w = h[6] | ((unsigned)h[7] << 16);
    lo.x = l[0] | ((unsigned)l[1] << 16); lo.y = l[2] | ((unsigned)l[3] << 16);
    lo.z = l[4] | ((unsigned)l[5] << 16); lo.w = l[6] | ((unsigned)l[7] << 16);
    *(uint4*)(aggHi + (size_t)node * DIM + lc * 8) = hi;
    *(uint4*)(aggLo + (size_t)node * DIM + lc * 8) = lo;
}

// ---- MFMA split GEMM: C = relu(A@W + b), near-fp32 via bf16 hi/lo (3 terms).
//      AMODE 0: A from hi/lo planes. AMODE 1: A fp32, decompose in-kernel.
//      OMODE 0: write hi/lo planes. 1: write bf16 hi only. 2: write fp32.
//      Wave = 64 rows x 32 cols (4 M-tiles x 2 N-tiles). ----
template <int AMODE, int OMODE, int STATS>
__global__ __launch_bounds__(256) void mfma_gemm_kernel(
    const ushortT* __restrict__ AHI, const ushortT* __restrict__ ALO,
    const float* __restrict__ A32,
    const ushortT* __restrict__ Whi, const ushortT* __restrict__ Wlo,
    const float* __restrict__ bias,
    void* __restrict__ O1, void* __restrict__ O2,
    float* __restrict__ ssum, float* __restrict__ ssq, int M)
{
    __shared__ float ls[DIM], lsq[DIM];
    int t     = threadIdx.x;
    int wave  = t >> 6;
    int lane  = t & 63;
    int quad  = lane >> 4;
    int l16   = lane & 15;
    int m0    = blockIdx.x * 64;
    int cbase = wave * 32;

    if (STATS) {
        if (t < DIM) { ls[t] = 0.f; lsq[t] = 0.f; }
        __syncthreads();
    }

    floatx4 acc[4][2];
#pragma unroll
    for (int mt = 0; mt < 4; ++mt)
#pragma unroll
        for (int nt = 0; nt < 2; ++nt)
            acc[mt][nt] = (floatx4){0.f, 0.f, 0.f, 0.f};

    for (int ks = 0; ks < 4; ++ks) {
        int k0 = ks * 32 + quad * 8;
        short8 bhi[2], blo[2];
#pragma unroll
        for (int nt = 0; nt < 2; ++nt) {
            const size_t woff = (size_t)(cbase + nt * 16 + l16) * DIM + k0;
            bhi[nt] = *(const short8*)(Whi + woff);
            blo[nt] = *(const short8*)(Wlo + woff);
        }
        short8 ahi[4], alo[4];
#pragma unroll
        for (int mt = 0; mt < 4; ++mt) {
            int row = m0 + mt * 16 + l16;
            ahi[mt] = (short8){0,0,0,0,0,0,0,0};
            alo[mt] = (short8){0,0,0,0,0,0,0,0};
            if (row < M) {
                if (AMODE == 0) {
                    ahi[mt] = *(const short8*)(AHI + (size_t)row * DIM + k0);
                    alo[mt] = *(const short8*)(ALO + (size_t)row * DIM + k0);
                } else {
                    float av[8];
                    *(float4*)&av[0] = *(const float4*)(A32 + (size_t)row * DIM + k0);
                    *(float4*)&av[4] = *(const float4*)(A32 + (size_t)row * DIM + k0 + 4);
#pragma unroll
                    for (int j = 0; j < 8; ++j) {
                        ushortT hv = f2bf(av[j]);
                        ahi[mt][j] = (short)hv;
                        alo[mt][j] = (short)f2bf(av[j] - bf2f(hv));
                    }
                }
            }
        }
#pragma unroll
        for (int mt = 0; mt < 4; ++mt)
#pragma unroll
            for (int nt = 0; nt < 2; ++nt) {
                acc[mt][nt] = __builtin_amdgcn_mfma_f32_16x16x32_bf16(ahi[mt], bhi[nt], acc[mt][nt], 0, 0, 0);
                acc[mt][nt] = __builtin_amdgcn_mfma_f32_16x16x32_bf16(alo[mt], bhi[nt], acc[mt][nt], 0, 0, 0);
                acc[mt][nt] = __builtin_amdgcn_mfma_f32_16x16x32_bf16(ahi[mt], blo[nt], acc[mt][nt], 0, 0, 0);
            }
    }

#pragma unroll
    for (int nt = 0; nt < 2; ++nt) {
        int col = cbase + nt * 16 + l16;
        float bcol = bias[col];
        float s = 0.f, sq = 0.f;
#pragma unroll
        for (int mt = 0; mt < 4; ++mt) {
#pragma unroll
            for (int r = 0; r < 4; ++r) {
                int gr = m0 + mt * 16 + quad * 4 + r;
                if (gr < M) {
                    float v = fmaxf(acc[mt][nt][r] + bcol, 0.f);
                    size_t off = (size_t)gr * DIM + col;
                    if (OMODE == 2) {
                        ((float*)O1)[off] = v;
                    } else if (OMODE == 1) {
                        ((ushortT*)O1)[off] = f2bf(v);
                    } else {
                        ushortT hv = f2bf(v);
                        ((ushortT*)O1)[off] = hv;
                        ((ushortT*)O2)[off] = f2bf(v - bf2f(hv));
                    }
                    s += v;
                    sq += v * v;
                }
            }
        }
        if (STATS) {
            s  += __shfl_xor(s, 16);  s  += __shfl_xor(s, 32);
            sq += __shfl_xor(sq, 16); sq += __shfl_xor(sq, 32);
            if (quad == 0) {
                atomicAdd(&ls[col], s);
                atomicAdd(&lsq[col], sq);
            }
        }
    }
    if (STATS) {
        __syncthreads();
        if (t < DIM) {
            atomicAdd(&ssum[t], ls[t]);
            atomicAdd(&ssq[t], lsq[t]);
        }
    }
}

__global__ __launch_bounds__(256) void bn_apply_kernel(
    const float* __restrict__ R, float* __restrict__ O,
    const float* __restrict__ sums, const float* __restrict__ sqsums,
    const float* __restrict__ gamma, const float* __restrict__ beta, int M)
{
    int idx = blockIdx.x * 256 + threadIdx.x;
    if (idx >= M * 32) return;
    int c4 = idx & 31;
    float invM = 1.0f / (float)M;
    float4 v = ((const float4*)R)[idx];
    float o[4] = {v.x, v.y, v.z, v.w};
#pragma unroll
    for (int j = 0; j < 4; ++j) {
        int c = c4 * 4 + j;
        float m   = sums[c] * invM;
        float var = sqsums[c] * invM - m * m;
        float sc  = gamma[c] * rsqrtf(var + BN_EPS);
        o[j] = sc * (o[j] - m) + beta[c];
    }
    ((float4*)O)[idx] = make_float4(o[0], o[1], o[2], o[3]);
}

// ---- w = sigmoid(bn(r) @ sw_w + sw_b), BN folded in; r is bf16 ----
__global__ __launch_bounds__(256) void weigh_kernel(
    const ushortT* __restrict__ R,
    const float* __restrict__ ssum, const float* __restrict__ ssq,
    const float* __restrict__ gamma, const float* __restrict__ beta,
    const float* __restrict__ sw_w, const float* __restrict__ sw_b,
    float* __restrict__ wbuf, int N, float invM)
{
    int gid  = blockIdx.x * 256 + threadIdx.x;
    int node = gid >> 5;
    int l    = gid & 31;
    if (node >= N) return;
    int c0 = l * 4;
    uint2 u = *(const uint2*)(R + (size_t)node * DIM + c0);
    float r0 = bflo(u.x), r1 = bfhi(u.x), r2 = bflo(u.y), r3 = bfhi(u.y);
    float4 sm = *(const float4*)(ssum + c0);
    float4 sq = *(const float4*)(ssq + c0);
    float4 gm = *(const float4*)(gamma + c0);
    float4 bt = *(const float4*)(beta + c0);
    float4 sw = *(const float4*)(sw_w + c0);
    float m0 = sm.x * invM, m1 = sm.y * invM, m2 = sm.z * invM, m3 = sm.w * invM;
    float v0 = gm.x * rsqrtf(sq.x * invM - m0 * m0 + BN_EPS) * (r0 - m0) + bt.x;
    float v1 = gm.y * rsqrtf(sq.y * invM - m1 * m1 + BN_EPS) * (r1 - m1) + bt.y;
    float v2 = gm.z * rsqrtf(sq.z * invM - m2 * m2 + BN_EPS) * (r2 - m2) + bt.z;
    float v3 = gm.w * rsqrtf(sq.w * invM - m3 * m3 + BN_EPS) * (r3 - m3) + bt.w;
    float d = v0 * sw.x + v1 * sw.y + v2 * sw.z + v3 * sw.w;
#pragma unroll
    for (int off = 16; off > 0; off >>= 1)
        d += __shfl_down(d, off, 32);
    if (l == 0)
        wbuf[node] = 1.0f / (1.0f + expf(-(d + sw_b[0])));
}

// ---- noisy = (1-w)*bn(r) -> hi/lo planes; slots[g] += w*bn(r), segmented ----
__global__ __launch_bounds__(256) void split_seg_kernel(
    const ushortT* __restrict__ R, const float* __restrict__ wbuf,
    const int* __restrict__ batch,
    const float* __restrict__ ssum, const float* __restrict__ ssq,
    const float* __restrict__ gamma, const float* __restrict__ beta,
    ushortT* __restrict__ noisyHi, ushortT* __restrict__ noisyLo,
    float* __restrict__ slots, int N, float invM)
{
    int t    = threadIdx.x;
    int c    = t & 127;
    int half = t >> 7;
    int r0   = blockIdx.x * 128;
    int rend = r0 + 128;
    if (rend > N) rend = N;
    float m   = ssum[c] * invM;
    float var = ssq[c] * invM - m * m;
    float sc  = gamma[c] * rsqrtf(var + BN_EPS);
    float sh  = beta[c] - sc * m;
    int curg = -1;
    float acc = 0.f;
    for (int r = r0 + half; r < rend; r += 2) {
        float xv = sc * bf2f(R[(size_t)r * DIM + c]) + sh;
        float w  = wbuf[r];
        float nv = (1.f - w) * xv;
        ushortT hv = f2bf(nv);
        noisyHi[(size_t)r * DIM + c] = hv;
        noisyLo[(size_t)r * DIM + c] = f2bf(nv - bf2f(hv));
        int g = batch[r];
        if (g != curg) {
            if (curg >= 0) atomicAdd(&slots[(size_t)curg * DIM + c], acc);
            curg = g;
            acc = 0.f;
        }
        acc += w * xv;
    }
    if (curg >= 0) atomicAdd(&slots[(size_t)curg * DIM + c], acc);
}

extern "C" void kernel_launch(void* const* d_in, const int* in_sizes, int n_in,
                              void* d_out, int out_size, void* d_ws, size_t ws_size,
                              hipStream_t stream)
{
    const float* x      = (const float*)d_in[0];
    const int*   src    = (const int*)d_in[1];
    const int*   dst    = (const int*)d_in[2];
    const int*   batch  = (const int*)d_in[3];
    const float* cw1    = (const float*)d_in[5];
    const float* cb1    = (const float*)d_in[6];
    const float* cw2    = (const float*)d_in[7];
    const float* cb2    = (const float*)d_in[8];
    const float* bng    = (const float*)d_in[9];
    const float* bnb    = (const float*)d_in[10];
    const float* sw_w   = (const float*)d_in[11];
    const float* sw_b   = (const float*)d_in[12];
    const float* nmu_w  = (const float*)d_in[13];
    const float* nmu_b  = (const float*)d_in[14];
    const float* nlv_w  = (const float*)d_in[15];
    const float* nlv_b  = (const float*)d_in[16];
    const float* gmu_w  = (const float*)d_in[17];
    const float* gmu_b  = (const float*)d_in[18];
    const float* glv_w  = (const float*)d_in[19];
    const float* glv_b  = (const float*)d_in[20];
    const float* hgam   = (const float*)d_in[21];
    const float* hbet   = (const float*)d_in[22];

    const int N = in_sizes[0] / DIM;
    const int E = in_sizes[1];
    const int G = (out_size / DIM - 2 * N) / 2;

    float* out0 = (float*)d_out;
    float* out1 = out0 + (size_t)N * DIM;
    float* out2 = out1 + (size_t)N * DIM;
    float* out3 = out2 + (size_t)G * DIM;

    // ---- workspace layout ----
    char* wp = (char*)d_ws;
    auto alloc = [&](size_t bytes) {
        char* p = wp;
        wp += (bytes + 255) & ~(size_t)255;
        return p;
    };
    ushortT* xbf   = (ushortT*)alloc((size_t)N * DIM * 2); // layer-0 gather input
    ushortT* aggHi = (ushortT*)alloc((size_t)N * DIM * 2); // agg planes; later noisy
    ushortT* aggLo = (ushortT*)alloc((size_t)N * DIM * 2);
    ushortT* h1Hi  = (ushortT*)alloc((size_t)N * DIM * 2); // CSR temps overlaid pre-use
    ushortT* h1Lo  = (ushortT*)alloc((size_t)N * DIM * 2);
    ushortT* rfbf  = (ushortT*)alloc((size_t)N * DIM * 2); // layer output (pre-BN, bf16)
    ushortT* whi   = (ushortT*)alloc((size_t)10 * 16384 * 2);
    ushortT* wlo   = (ushortT*)alloc((size_t)10 * 16384 * 2);
    float* slots   = (float*)alloc((size_t)G * DIM * 4);
    float* stats   = (float*)alloc((size_t)7 * 2 * DIM * 4);
    float* wbuf    = (float*)alloc((size_t)N * 4);
    int* row_ptr   = (int*)alloc((size_t)(N + 2) * 4);
    int* eidx      = (int*)alloc((size_t)E * 4);
    // CSR temps overlay in h1Hi (first written at layer-0 GEMM1, after CSR build)
    int* deg   = (int*)h1Hi;
    int* iscan = deg + N;
    int* bsum  = iscan + N;
    int* cur   = bsum + 256;

    auto SS = [&](int i) { return stats + (size_t)i * 2 * DIM; };
    auto SQ = [&](int i) { return stats + (size_t)i * 2 * DIM + DIM; };

    const int edge_blocks = (E + 255) / 256;
    const int scan_blocks = (N + 255) / 256;
    const int gemm_blocks = (N + 63) / 64;
    const int g16_blocks  = (N * 16 + 255) / 256;
    const int g32_blocks  = (N * 32 + 255) / 256;
    const float invN = 1.0f / (float)N;

    hipMemsetAsync(stats, 0, (size_t)7 * 2 * DIM * 4, stream);
    hipMemsetAsync(slots, 0, (size_t)G * DIM * 4, stream);
    hipMemsetAsync(deg, 0, (size_t)N * 4, stream);

    convw_kernel<<<(10 * 16384) / 256, 256, 0, stream>>>(
        cw1, cw2, nmu_w, nlv_w, gmu_w, glv_w, whi, wlo);
    convx_kernel<<<g16_blocks, 256, 0, stream>>>(x, xbf, N * 16);

    hist_kernel<<<edge_blocks, 256, 0, stream>>>(dst, deg, E);
    scan1_kernel<<<scan_blocks, 256, 0, stream>>>(deg, iscan, bsum, N);
    scan2_kernel<<<1, 256, 0, stream>>>(bsum, scan_blocks);
    scan3_kernel<<<scan_blocks, 256, 0, stream>>>(iscan, bsum, deg, row_ptr, cur, N);
    fill_kernel<<<edge_blocks, 256, 0, stream>>>(src, dst, cur, eidx, E);

    const ushortT* gin = xbf;
    for (int l = 0; l < 3; ++l) {
        const float* sums_prev = (l == 0) ? nullptr : SS(l - 1);
        const float* sq_prev   = (l == 0) ? nullptr : SQ(l - 1);
        const float* g_prev    = (l == 0) ? nullptr : bng + (size_t)(l - 1) * DIM;
        const float* b_prev    = (l == 0) ? nullptr : bnb + (size_t)(l - 1) * DIM;
        gather_kernel<<<g16_blocks, 256, 0, stream>>>(
            gin, row_ptr, eidx, sums_prev, sq_prev, g_prev, b_prev,
            aggHi, aggLo, N, invN);
        mfma_gemm_kernel<0, 0, 0><<<gemm_blocks, 256, 0, stream>>>(
            aggHi, aggLo, nullptr,
            whi + (size_t)l * 16384, wlo + (size_t)l * 16384,
            cb1 + (size_t)l * DIM, h1Hi, h1Lo, nullptr, nullptr, N);
        mfma_gemm_kernel<0, 1, 1><<<gemm_blocks, 256, 0, stream>>>(
            h1Hi, h1Lo, nullptr,
            whi + (size_t)(3 + l) * 16384, wlo + (size_t)(3 + l) * 16384,
            cb2 + (size_t)l * DIM, rfbf, nullptr, SS(l), SQ(l), N);
        gin = rfbf;
    }

    // BN(layer2) folded into weigh/split
    weigh_kernel<<<g32_blocks, 256, 0, stream>>>(
        rfbf, SS(2), SQ(2), bng + 2 * DIM, bnb + 2 * DIM, sw_w, sw_b, wbuf, N, invN);
    split_seg_kernel<<<(N + 127) / 128, 256, 0, stream>>>(
        rfbf, wbuf, batch, SS(2), SQ(2), bng + 2 * DIM, bnb + 2 * DIM,
        aggHi /*noisyHi*/, aggLo /*noisyLo*/, slots, N, invN);

    // node heads: planes-in MFMA GEMM with fused stats, fp32 out, then BN in place
    mfma_gemm_kernel<0, 2, 1><<<gemm_blocks, 256, 0, stream>>>(
        aggHi, aggLo, nullptr,
        whi + (size_t)6 * 16384, wlo + (size_t)6 * 16384,
        nmu_b, out0, nullptr, SS(3), SQ(3), N);
    mfma_gemm_kernel<0, 2, 1><<<gemm_blocks, 256, 0, stream>>>(
        aggHi, aggLo, nullptr,
        whi + (size_t)7 * 16384, wlo + (size_t)7 * 16384,
        nlv_b, out1, nullptr, SS(4), SQ(4), N);
    bn_apply_kernel<<<g32_blocks, 256, 0, stream>>>(
        out0, out0, SS(3), SQ(3), hgam + 0 * DIM, hbet + 0 * DIM, N);
    bn_apply_kernel<<<g32_blocks, 256, 0, stream>>>(
        out1, out1, SS(4), SQ(4), hgam + 1 * DIM, hbet + 1 * DIM, N);

    // graph heads: fp32 A, in-kernel decompose (M = G, tiny)
    const int gemm_blocks_G = (G + 63) / 64;
    mfma_gemm_kernel<1, 2, 1><<<gemm_blocks_G, 256, 0, stream>>>(
        nullptr, nullptr, slots,
        whi + (size_t)8 * 16384, wlo + (size_t)8 * 16384,
        gmu_b, out2, nullptr, SS(5), SQ(5), G);
    mfma_gemm_kernel<1, 2, 1><<<gemm_blocks_G, 256, 0, stream>>>(
        nullptr, nullptr, slots,
        whi + (size_t)9 * 16384, wlo + (size_t)9 * 16384,
        glv_b, out3, nullptr, SS(6), SQ(6), G);
    bn_apply_kernel<<<(G * 32 + 255) / 256, 256, 0, stream>>>(
        out2, out2, SS(5), SQ(5), hgam + 2 * DIM, hbet + 2 * DIM, G);
    bn_apply_kernel<<<(G * 32 + 255) / 256, 256, 0, stream>>>(
        out3, out3, SS(6), SQ(6), hgam + 3 * DIM, hbet + 3 * DIM, G);
}

// Round 7
// 629.431 us; speedup vs baseline: 6.1414x; 1.0854x over previous
//
#include <hip/hip_runtime.h>
#include <hip/hip_bf16.h>

#define DIM 128
#define BN_EPS 1e-5f
#define NSTRIPE 32

typedef unsigned short ushortT;
typedef __attribute__((ext_vector_type(8))) short short8;
typedef __attribute__((ext_vector_type(4))) float floatx4;

__device__ __forceinline__ float bflo(unsigned u) { return __uint_as_float(u << 16); }
__device__ __forceinline__ float bfhi(unsigned u) { return __uint_as_float(u & 0xffff0000u); }
__device__ __forceinline__ float bf2f(ushortT h) { return __uint_as_float(((unsigned)h) << 16); }
__device__ __forceinline__ ushortT f2bf(float f) {
    unsigned x = __float_as_uint(f);
    unsigned r = (x + 0x7fff + ((x >> 16) & 1)) >> 16;
    return (ushortT)r;
}

// ---------------- CSR build ----------------
__global__ __launch_bounds__(256) void hist_kernel(
    const int* __restrict__ dst, int* __restrict__ deg, int E)
{
    int e = blockIdx.x * 256 + threadIdx.x;
    if (e < E) atomicAdd(&deg[dst[e]], 1);
}

__global__ __launch_bounds__(256) void scan1_kernel(
    const int* __restrict__ deg, int* __restrict__ iscan,
    int* __restrict__ bsum, int N)
{
    __shared__ int s[256];
    int t = threadIdx.x;
    int i = blockIdx.x * 256 + t;
    int v = (i < N) ? deg[i] : 0;
    s[t] = v;
    __syncthreads();
#pragma unroll
    for (int off = 1; off < 256; off <<= 1) {
        int u = (t >= off) ? s[t - off] : 0;
        __syncthreads();
        s[t] += u;
        __syncthreads();
    }
    if (i < N) iscan[i] = s[t];
    if (t == 255) bsum[blockIdx.x] = s[255];
}

__global__ __launch_bounds__(256) void scan2_kernel(int* __restrict__ bsum, int nb)
{
    __shared__ int s[256];
    int t = threadIdx.x;
    int v = (t < nb) ? bsum[t] : 0;
    s[t] = v;
    __syncthreads();
#pragma unroll
    for (int off = 1; off < 256; off <<= 1) {
        int u = (t >= off) ? s[t - off] : 0;
        __syncthreads();
        s[t] += u;
        __syncthreads();
    }
    if (t < nb) bsum[t] = s[t] - v; // exclusive
}

__global__ __launch_bounds__(256) void scan3_kernel(
    const int* __restrict__ iscan, const int* __restrict__ bsum,
    const int* __restrict__ deg, int* __restrict__ row_ptr,
    int* __restrict__ cur, int N)
{
    int i = blockIdx.x * 256 + threadIdx.x;
    if (i < N) {
        int inc = iscan[i] + bsum[i >> 8];
        row_ptr[i + 1] = inc;
        cur[i] = inc - deg[i];
    }
    if (i == 0) row_ptr[0] = 0;
}

__global__ __launch_bounds__(256) void fill_kernel(
    const int* __restrict__ src, const int* __restrict__ dst,
    int* __restrict__ cur, int* __restrict__ eidx, int E)
{
    int e = blockIdx.x * 256 + threadIdx.x;
    if (e < E) {
        int pos = atomicAdd(&cur[dst[e]], 1);
        eidx[pos] = src[e];
    }
}

// ---- weights -> transposed bf16 hi/lo planes. 0-2: cw1, 3-5: cw2, 6:nmu,7:nlv,8:gmu,9:glv ----
__global__ __launch_bounds__(256) void convw_kernel(
    const float* __restrict__ cw1, const float* __restrict__ cw2,
    const float* __restrict__ nmu, const float* __restrict__ nlv,
    const float* __restrict__ gmu, const float* __restrict__ glv,
    ushortT* __restrict__ whi, ushortT* __restrict__ wlo)
{
    int tid = blockIdx.x * 256 + threadIdx.x; // 10*16384
    int mat = tid >> 14;
    int i   = tid & 16383;
    int n = i >> 7, k = i & 127;
    const float* Wm = (mat < 3) ? cw1 + (size_t)mat * 16384
                    : (mat < 6) ? cw2 + (size_t)(mat - 3) * 16384
                    : (mat == 6) ? nmu : (mat == 7) ? nlv
                    : (mat == 8) ? gmu : glv;
    float w = Wm[k * DIM + n];
    ushortT h = f2bf(w);
    whi[(size_t)mat * 16384 + i] = h;
    wlo[(size_t)mat * 16384 + i] = f2bf(w - bf2f(h));
}

// ---- x fp32 -> bf16 plane ----
__global__ __launch_bounds__(256) void convx_kernel(
    const float* __restrict__ x, ushortT* __restrict__ xb, int n8)
{
    int i = blockIdx.x * 256 + threadIdx.x;
    if (i >= n8) return;
    const float4* xp = (const float4*)x;
    float4 a = xp[2 * i], b = xp[2 * i + 1];
    uint4 o;
    o.x = (unsigned)f2bf(a.x) | ((unsigned)f2bf(a.y) << 16);
    o.y = (unsigned)f2bf(a.z) | ((unsigned)f2bf(a.w) << 16);
    o.z = (unsigned)f2bf(b.x) | ((unsigned)f2bf(b.y) << 16);
    o.w = (unsigned)f2bf(b.z) | ((unsigned)f2bf(b.w) << 16);
    ((uint4*)xb)[i] = o;
}

// ---- merge 32 stat stripes -> final [256] (sum | sq) ----
__global__ __launch_bounds__(256) void merge_stats_kernel(
    const float* __restrict__ sbuf, float* __restrict__ out)
{
    int t = threadIdx.x;
    float s = 0.f;
#pragma unroll
    for (int i = 0; i < NSTRIPE; ++i) s += sbuf[i * 256 + t];
    out[t] = s;
}

// ---- gather (bf16 in) + folded BN affine; out = packed (hi<<16)|lo uint plane ----
__global__ __launch_bounds__(256) void gather_kernel(
    const ushortT* __restrict__ Xb, const int* __restrict__ row_ptr,
    const int* __restrict__ eidx,
    const float* __restrict__ ssum, const float* __restrict__ ssq,
    const float* __restrict__ gamma, const float* __restrict__ beta,
    unsigned* __restrict__ aggP, int N, float invM)
{
    int gid  = blockIdx.x * 256 + threadIdx.x;
    int node = gid >> 4;
    int lc   = gid & 15;   // 8 cols per lane
    if (node >= N) return;
    int b = row_ptr[node];
    int e = row_ptr[node + 1];
    float acc[8];
    uint4 u = *(const uint4*)(Xb + (size_t)node * DIM + lc * 8);
    acc[0] = bflo(u.x); acc[1] = bfhi(u.x);
    acc[2] = bflo(u.y); acc[3] = bfhi(u.y);
    acc[4] = bflo(u.z); acc[5] = bfhi(u.z);
    acc[6] = bflo(u.w); acc[7] = bfhi(u.w);
    for (int i = b; i < e; ++i) {
        int s = eidx[i];
        uint4 v = *(const uint4*)(Xb + (size_t)s * DIM + lc * 8);
        acc[0] += bflo(v.x); acc[1] += bfhi(v.x);
        acc[2] += bflo(v.y); acc[3] += bfhi(v.y);
        acc[4] += bflo(v.z); acc[5] += bfhi(v.z);
        acc[6] += bflo(v.w); acc[7] += bfhi(v.w);
    }
    if (ssum) {
        float cnt = (float)(e - b + 1);
        int c0 = lc * 8;
#pragma unroll
        for (int j = 0; j < 8; ++j) {
            int c = c0 + j;
            float m   = ssum[c] * invM;
            float var = ssq[c] * invM - m * m;
            float sc  = gamma[c] * rsqrtf(var + BN_EPS);
            acc[j] = sc * acc[j] + cnt * (beta[c] - sc * m);
        }
    }
    uint4 p[2];
#pragma unroll
    for (int j = 0; j < 8; ++j) {
        ushortT h = f2bf(acc[j]);
        ushortT l = f2bf(acc[j] - bf2f(h));
        ((unsigned*)p)[j] = ((unsigned)h << 16) | l;
    }
    *(uint4*)(aggP + (size_t)node * DIM + lc * 8)     = p[0];
    *(uint4*)(aggP + (size_t)node * DIM + lc * 8 + 4) = p[1];
}

// ---- MFMA split GEMM: C = relu(A@W + b), near-fp32 via bf16 hi/lo (3 terms).
//      AMODE 0: A packed uint plane. AMODE 1: A fp32, decompose in-kernel.
//      OMODE 0: packed uint out. 1: bf16 hi out. 2: fp32 out.
//      STATS 0: none. 1: striped atomics (stripe = blockIdx&31). 2: direct atomics. ----
template <int AMODE, int OMODE, int STATS>
__global__ __launch_bounds__(256) void mfma_gemm_kernel(
    const unsigned* __restrict__ AP, const float* __restrict__ A32,
    const ushortT* __restrict__ Whi, const ushortT* __restrict__ Wlo,
    const float* __restrict__ bias,
    void* __restrict__ O1,
    float* __restrict__ sdst, float* __restrict__ ssq2, int M)
{
    __shared__ float ls[DIM], lsq[DIM];
    int t     = threadIdx.x;
    int wave  = t >> 6;
    int lane  = t & 63;
    int quad  = lane >> 4;
    int l16   = lane & 15;
    int m0    = blockIdx.x * 64;
    int cbase = wave * 32;

    if (STATS) {
        if (t < DIM) { ls[t] = 0.f; lsq[t] = 0.f; }
        __syncthreads();
    }

    floatx4 acc[4][2];
#pragma unroll
    for (int mt = 0; mt < 4; ++mt)
#pragma unroll
        for (int nt = 0; nt < 2; ++nt)
            acc[mt][nt] = (floatx4){0.f, 0.f, 0.f, 0.f};

    for (int ks = 0; ks < 4; ++ks) {
        int k0 = ks * 32 + quad * 8;
        short8 bhi[2], blo[2];
#pragma unroll
        for (int nt = 0; nt < 2; ++nt) {
            const size_t woff = (size_t)(cbase + nt * 16 + l16) * DIM + k0;
            bhi[nt] = *(const short8*)(Whi + woff);
            blo[nt] = *(const short8*)(Wlo + woff);
        }
        short8 ahi[4], alo[4];
#pragma unroll
        for (int mt = 0; mt < 4; ++mt) {
            int row = m0 + mt * 16 + l16;
            ahi[mt] = (short8){0,0,0,0,0,0,0,0};
            alo[mt] = (short8){0,0,0,0,0,0,0,0};
            if (row < M) {
                if (AMODE == 0) {
                    unsigned ap[8];
                    *(uint4*)&ap[0] = *(const uint4*)(AP + (size_t)row * DIM + k0);
                    *(uint4*)&ap[4] = *(const uint4*)(AP + (size_t)row * DIM + k0 + 4);
#pragma unroll
                    for (int j = 0; j < 8; ++j) {
                        ahi[mt][j] = (short)(ap[j] >> 16);
                        alo[mt][j] = (short)(ap[j] & 0xffffu);
                    }
                } else {
                    float av[8];
                    *(float4*)&av[0] = *(const float4*)(A32 + (size_t)row * DIM + k0);
                    *(float4*)&av[4] = *(const float4*)(A32 + (size_t)row * DIM + k0 + 4);
#pragma unroll
                    for (int j = 0; j < 8; ++j) {
                        ushortT hv = f2bf(av[j]);
                        ahi[mt][j] = (short)hv;
                        alo[mt][j] = (short)f2bf(av[j] - bf2f(hv));
                    }
                }
            }
        }
#pragma unroll
        for (int mt = 0; mt < 4; ++mt)
#pragma unroll
            for (int nt = 0; nt < 2; ++nt) {
                acc[mt][nt] = __builtin_amdgcn_mfma_f32_16x16x32_bf16(ahi[mt], bhi[nt], acc[mt][nt], 0, 0, 0);
                acc[mt][nt] = __builtin_amdgcn_mfma_f32_16x16x32_bf16(alo[mt], bhi[nt], acc[mt][nt], 0, 0, 0);
                acc[mt][nt] = __builtin_amdgcn_mfma_f32_16x16x32_bf16(ahi[mt], blo[nt], acc[mt][nt], 0, 0, 0);
            }
    }

#pragma unroll
    for (int nt = 0; nt < 2; ++nt) {
        int col = cbase + nt * 16 + l16;
        float bcol = bias[col];
        float s = 0.f, sq = 0.f;
#pragma unroll
        for (int mt = 0; mt < 4; ++mt) {
#pragma unroll
            for (int r = 0; r < 4; ++r) {
                int gr = m0 + mt * 16 + quad * 4 + r;
                if (gr < M) {
                    float v = fmaxf(acc[mt][nt][r] + bcol, 0.f);
                    size_t off = (size_t)gr * DIM + col;
                    if (OMODE == 2) {
                        ((float*)O1)[off] = v;
                    } else if (OMODE == 1) {
                        ((ushortT*)O1)[off] = f2bf(v);
                    } else {
                        ushortT hv = f2bf(v);
                        ushortT lv = f2bf(v - bf2f(hv));
                        ((unsigned*)O1)[off] = ((unsigned)hv << 16) | lv;
                    }
                    s += v;
                    sq += v * v;
                }
            }
        }
        if (STATS) {
            s  += __shfl_xor(s, 16);  s  += __shfl_xor(s, 32);
            sq += __shfl_xor(sq, 16); sq += __shfl_xor(sq, 32);
            if (quad == 0) {
                atomicAdd(&ls[col], s);
                atomicAdd(&lsq[col], sq);
            }
        }
    }
    if (STATS == 1) {
        __syncthreads();
        float* dst = sdst + (size_t)(blockIdx.x & (NSTRIPE - 1)) * 256;
        if (t < 128) atomicAdd(&dst[t], ls[t]);
        else         atomicAdd(&dst[t], lsq[t - 128]);
    } else if (STATS == 2) {
        __syncthreads();
        if (t < DIM) {
            atomicAdd(&sdst[t], ls[t]);
            atomicAdd(&ssq2[t], lsq[t]);
        }
    }
}

__global__ __launch_bounds__(256) void bn_apply_kernel(
    const float* __restrict__ R, float* __restrict__ O,
    const float* __restrict__ sums, const float* __restrict__ sqsums,
    const float* __restrict__ gamma, const float* __restrict__ beta, int M)
{
    int idx = blockIdx.x * 256 + threadIdx.x;
    if (idx >= M * 32) return;
    int c4 = idx & 31;
    float invM = 1.0f / (float)M;
    float4 v = ((const float4*)R)[idx];
    float o[4] = {v.x, v.y, v.z, v.w};
#pragma unroll
    for (int j = 0; j < 4; ++j) {
        int c = c4 * 4 + j;
        float m   = sums[c] * invM;
        float var = sqsums[c] * invM - m * m;
        float sc  = gamma[c] * rsqrtf(var + BN_EPS);
        o[j] = sc * (o[j] - m) + beta[c];
    }
    ((float4*)O)[idx] = make_float4(o[0], o[1], o[2], o[3]);
}

// ---- w = sigmoid(bn(r) @ sw_w + sw_b), BN folded in; r is bf16 ----
__global__ __launch_bounds__(256) void weigh_kernel(
    const ushortT* __restrict__ R,
    const float* __restrict__ ssum, const float* __restrict__ ssq,
    const float* __restrict__ gamma, const float* __restrict__ beta,
    const float* __restrict__ sw_w, const float* __restrict__ sw_b,
    float* __restrict__ wbuf, int N, float invM)
{
    int gid  = blockIdx.x * 256 + threadIdx.x;
    int node = gid >> 5;
    int l    = gid & 31;
    if (node >= N) return;
    int c0 = l * 4;
    uint2 u = *(const uint2*)(R + (size_t)node * DIM + c0);
    float r0 = bflo(u.x), r1 = bfhi(u.x), r2 = bflo(u.y), r3 = bfhi(u.y);
    float4 sm = *(const float4*)(ssum + c0);
    float4 sq = *(const float4*)(ssq + c0);
    float4 gm = *(const float4*)(gamma + c0);
    float4 bt = *(const float4*)(beta + c0);
    float4 sw = *(const float4*)(sw_w + c0);
    float m0 = sm.x * invM, m1 = sm.y * invM, m2 = sm.z * invM, m3 = sm.w * invM;
    float v0 = gm.x * rsqrtf(sq.x * invM - m0 * m0 + BN_EPS) * (r0 - m0) + bt.x;
    float v1 = gm.y * rsqrtf(sq.y * invM - m1 * m1 + BN_EPS) * (r1 - m1) + bt.y;
    float v2 = gm.z * rsqrtf(sq.z * invM - m2 * m2 + BN_EPS) * (r2 - m2) + bt.z;
    float v3 = gm.w * rsqrtf(sq.w * invM - m3 * m3 + BN_EPS) * (r3 - m3) + bt.w;
    float d = v0 * sw.x + v1 * sw.y + v2 * sw.z + v3 * sw.w;
#pragma unroll
    for (int off = 16; off > 0; off >>= 1)
        d += __shfl_down(d, off, 32);
    if (l == 0)
        wbuf[node] = 1.0f / (1.0f + expf(-(d + sw_b[0])));
}

// ---- noisy = (1-w)*bn(r) -> packed plane; slots[g] += w*bn(r), segmented ----
__global__ __launch_bounds__(256) void split_seg_kernel(
    const ushortT* __restrict__ R, const float* __restrict__ wbuf,
    const int* __restrict__ batch,
    const float* __restrict__ ssum, const float* __restrict__ ssq,
    const float* __restrict__ gamma, const float* __restrict__ beta,
    unsigned* __restrict__ noisyP, float* __restrict__ slots, int N, float invM)
{
    int t    = threadIdx.x;
    int c    = t & 127;
    int half = t >> 7;
    int r0   = blockIdx.x * 128;
    int rend = r0 + 128;
    if (rend > N) rend = N;
    float m   = ssum[c] * invM;
    float var = ssq[c] * invM - m * m;
    float sc  = gamma[c] * rsqrtf(var + BN_EPS);
    float sh  = beta[c] - sc * m;
    int curg = -1;
    float acc = 0.f;
    for (int r = r0 + half; r < rend; r += 2) {
        float xv = sc * bf2f(R[(size_t)r * DIM + c]) + sh;
        float w  = wbuf[r];
        float nv = (1.f - w) * xv;
        ushortT hv = f2bf(nv);
        ushortT lv = f2bf(nv - bf2f(hv));
        noisyP[(size_t)r * DIM + c] = ((unsigned)hv << 16) | lv;
        int g = batch[r];
        if (g != curg) {
            if (curg >= 0) atomicAdd(&slots[(size_t)curg * DIM + c], acc);
            curg = g;
            acc = 0.f;
        }
        acc += w * xv;
    }
    if (curg >= 0) atomicAdd(&slots[(size_t)curg * DIM + c], acc);
}

extern "C" void kernel_launch(void* const* d_in, const int* in_sizes, int n_in,
                              void* d_out, int out_size, void* d_ws, size_t ws_size,
                              hipStream_t stream)
{
    const float* x      = (const float*)d_in[0];
    const int*   src    = (const int*)d_in[1];
    const int*   dst    = (const int*)d_in[2];
    const int*   batch  = (const int*)d_in[3];
    const float* cw1    = (const float*)d_in[5];
    const float* cb1    = (const float*)d_in[6];
    const float* cw2    = (const float*)d_in[7];
    const float* cb2    = (const float*)d_in[8];
    const float* bng    = (const float*)d_in[9];
    const float* bnb    = (const float*)d_in[10];
    const float* sw_w   = (const float*)d_in[11];
    const float* sw_b   = (const float*)d_in[12];
    const float* nmu_w  = (const float*)d_in[13];
    const float* nmu_b  = (const float*)d_in[14];
    const float* nlv_w  = (const float*)d_in[15];
    const float* nlv_b  = (const float*)d_in[16];
    const float* gmu_w  = (const float*)d_in[17];
    const float* gmu_b  = (const float*)d_in[18];
    const float* glv_w  = (const float*)d_in[19];
    const float* glv_b  = (const float*)d_in[20];
    const float* hgam   = (const float*)d_in[21];
    const float* hbet   = (const float*)d_in[22];

    const int N = in_sizes[0] / DIM;
    const int E = in_sizes[1];
    const int G = (out_size / DIM - 2 * N) / 2;

    float* out0 = (float*)d_out;
    float* out1 = out0 + (size_t)N * DIM;
    float* out2 = out1 + (size_t)N * DIM;
    float* out3 = out2 + (size_t)G * DIM;

    // ---- workspace layout ----
    char* wp = (char*)d_ws;
    auto alloc = [&](size_t bytes) {
        char* p = wp;
        wp += (bytes + 255) & ~(size_t)255;
        return p;
    };
    ushortT*  xbf   = (ushortT*)alloc((size_t)N * DIM * 2);  // layer-0 gather input
    unsigned* aggP  = (unsigned*)alloc((size_t)N * DIM * 4); // packed agg; later noisy
    unsigned* h1P   = (unsigned*)alloc((size_t)N * DIM * 4); // CSR temps overlaid pre-use
    ushortT*  rfbf  = (ushortT*)alloc((size_t)N * DIM * 2);  // layer output (pre-BN, bf16)
    ushortT*  whi   = (ushortT*)alloc((size_t)10 * 16384 * 2);
    ushortT*  wlo   = (ushortT*)alloc((size_t)10 * 16384 * 2);
    float* slots    = (float*)alloc((size_t)G * DIM * 4);
    float* stats    = (float*)alloc((size_t)7 * 256 * 4);     // final [sum(128)|sq(128)] x7
    float* sbuf     = (float*)alloc((size_t)5 * NSTRIPE * 256 * 4); // stripe bufs x5
    float* wbuf     = (float*)alloc((size_t)N * 4);
    int* row_ptr    = (int*)alloc((size_t)(N + 2) * 4);
    int* eidx       = (int*)alloc((size_t)E * 4);
    // CSR temps overlay in h1P (first written at layer-0 GEMM1, after CSR build)
    int* deg   = (int*)h1P;
    int* iscan = deg + N;
    int* bsum  = iscan + N;
    int* cur   = bsum + 256;

    auto SS = [&](int i) { return stats + (size_t)i * 256; };
    auto SQ = [&](int i) { return stats + (size_t)i * 256 + 128; };
    auto SB = [&](int i) { return sbuf + (size_t)i * NSTRIPE * 256; };

    const int edge_blocks = (E + 255) / 256;
    const int scan_blocks = (N + 255) / 256;
    const int gemm_blocks = (N + 63) / 64;
    const int g16_blocks  = (N * 16 + 255) / 256;
    const int g32_blocks  = (N * 32 + 255) / 256;
    const float invN = 1.0f / (float)N;

    hipMemsetAsync(stats, 0, (size_t)7 * 256 * 4, stream);
    hipMemsetAsync(sbuf, 0, (size_t)5 * NSTRIPE * 256 * 4, stream);
    hipMemsetAsync(slots, 0, (size_t)G * DIM * 4, stream);
    hipMemsetAsync(deg, 0, (size_t)N * 4, stream);

    convw_kernel<<<(10 * 16384) / 256, 256, 0, stream>>>(
        cw1, cw2, nmu_w, nlv_w, gmu_w, glv_w, whi, wlo);
    convx_kernel<<<g16_blocks, 256, 0, stream>>>(x, xbf, N * 16);

    hist_kernel<<<edge_blocks, 256, 0, stream>>>(dst, deg, E);
    scan1_kernel<<<scan_blocks, 256, 0, stream>>>(deg, iscan, bsum, N);
    scan2_kernel<<<1, 256, 0, stream>>>(bsum, scan_blocks);
    scan3_kernel<<<scan_blocks, 256, 0, stream>>>(iscan, bsum, deg, row_ptr, cur, N);
    fill_kernel<<<edge_blocks, 256, 0, stream>>>(src, dst, cur, eidx, E);

    const ushortT* gin = xbf;
    for (int l = 0; l < 3; ++l) {
        const float* sums_prev = (l == 0) ? nullptr : SS(l - 1);
        const float* sq_prev   = (l == 0) ? nullptr : SQ(l - 1);
        const float* g_prev    = (l == 0) ? nullptr : bng + (size_t)(l - 1) * DIM;
        const float* b_prev    = (l == 0) ? nullptr : bnb + (size_t)(l - 1) * DIM;
        gather_kernel<<<g16_blocks, 256, 0, stream>>>(
            gin, row_ptr, eidx, sums_prev, sq_prev, g_prev, b_prev,
            aggP, N, invN);
        mfma_gemm_kernel<0, 0, 0><<<gemm_blocks, 256, 0, stream>>>(
            aggP, nullptr,
            whi + (size_t)l * 16384, wlo + (size_t)l * 16384,
            cb1 + (size_t)l * DIM, h1P, nullptr, nullptr, N);
        mfma_gemm_kernel<0, 1, 1><<<gemm_blocks, 256, 0, stream>>>(
            h1P, nullptr,
            whi + (size_t)(3 + l) * 16384, wlo + (size_t)(3 + l) * 16384,
            cb2 + (size_t)l * DIM, rfbf, SB(l), nullptr, N);
        merge_stats_kernel<<<1, 256, 0, stream>>>(SB(l), SS(l));
        gin = rfbf;
    }

    // BN(layer2) folded into weigh/split
    weigh_kernel<<<g32_blocks, 256, 0, stream>>>(
        rfbf, SS(2), SQ(2), bng + 2 * DIM, bnb + 2 * DIM, sw_w, sw_b, wbuf, N, invN);
    split_seg_kernel<<<(N + 127) / 128, 256, 0, stream>>>(
        rfbf, wbuf, batch, SS(2), SQ(2), bng + 2 * DIM, bnb + 2 * DIM,
        aggP /*noisy packed*/, slots, N, invN);

    // node heads: packed-A MFMA GEMM with striped stats, fp32 out, then BN in place
    mfma_gemm_kernel<0, 2, 1><<<gemm_blocks, 256, 0, stream>>>(
        aggP, nullptr,
        whi + (size_t)6 * 16384, wlo + (size_t)6 * 16384,
        nmu_b, out0, SB(3), nullptr, N);
    merge_stats_kernel<<<1, 256, 0, stream>>>(SB(3), SS(3));
    mfma_gemm_kernel<0, 2, 1><<<gemm_blocks, 256, 0, stream>>>(
        aggP, nullptr,
        whi + (size_t)7 * 16384, wlo + (size_t)7 * 16384,
        nlv_b, out1, SB(4), nullptr, N);
    merge_stats_kernel<<<1, 256, 0, stream>>>(SB(4), SS(4));
    bn_apply_kernel<<<g32_blocks, 256, 0, stream>>>(
        out0, out0, SS(3), SQ(3), hgam + 0 * DIM, hbet + 0 * DIM, N);
    bn_apply_kernel<<<g32_blocks, 256, 0, stream>>>(
        out1, out1, SS(4), SQ(4), hgam + 1 * DIM, hbet + 1 * DIM, N);

    // graph heads: fp32 A, in-kernel decompose, direct stats (M = G, tiny)
    const int gemm_blocks_G = (G + 63) / 64;
    mfma_gemm_kernel<1, 2, 2><<<gemm_blocks_G, 256, 0, stream>>>(
        nullptr, slots,
        whi + (size_t)8 * 16384, wlo + (size_t)8 * 16384,
        gmu_b, out2, SS(5), SQ(5), G);
    mfma_gemm_kernel<1, 2, 2><<<gemm_blocks_G, 256, 0, stream>>>(
        nullptr, slots,
        whi + (size_t)9 * 16384, wlo + (size_t)9 * 16384,
        glv_b, out3, SS(6), SQ(6), G);
    bn_apply_kernel<<<(G * 32 + 255) / 256, 256, 0, stream>>>(
        out2, out2, SS(5), SQ(5), hgam + 2 * DIM, hbet + 2 * DIM, G);
    bn_apply_kernel<<<(G * 32 + 255) / 256, 256, 0, stream>>>(
        out3, out3, SS(6), SQ(6), hgam + 3 * DIM, hbet + 3 * DIM, G);
}

// Round 8
// 572.454 us; speedup vs baseline: 6.7527x; 1.0995x over previous
//
#include <hip/hip_runtime.h>
#include <hip/hip_bf16.h>

#define DIM 128
#define BN_EPS 1e-5f
#define NSTRIPE 32

typedef unsigned short ushortT;
typedef __attribute__((ext_vector_type(8))) short short8;
typedef __attribute__((ext_vector_type(4))) float floatx4;

__device__ __forceinline__ float bflo(unsigned u) { return __uint_as_float(u << 16); }
__device__ __forceinline__ float bfhi(unsigned u) { return __uint_as_float(u & 0xffff0000u); }
__device__ __forceinline__ float bf2f(ushortT h) { return __uint_as_float(((unsigned)h) << 16); }
__device__ __forceinline__ ushortT f2bf(float f) {
    unsigned x = __float_as_uint(f);
    unsigned r = (x + 0x7fff + ((x >> 16) & 1)) >> 16;
    return (ushortT)r;
}
__device__ __forceinline__ void decode8(const unsigned* ap, short8& hi, short8& lo) {
#pragma unroll
    for (int j = 0; j < 8; ++j) {
        hi[j] = (short)(ap[j] >> 16);
        lo[j] = (short)(ap[j] & 0xffffu);
    }
}

// ---------------- CSR build ----------------
__global__ __launch_bounds__(256) void hist_kernel(
    const int* __restrict__ dst, int* __restrict__ deg, int E)
{
    int e = blockIdx.x * 256 + threadIdx.x;
    if (e < E) atomicAdd(&deg[dst[e]], 1);
}

__global__ __launch_bounds__(256) void scan1_kernel(
    const int* __restrict__ deg, int* __restrict__ iscan,
    int* __restrict__ bsum, int N)
{
    __shared__ int s[256];
    int t = threadIdx.x;
    int i = blockIdx.x * 256 + t;
    int v = (i < N) ? deg[i] : 0;
    s[t] = v;
    __syncthreads();
#pragma unroll
    for (int off = 1; off < 256; off <<= 1) {
        int u = (t >= off) ? s[t - off] : 0;
        __syncthreads();
        s[t] += u;
        __syncthreads();
    }
    if (i < N) iscan[i] = s[t];
    if (t == 255) bsum[blockIdx.x] = s[255];
}

__global__ __launch_bounds__(256) void scan2_kernel(int* __restrict__ bsum, int nb)
{
    __shared__ int s[256];
    int t = threadIdx.x;
    int v = (t < nb) ? bsum[t] : 0;
    s[t] = v;
    __syncthreads();
#pragma unroll
    for (int off = 1; off < 256; off <<= 1) {
        int u = (t >= off) ? s[t - off] : 0;
        __syncthreads();
        s[t] += u;
        __syncthreads();
    }
    if (t < nb) bsum[t] = s[t] - v; // exclusive
}

__global__ __launch_bounds__(256) void scan3_kernel(
    const int* __restrict__ iscan, const int* __restrict__ bsum,
    const int* __restrict__ deg, int* __restrict__ row_ptr,
    int* __restrict__ cur, int N)
{
    int i = blockIdx.x * 256 + threadIdx.x;
    if (i < N) {
        int inc = iscan[i] + bsum[i >> 8];
        row_ptr[i + 1] = inc;
        cur[i] = inc - deg[i];
    }
    if (i == 0) row_ptr[0] = 0;
}

__global__ __launch_bounds__(256) void fill_kernel(
    const int* __restrict__ src, const int* __restrict__ dst,
    int* __restrict__ cur, int* __restrict__ eidx, int E)
{
    int e = blockIdx.x * 256 + threadIdx.x;
    if (e < E) {
        int pos = atomicAdd(&cur[dst[e]], 1);
        eidx[pos] = src[e];
    }
}

// ---- weights -> transposed bf16 hi/lo planes. 0-2: cw1, 3-5: cw2, 6:nmu,7:nlv,8:gmu,9:glv ----
__global__ __launch_bounds__(256) void convw_kernel(
    const float* __restrict__ cw1, const float* __restrict__ cw2,
    const float* __restrict__ nmu, const float* __restrict__ nlv,
    const float* __restrict__ gmu, const float* __restrict__ glv,
    ushortT* __restrict__ whi, ushortT* __restrict__ wlo)
{
    int tid = blockIdx.x * 256 + threadIdx.x; // 10*16384
    int mat = tid >> 14;
    int i   = tid & 16383;
    int n = i >> 7, k = i & 127;
    const float* Wm = (mat < 3) ? cw1 + (size_t)mat * 16384
                    : (mat < 6) ? cw2 + (size_t)(mat - 3) * 16384
                    : (mat == 6) ? nmu : (mat == 7) ? nlv
                    : (mat == 8) ? gmu : glv;
    float w = Wm[k * DIM + n];
    ushortT h = f2bf(w);
    whi[(size_t)mat * 16384 + i] = h;
    wlo[(size_t)mat * 16384 + i] = f2bf(w - bf2f(h));
}

// ---- x fp32 -> bf16 plane ----
__global__ __launch_bounds__(256) void convx_kernel(
    const float* __restrict__ x, ushortT* __restrict__ xb, int n8)
{
    int i = blockIdx.x * 256 + threadIdx.x;
    if (i >= n8) return;
    const float4* xp = (const float4*)x;
    float4 a = xp[2 * i], b = xp[2 * i + 1];
    uint4 o;
    o.x = (unsigned)f2bf(a.x) | ((unsigned)f2bf(a.y) << 16);
    o.y = (unsigned)f2bf(a.z) | ((unsigned)f2bf(a.w) << 16);
    o.z = (unsigned)f2bf(b.x) | ((unsigned)f2bf(b.y) << 16);
    o.w = (unsigned)f2bf(b.z) | ((unsigned)f2bf(b.w) << 16);
    ((uint4*)xb)[i] = o;
}

// ---- merge 32 stat stripes -> final [256] (sum | sq) ----
__global__ __launch_bounds__(256) void merge_stats_kernel(
    const float* __restrict__ sbuf, float* __restrict__ out)
{
    int t = threadIdx.x;
    float s = 0.f;
#pragma unroll
    for (int i = 0; i < NSTRIPE; ++i) s += sbuf[i * 256 + t];
    out[t] = s;
}

// ---- gather (bf16 in) + folded BN affine; out = packed (hi<<16)|lo uint plane ----
__global__ __launch_bounds__(256) void gather_kernel(
    const ushortT* __restrict__ Xb, const int* __restrict__ row_ptr,
    const int* __restrict__ eidx,
    const float* __restrict__ ssum, const float* __restrict__ ssq,
    const float* __restrict__ gamma, const float* __restrict__ beta,
    unsigned* __restrict__ aggP, int N, float invM)
{
    int gid  = blockIdx.x * 256 + threadIdx.x;
    int node = gid >> 4;
    int lc   = gid & 15;   // 8 cols per lane
    if (node >= N) return;
    int b = row_ptr[node];
    int e = row_ptr[node + 1];
    float acc[8];
    uint4 u = *(const uint4*)(Xb + (size_t)node * DIM + lc * 8);
    acc[0] = bflo(u.x); acc[1] = bfhi(u.x);
    acc[2] = bflo(u.y); acc[3] = bfhi(u.y);
    acc[4] = bflo(u.z); acc[5] = bfhi(u.z);
    acc[6] = bflo(u.w); acc[7] = bfhi(u.w);
    for (int i = b; i < e; ++i) {
        int s = eidx[i];
        uint4 v = *(const uint4*)(Xb + (size_t)s * DIM + lc * 8);
        acc[0] += bflo(v.x); acc[1] += bfhi(v.x);
        acc[2] += bflo(v.y); acc[3] += bfhi(v.y);
        acc[4] += bflo(v.z); acc[5] += bfhi(v.z);
        acc[6] += bflo(v.w); acc[7] += bfhi(v.w);
    }
    if (ssum) {
        float cnt = (float)(e - b + 1);
        int c0 = lc * 8;
#pragma unroll
        for (int j = 0; j < 8; ++j) {
            int c = c0 + j;
            float m   = ssum[c] * invM;
            float var = ssq[c] * invM - m * m;
            float sc  = gamma[c] * rsqrtf(var + BN_EPS);
            acc[j] = sc * acc[j] + cnt * (beta[c] - sc * m);
        }
    }
    uint4 p[2];
#pragma unroll
    for (int j = 0; j < 8; ++j) {
        ushortT h = f2bf(acc[j]);
        ushortT l = f2bf(acc[j] - bf2f(h));
        ((unsigned*)p)[j] = ((unsigned)h << 16) | l;
    }
    *(uint4*)(aggP + (size_t)node * DIM + lc * 8)     = p[0];
    *(uint4*)(aggP + (size_t)node * DIM + lc * 8 + 4) = p[1];
}

// ---- fused GIN layer: r = relu(relu(agg@W1+b1)@W2+b2), h1 via LDS, striped stats.
//      Block = 32 rows; wave = 32 rows x 32 cols (2 M-tiles x 2 N-tiles). ----
__global__ __launch_bounds__(256) void layer_kernel(
    const unsigned* __restrict__ AP,
    const ushortT* __restrict__ W1hi, const ushortT* __restrict__ W1lo,
    const float* __restrict__ b1,
    const ushortT* __restrict__ W2hi, const ushortT* __restrict__ W2lo,
    const float* __restrict__ b2,
    ushortT* __restrict__ rout, float* __restrict__ sdst, int M)
{
    __shared__ unsigned h1s[32][DIM + 4];
    __shared__ float ls[DIM], lsq[DIM];
    int t = threadIdx.x;
    int wave = t >> 6, lane = t & 63, quad = lane >> 4, l16 = lane & 15;
    int m0 = blockIdx.x * 32;
    int cbase = wave * 32;

    if (t < DIM) { ls[t] = 0.f; lsq[t] = 0.f; }

    floatx4 acc[2][2];
#pragma unroll
    for (int mt = 0; mt < 2; ++mt)
#pragma unroll
        for (int nt = 0; nt < 2; ++nt)
            acc[mt][nt] = (floatx4){0.f, 0.f, 0.f, 0.f};

    // ---- phase 1: h1 = A @ W1 ----
#pragma unroll
    for (int ks = 0; ks < 4; ++ks) {
        int k0 = ks * 32 + quad * 8;
        short8 bhi[2], blo[2];
#pragma unroll
        for (int nt = 0; nt < 2; ++nt) {
            const size_t woff = (size_t)(cbase + nt * 16 + l16) * DIM + k0;
            bhi[nt] = *(const short8*)(W1hi + woff);
            blo[nt] = *(const short8*)(W1lo + woff);
        }
#pragma unroll
        for (int mt = 0; mt < 2; ++mt) {
            int row = m0 + mt * 16 + l16;
            unsigned ap[8] = {0, 0, 0, 0, 0, 0, 0, 0};
            if (row < M) {
                *(uint4*)&ap[0] = *(const uint4*)(AP + (size_t)row * DIM + k0);
                *(uint4*)&ap[4] = *(const uint4*)(AP + (size_t)row * DIM + k0 + 4);
            }
            short8 ahi, alo;
            decode8(ap, ahi, alo);
#pragma unroll
            for (int nt = 0; nt < 2; ++nt) {
                acc[mt][nt] = __builtin_amdgcn_mfma_f32_16x16x32_bf16(ahi, bhi[nt], acc[mt][nt], 0, 0, 0);
                acc[mt][nt] = __builtin_amdgcn_mfma_f32_16x16x32_bf16(alo, bhi[nt], acc[mt][nt], 0, 0, 0);
                acc[mt][nt] = __builtin_amdgcn_mfma_f32_16x16x32_bf16(ahi, blo[nt], acc[mt][nt], 0, 0, 0);
            }
        }
    }
    // epilogue 1 -> LDS (packed)
#pragma unroll
    for (int nt = 0; nt < 2; ++nt) {
        int col = cbase + nt * 16 + l16;
        float bcol = b1[col];
#pragma unroll
        for (int mt = 0; mt < 2; ++mt)
#pragma unroll
            for (int r = 0; r < 4; ++r) {
                int lr = mt * 16 + quad * 4 + r;
                float v = fmaxf(acc[mt][nt][r] + bcol, 0.f);
                ushortT hv = f2bf(v);
                ushortT lv = f2bf(v - bf2f(hv));
                h1s[lr][col] = ((unsigned)hv << 16) | lv;
            }
    }
    __syncthreads();

    // ---- phase 2: r = h1 @ W2 ----
#pragma unroll
    for (int mt = 0; mt < 2; ++mt)
#pragma unroll
        for (int nt = 0; nt < 2; ++nt)
            acc[mt][nt] = (floatx4){0.f, 0.f, 0.f, 0.f};

#pragma unroll
    for (int ks = 0; ks < 4; ++ks) {
        int k0 = ks * 32 + quad * 8;
        short8 bhi[2], blo[2];
#pragma unroll
        for (int nt = 0; nt < 2; ++nt) {
            const size_t woff = (size_t)(cbase + nt * 16 + l16) * DIM + k0;
            bhi[nt] = *(const short8*)(W2hi + woff);
            blo[nt] = *(const short8*)(W2lo + woff);
        }
#pragma unroll
        for (int mt = 0; mt < 2; ++mt) {
            int lr = mt * 16 + l16;
            unsigned ap[8];
            *(uint4*)&ap[0] = *(const uint4*)&h1s[lr][k0];
            *(uint4*)&ap[4] = *(const uint4*)&h1s[lr][k0 + 4];
            short8 ahi, alo;
            decode8(ap, ahi, alo);
#pragma unroll
            for (int nt = 0; nt < 2; ++nt) {
                acc[mt][nt] = __builtin_amdgcn_mfma_f32_16x16x32_bf16(ahi, bhi[nt], acc[mt][nt], 0, 0, 0);
                acc[mt][nt] = __builtin_amdgcn_mfma_f32_16x16x32_bf16(alo, bhi[nt], acc[mt][nt], 0, 0, 0);
                acc[mt][nt] = __builtin_amdgcn_mfma_f32_16x16x32_bf16(ahi, blo[nt], acc[mt][nt], 0, 0, 0);
            }
        }
    }
    // epilogue 2: bf16 out + striped stats
#pragma unroll
    for (int nt = 0; nt < 2; ++nt) {
        int col = cbase + nt * 16 + l16;
        float bcol = b2[col];
        float s = 0.f, sq = 0.f;
#pragma unroll
        for (int mt = 0; mt < 2; ++mt)
#pragma unroll
            for (int r = 0; r < 4; ++r) {
                int gr = m0 + mt * 16 + quad * 4 + r;
                if (gr < M) {
                    float v = fmaxf(acc[mt][nt][r] + bcol, 0.f);
                    rout[(size_t)gr * DIM + col] = f2bf(v);
                    s += v;
                    sq += v * v;
                }
            }
        s  += __shfl_xor(s, 16);  s  += __shfl_xor(s, 32);
        sq += __shfl_xor(sq, 16); sq += __shfl_xor(sq, 32);
        if (quad == 0) {
            atomicAdd(&ls[col], s);
            atomicAdd(&lsq[col], sq);
        }
    }
    __syncthreads();
    float* dstp = sdst + (size_t)(blockIdx.x & (NSTRIPE - 1)) * 256;
    if (t < 128) atomicAdd(&dstp[t], ls[t]);
    else         atomicAdd(&dstp[t], lsq[t - 128]);
}

// ---- fused node heads: outA = relu(A@WA+bA), outB = relu(A@WB+bB), striped stats ----
__global__ __launch_bounds__(256) void heads_kernel(
    const unsigned* __restrict__ AP,
    const ushortT* __restrict__ WAhi, const ushortT* __restrict__ WAlo,
    const float* __restrict__ bA, float* __restrict__ outA, float* __restrict__ sdstA,
    const ushortT* __restrict__ WBhi, const ushortT* __restrict__ WBlo,
    const float* __restrict__ bB, float* __restrict__ outB, float* __restrict__ sdstB,
    int M)
{
    __shared__ float lsA[DIM], lsqA[DIM], lsB[DIM], lsqB[DIM];
    int t = threadIdx.x;
    int wave = t >> 6, lane = t & 63, quad = lane >> 4, l16 = lane & 15;
    int m0 = blockIdx.x * 32;
    int cbase = wave * 32;

    if (t < DIM) { lsA[t] = 0.f; lsqA[t] = 0.f; lsB[t] = 0.f; lsqB[t] = 0.f; }
    __syncthreads();

    floatx4 accA[2][2], accB[2][2];
#pragma unroll
    for (int mt = 0; mt < 2; ++mt)
#pragma unroll
        for (int nt = 0; nt < 2; ++nt) {
            accA[mt][nt] = (floatx4){0.f, 0.f, 0.f, 0.f};
            accB[mt][nt] = (floatx4){0.f, 0.f, 0.f, 0.f};
        }

#pragma unroll
    for (int ks = 0; ks < 4; ++ks) {
        int k0 = ks * 32 + quad * 8;
        short8 bAhi[2], bAlo[2], bBhi[2], bBlo[2];
#pragma unroll
        for (int nt = 0; nt < 2; ++nt) {
            const size_t woff = (size_t)(cbase + nt * 16 + l16) * DIM + k0;
            bAhi[nt] = *(const short8*)(WAhi + woff);
            bAlo[nt] = *(const short8*)(WAlo + woff);
            bBhi[nt] = *(const short8*)(WBhi + woff);
            bBlo[nt] = *(const short8*)(WBlo + woff);
        }
#pragma unroll
        for (int mt = 0; mt < 2; ++mt) {
            int row = m0 + mt * 16 + l16;
            unsigned ap[8] = {0, 0, 0, 0, 0, 0, 0, 0};
            if (row < M) {
                *(uint4*)&ap[0] = *(const uint4*)(AP + (size_t)row * DIM + k0);
                *(uint4*)&ap[4] = *(const uint4*)(AP + (size_t)row * DIM + k0 + 4);
            }
            short8 ahi, alo;
            decode8(ap, ahi, alo);
#pragma unroll
            for (int nt = 0; nt < 2; ++nt) {
                accA[mt][nt] = __builtin_amdgcn_mfma_f32_16x16x32_bf16(ahi, bAhi[nt], accA[mt][nt], 0, 0, 0);
                accA[mt][nt] = __builtin_amdgcn_mfma_f32_16x16x32_bf16(alo, bAhi[nt], accA[mt][nt], 0, 0, 0);
                accA[mt][nt] = __builtin_amdgcn_mfma_f32_16x16x32_bf16(ahi, bAlo[nt], accA[mt][nt], 0, 0, 0);
                accB[mt][nt] = __builtin_amdgcn_mfma_f32_16x16x32_bf16(ahi, bBhi[nt], accB[mt][nt], 0, 0, 0);
                accB[mt][nt] = __builtin_amdgcn_mfma_f32_16x16x32_bf16(alo, bBhi[nt], accB[mt][nt], 0, 0, 0);
                accB[mt][nt] = __builtin_amdgcn_mfma_f32_16x16x32_bf16(ahi, bBlo[nt], accB[mt][nt], 0, 0, 0);
            }
        }
    }

#pragma unroll
    for (int nt = 0; nt < 2; ++nt) {
        int col = cbase + nt * 16 + l16;
        float bcA = bA[col], bcB = bB[col];
        float sA = 0.f, sqA = 0.f, sB = 0.f, sqB = 0.f;
#pragma unroll
        for (int mt = 0; mt < 2; ++mt)
#pragma unroll
            for (int r = 0; r < 4; ++r) {
                int gr = m0 + mt * 16 + quad * 4 + r;
                if (gr < M) {
                    size_t off = (size_t)gr * DIM + col;
                    float vA = fmaxf(accA[mt][nt][r] + bcA, 0.f);
                    float vB = fmaxf(accB[mt][nt][r] + bcB, 0.f);
                    outA[off] = vA;
                    outB[off] = vB;
                    sA += vA; sqA += vA * vA;
                    sB += vB; sqB += vB * vB;
                }
            }
        sA += __shfl_xor(sA, 16);  sA += __shfl_xor(sA, 32);
        sqA += __shfl_xor(sqA, 16); sqA += __shfl_xor(sqA, 32);
        sB += __shfl_xor(sB, 16);  sB += __shfl_xor(sB, 32);
        sqB += __shfl_xor(sqB, 16); sqB += __shfl_xor(sqB, 32);
        if (quad == 0) {
            atomicAdd(&lsA[col], sA);
            atomicAdd(&lsqA[col], sqA);
            atomicAdd(&lsB[col], sB);
            atomicAdd(&lsqB[col], sqB);
        }
    }
    __syncthreads();
    int stripe = blockIdx.x & (NSTRIPE - 1);
    float* dA = sdstA + (size_t)stripe * 256;
    float* dB = sdstB + (size_t)stripe * 256;
    if (t < 128) { atomicAdd(&dA[t], lsA[t]); atomicAdd(&dB[t], lsB[t]); }
    else         { atomicAdd(&dA[t], lsqA[t - 128]); atomicAdd(&dB[t], lsqB[t - 128]); }
}

// ---- generic split GEMM for graph heads (fp32 A, in-kernel decompose, direct stats) ----
__global__ __launch_bounds__(256) void gemm_graph_kernel(
    const float* __restrict__ A32,
    const ushortT* __restrict__ Whi, const ushortT* __restrict__ Wlo,
    const float* __restrict__ bias, float* __restrict__ C,
    float* __restrict__ ssum, float* __restrict__ ssq, int M)
{
    __shared__ float ls[DIM], lsq[DIM];
    int t     = threadIdx.x;
    int wave  = t >> 6;
    int lane  = t & 63;
    int quad  = lane >> 4;
    int l16   = lane & 15;
    int m0    = blockIdx.x * 64;
    int cbase = wave * 32;

    if (t < DIM) { ls[t] = 0.f; lsq[t] = 0.f; }
    __syncthreads();

    floatx4 acc[4][2];
#pragma unroll
    for (int mt = 0; mt < 4; ++mt)
#pragma unroll
        for (int nt = 0; nt < 2; ++nt)
            acc[mt][nt] = (floatx4){0.f, 0.f, 0.f, 0.f};

    for (int ks = 0; ks < 4; ++ks) {
        int k0 = ks * 32 + quad * 8;
        short8 bhi[2], blo[2];
#pragma unroll
        for (int nt = 0; nt < 2; ++nt) {
            const size_t woff = (size_t)(cbase + nt * 16 + l16) * DIM + k0;
            bhi[nt] = *(const short8*)(Whi + woff);
            blo[nt] = *(const short8*)(Wlo + woff);
        }
#pragma unroll
        for (int mt = 0; mt < 4; ++mt) {
            int row = m0 + mt * 16 + l16;
            short8 ahi = {0,0,0,0,0,0,0,0};
            short8 alo = {0,0,0,0,0,0,0,0};
            if (row < M) {
                float av[8];
                *(float4*)&av[0] = *(const float4*)(A32 + (size_t)row * DIM + k0);
                *(float4*)&av[4] = *(const float4*)(A32 + (size_t)row * DIM + k0 + 4);
#pragma unroll
                for (int j = 0; j < 8; ++j) {
                    ushortT hv = f2bf(av[j]);
                    ahi[j] = (short)hv;
                    alo[j] = (short)f2bf(av[j] - bf2f(hv));
                }
            }
#pragma unroll
            for (int nt = 0; nt < 2; ++nt) {
                acc[mt][nt] = __builtin_amdgcn_mfma_f32_16x16x32_bf16(ahi, bhi[nt], acc[mt][nt], 0, 0, 0);
                acc[mt][nt] = __builtin_amdgcn_mfma_f32_16x16x32_bf16(alo, bhi[nt], acc[mt][nt], 0, 0, 0);
                acc[mt][nt] = __builtin_amdgcn_mfma_f32_16x16x32_bf16(ahi, blo[nt], acc[mt][nt], 0, 0, 0);
            }
        }
    }

#pragma unroll
    for (int nt = 0; nt < 2; ++nt) {
        int col = cbase + nt * 16 + l16;
        float bcol = bias[col];
        float s = 0.f, sq = 0.f;
#pragma unroll
        for (int mt = 0; mt < 4; ++mt)
#pragma unroll
            for (int r = 0; r < 4; ++r) {
                int gr = m0 + mt * 16 + quad * 4 + r;
                if (gr < M) {
                    float v = fmaxf(acc[mt][nt][r] + bcol, 0.f);
                    C[(size_t)gr * DIM + col] = v;
                    s += v;
                    sq += v * v;
                }
            }
        s  += __shfl_xor(s, 16);  s  += __shfl_xor(s, 32);
        sq += __shfl_xor(sq, 16); sq += __shfl_xor(sq, 32);
        if (quad == 0) {
            atomicAdd(&ls[col], s);
            atomicAdd(&lsq[col], sq);
        }
    }
    __syncthreads();
    if (t < DIM) {
        atomicAdd(&ssum[t], ls[t]);
        atomicAdd(&ssq[t], lsq[t]);
    }
}

__global__ __launch_bounds__(256) void bn_apply_kernel(
    const float* __restrict__ R, float* __restrict__ O,
    const float* __restrict__ sums, const float* __restrict__ sqsums,
    const float* __restrict__ gamma, const float* __restrict__ beta, int M)
{
    int idx = blockIdx.x * 256 + threadIdx.x;
    if (idx >= M * 32) return;
    int c4 = idx & 31;
    float invM = 1.0f / (float)M;
    float4 v = ((const float4*)R)[idx];
    float o[4] = {v.x, v.y, v.z, v.w};
#pragma unroll
    for (int j = 0; j < 4; ++j) {
        int c = c4 * 4 + j;
        float m   = sums[c] * invM;
        float var = sqsums[c] * invM - m * m;
        float sc  = gamma[c] * rsqrtf(var + BN_EPS);
        o[j] = sc * (o[j] - m) + beta[c];
    }
    ((float4*)O)[idx] = make_float4(o[0], o[1], o[2], o[3]);
}

// ---- w = sigmoid(bn(r) @ sw_w + sw_b), BN folded in; r is bf16 ----
__global__ __launch_bounds__(256) void weigh_kernel(
    const ushortT* __restrict__ R,
    const float* __restrict__ ssum, const float* __restrict__ ssq,
    const float* __restrict__ gamma, const float* __restrict__ beta,
    const float* __restrict__ sw_w, const float* __restrict__ sw_b,
    float* __restrict__ wbuf, int N, float invM)
{
    int gid  = blockIdx.x * 256 + threadIdx.x;
    int node = gid >> 5;
    int l    = gid & 31;
    if (node >= N) return;
    int c0 = l * 4;
    uint2 u = *(const uint2*)(R + (size_t)node * DIM + c0);
    float r0 = bflo(u.x), r1 = bfhi(u.x), r2 = bflo(u.y), r3 = bfhi(u.y);
    float4 sm = *(const float4*)(ssum + c0);
    float4 sq = *(const float4*)(ssq + c0);
    float4 gm = *(const float4*)(gamma + c0);
    float4 bt = *(const float4*)(beta + c0);
    float4 sw = *(const float4*)(sw_w + c0);
    float m0 = sm.x * invM, m1 = sm.y * invM, m2 = sm.z * invM, m3 = sm.w * invM;
    float v0 = gm.x * rsqrtf(sq.x * invM - m0 * m0 + BN_EPS) * (r0 - m0) + bt.x;
    float v1 = gm.y * rsqrtf(sq.y * invM - m1 * m1 + BN_EPS) * (r1 - m1) + bt.y;
    float v2 = gm.z * rsqrtf(sq.z * invM - m2 * m2 + BN_EPS) * (r2 - m2) + bt.z;
    float v3 = gm.w * rsqrtf(sq.w * invM - m3 * m3 + BN_EPS) * (r3 - m3) + bt.w;
    float d = v0 * sw.x + v1 * sw.y + v2 * sw.z + v3 * sw.w;
#pragma unroll
    for (int off = 16; off > 0; off >>= 1)
        d += __shfl_down(d, off, 32);
    if (l == 0)
        wbuf[node] = 1.0f / (1.0f + expf(-(d + sw_b[0])));
}

// ---- noisy = (1-w)*bn(r) -> packed plane; slots[g] += w*bn(r), segmented ----
__global__ __launch_bounds__(256) void split_seg_kernel(
    const ushortT* __restrict__ R, const float* __restrict__ wbuf,
    const int* __restrict__ batch,
    const float* __restrict__ ssum, const float* __restrict__ ssq,
    const float* __restrict__ gamma, const float* __restrict__ beta,
    unsigned* __restrict__ noisyP, float* __restrict__ slots, int N, float invM)
{
    int t    = threadIdx.x;
    int c    = t & 127;
    int half = t >> 7;
    int r0   = blockIdx.x * 128;
    int rend = r0 + 128;
    if (rend > N) rend = N;
    float m   = ssum[c] * invM;
    float var = ssq[c] * invM - m * m;
    float sc  = gamma[c] * rsqrtf(var + BN_EPS);
    float sh  = beta[c] - sc * m;
    int curg = -1;
    float acc = 0.f;
    for (int r = r0 + half; r < rend; r += 2) {
        float xv = sc * bf2f(R[(size_t)r * DIM + c]) + sh;
        float w  = wbuf[r];
        float nv = (1.f - w) * xv;
        ushortT hv = f2bf(nv);
        ushortT lv = f2bf(nv - bf2f(hv));
        noisyP[(size_t)r * DIM + c] = ((unsigned)hv << 16) | lv;
        int g = batch[r];
        if (g != curg) {
            if (curg >= 0) atomicAdd(&slots[(size_t)curg * DIM + c], acc);
            curg = g;
            acc = 0.f;
        }
        acc += w * xv;
    }
    if (curg >= 0) atomicAdd(&slots[(size_t)curg * DIM + c], acc);
}

extern "C" void kernel_launch(void* const* d_in, const int* in_sizes, int n_in,
                              void* d_out, int out_size, void* d_ws, size_t ws_size,
                              hipStream_t stream)
{
    const float* x      = (const float*)d_in[0];
    const int*   src    = (const int*)d_in[1];
    const int*   dst    = (const int*)d_in[2];
    const int*   batch  = (const int*)d_in[3];
    const float* cw1    = (const float*)d_in[5];
    const float* cb1    = (const float*)d_in[6];
    const float* cw2    = (const float*)d_in[7];
    const float* cb2    = (const float*)d_in[8];
    const float* bng    = (const float*)d_in[9];
    const float* bnb    = (const float*)d_in[10];
    const float* sw_w   = (const float*)d_in[11];
    const float* sw_b   = (const float*)d_in[12];
    const float* nmu_w  = (const float*)d_in[13];
    const float* nmu_b  = (const float*)d_in[14];
    const float* nlv_w  = (const float*)d_in[15];
    const float* nlv_b  = (const float*)d_in[16];
    const float* gmu_w  = (const float*)d_in[17];
    const float* gmu_b  = (const float*)d_in[18];
    const float* glv_w  = (const float*)d_in[19];
    const float* glv_b  = (const float*)d_in[20];
    const float* hgam   = (const float*)d_in[21];
    const float* hbet   = (const float*)d_in[22];

    const int N = in_sizes[0] / DIM;
    const int E = in_sizes[1];
    const int G = (out_size / DIM - 2 * N) / 2;

    float* out0 = (float*)d_out;
    float* out1 = out0 + (size_t)N * DIM;
    float* out2 = out1 + (size_t)N * DIM;
    float* out3 = out2 + (size_t)G * DIM;

    // ---- workspace layout ----
    char* wp = (char*)d_ws;
    auto alloc = [&](size_t bytes) {
        char* p = wp;
        wp += (bytes + 255) & ~(size_t)255;
        return p;
    };
    ushortT*  xbf   = (ushortT*)alloc((size_t)N * DIM * 2);  // layer-0 gather input
    unsigned* aggP  = (unsigned*)alloc((size_t)N * DIM * 4); // packed agg; later noisy
    ushortT*  rfbf  = (ushortT*)alloc((size_t)N * DIM * 2);  // layer output (pre-BN, bf16)
    ushortT*  whi   = (ushortT*)alloc((size_t)10 * 16384 * 2);
    ushortT*  wlo   = (ushortT*)alloc((size_t)10 * 16384 * 2);
    float* slots    = (float*)alloc((size_t)G * DIM * 4);
    float* stats    = (float*)alloc((size_t)7 * 256 * 4);          // [sum|sq] x7
    float* sbuf     = (float*)alloc((size_t)5 * NSTRIPE * 256 * 4);// stripe bufs x5
    float* wbuf     = (float*)alloc((size_t)N * 4);
    int* row_ptr    = (int*)alloc((size_t)(N + 2) * 4);
    int* eidx       = (int*)alloc((size_t)E * 4);
    // CSR temps overlay in aggP (aggP first written by gather, after CSR build)
    int* deg   = (int*)aggP;
    int* iscan = deg + N;
    int* bsum  = iscan + N;
    int* cur   = bsum + 256;

    auto SS = [&](int i) { return stats + (size_t)i * 256; };
    auto SQ = [&](int i) { return stats + (size_t)i * 256 + 128; };
    auto SB = [&](int i) { return sbuf + (size_t)i * NSTRIPE * 256; };

    const int edge_blocks  = (E + 255) / 256;
    const int scan_blocks  = (N + 255) / 256;
    const int layer_blocks = (N + 31) / 32;
    const int g16_blocks   = (N * 16 + 255) / 256;
    const int g32_blocks   = (N * 32 + 255) / 256;
    const float invN = 1.0f / (float)N;

    hipMemsetAsync(stats, 0, (size_t)7 * 256 * 4, stream);
    hipMemsetAsync(sbuf, 0, (size_t)5 * NSTRIPE * 256 * 4, stream);
    hipMemsetAsync(slots, 0, (size_t)G * DIM * 4, stream);
    hipMemsetAsync(deg, 0, (size_t)N * 4, stream);

    convw_kernel<<<(10 * 16384) / 256, 256, 0, stream>>>(
        cw1, cw2, nmu_w, nlv_w, gmu_w, glv_w, whi, wlo);
    convx_kernel<<<g16_blocks, 256, 0, stream>>>(x, xbf, N * 16);

    hist_kernel<<<edge_blocks, 256, 0, stream>>>(dst, deg, E);
    scan1_kernel<<<scan_blocks, 256, 0, stream>>>(deg, iscan, bsum, N);
    scan2_kernel<<<1, 256, 0, stream>>>(bsum, scan_blocks);
    scan3_kernel<<<scan_blocks, 256, 0, stream>>>(iscan, bsum, deg, row_ptr, cur, N);
    fill_kernel<<<edge_blocks, 256, 0, stream>>>(src, dst, cur, eidx, E);

    const ushortT* gin = xbf;
    for (int l = 0; l < 3; ++l) {
        const float* sums_prev = (l == 0) ? nullptr : SS(l - 1);
        const float* sq_prev   = (l == 0) ? nullptr : SQ(l - 1);
        const float* g_prev    = (l == 0) ? nullptr : bng + (size_t)(l - 1) * DIM;
        const float* b_prev    = (l == 0) ? nullptr : bnb + (size_t)(l - 1) * DIM;
        gather_kernel<<<g16_blocks, 256, 0, stream>>>(
            gin, row_ptr, eidx, sums_prev, sq_prev, g_prev, b_prev,
            aggP, N, invN);
        layer_kernel<<<layer_blocks, 256, 0, stream>>>(
            aggP,
            whi + (size_t)l * 16384, wlo + (size_t)l * 16384, cb1 + (size_t)l * DIM,
            whi + (size_t)(3 + l) * 16384, wlo + (size_t)(3 + l) * 16384, cb2 + (size_t)l * DIM,
            rfbf, SB(l), N);
        merge_stats_kernel<<<1, 256, 0, stream>>>(SB(l), SS(l));
        gin = rfbf;
    }

    // BN(layer2) folded into weigh/split
    weigh_kernel<<<g32_blocks, 256, 0, stream>>>(
        rfbf, SS(2), SQ(2), bng + 2 * DIM, bnb + 2 * DIM, sw_w, sw_b, wbuf, N, invN);
    split_seg_kernel<<<(N + 127) / 128, 256, 0, stream>>>(
        rfbf, wbuf, batch, SS(2), SQ(2), bng + 2 * DIM, bnb + 2 * DIM,
        aggP /*noisy packed*/, slots, N, invN);

    // fused node heads (both GEMMs in one pass over noisy), then BN in place
    heads_kernel<<<layer_blocks, 256, 0, stream>>>(
        aggP,
        whi + (size_t)6 * 16384, wlo + (size_t)6 * 16384, nmu_b, out0, SB(3),
        whi + (size_t)7 * 16384, wlo + (size_t)7 * 16384, nlv_b, out1, SB(4), N);
    merge_stats_kernel<<<1, 256, 0, stream>>>(SB(3), SS(3));
    merge_stats_kernel<<<1, 256, 0, stream>>>(SB(4), SS(4));
    bn_apply_kernel<<<g32_blocks, 256, 0, stream>>>(
        out0, out0, SS(3), SQ(3), hgam + 0 * DIM, hbet + 0 * DIM, N);
    bn_apply_kernel<<<g32_blocks, 256, 0, stream>>>(
        out1, out1, SS(4), SQ(4), hgam + 1 * DIM, hbet + 1 * DIM, N);

    // graph heads (tiny)
    const int gemm_blocks_G = (G + 63) / 64;
    gemm_graph_kernel<<<gemm_blocks_G, 256, 0, stream>>>(
        slots, whi + (size_t)8 * 16384, wlo + (size_t)8 * 16384,
        gmu_b, out2, SS(5), SQ(5), G);
    gemm_graph_kernel<<<gemm_blocks_G, 256, 0, stream>>>(
        slots, whi + (size_t)9 * 16384, wlo + (size_t)9 * 16384,
        glv_b, out3, SS(6), SQ(6), G);
    bn_apply_kernel<<<(G * 32 + 255) / 256, 256, 0, stream>>>(
        out2, out2, SS(5), SQ(5), hgam + 2 * DIM, hbet + 2 * DIM, G);
    bn_apply_kernel<<<(G * 32 + 255) / 256, 256, 0, stream>>>(
        out3, out3, SS(6), SQ(6), hgam + 3 * DIM, hbet + 3 * DIM, G);
}

// Round 9
// 539.694 us; speedup vs baseline: 7.1626x; 1.0607x over previous
//
#include <hip/hip_runtime.h>
#include <hip/hip_bf16.h>

#define DIM 128
#define BN_EPS 1e-5f
#define NSTRIPE 32

typedef unsigned short ushortT;
typedef __attribute__((ext_vector_type(8))) short short8;
typedef __attribute__((ext_vector_type(4))) float floatx4;

__device__ __forceinline__ float bflo(unsigned u) { return __uint_as_float(u << 16); }
__device__ __forceinline__ float bfhi(unsigned u) { return __uint_as_float(u & 0xffff0000u); }
__device__ __forceinline__ float bf2f(ushortT h) { return __uint_as_float(((unsigned)h) << 16); }
__device__ __forceinline__ ushortT f2bf(float f) {
    unsigned x = __float_as_uint(f);
    unsigned r = (x + 0x7fff + ((x >> 16) & 1)) >> 16;
    return (ushortT)r;
}
__device__ __forceinline__ void decode8(const unsigned* ap, short8& hi, short8& lo) {
#pragma unroll
    for (int j = 0; j < 8; ++j) {
        hi[j] = (short)(ap[j] >> 16);
        lo[j] = (short)(ap[j] & 0xffffu);
    }
}
__device__ __forceinline__ void acc8(float* a, uint4 v) {
    a[0] += bflo(v.x); a[1] += bfhi(v.x);
    a[2] += bflo(v.y); a[3] += bfhi(v.y);
    a[4] += bflo(v.z); a[5] += bfhi(v.z);
    a[6] += bflo(v.w); a[7] += bfhi(v.w);
}

// ---------------- CSR build ----------------
__global__ __launch_bounds__(256) void hist_kernel(
    const int* __restrict__ dst, int* __restrict__ deg, int E)
{
    int e = blockIdx.x * 256 + threadIdx.x;
    if (e < E) atomicAdd(&deg[dst[e]], 1);
}

__global__ __launch_bounds__(256) void scan1_kernel(
    const int* __restrict__ deg, int* __restrict__ iscan,
    int* __restrict__ bsum, int N)
{
    __shared__ int s[256];
    int t = threadIdx.x;
    int i = blockIdx.x * 256 + t;
    int v = (i < N) ? deg[i] : 0;
    s[t] = v;
    __syncthreads();
#pragma unroll
    for (int off = 1; off < 256; off <<= 1) {
        int u = (t >= off) ? s[t - off] : 0;
        __syncthreads();
        s[t] += u;
        __syncthreads();
    }
    if (i < N) iscan[i] = s[t];
    if (t == 255) bsum[blockIdx.x] = s[255];
}

__global__ __launch_bounds__(256) void scan2_kernel(int* __restrict__ bsum, int nb)
{
    __shared__ int s[256];
    int t = threadIdx.x;
    int v = (t < nb) ? bsum[t] : 0;
    s[t] = v;
    __syncthreads();
#pragma unroll
    for (int off = 1; off < 256; off <<= 1) {
        int u = (t >= off) ? s[t - off] : 0;
        __syncthreads();
        s[t] += u;
        __syncthreads();
    }
    if (t < nb) bsum[t] = s[t] - v; // exclusive
}

__global__ __launch_bounds__(256) void scan3_kernel(
    const int* __restrict__ iscan, const int* __restrict__ bsum,
    const int* __restrict__ deg, int* __restrict__ row_ptr,
    int* __restrict__ cur, int N)
{
    int i = blockIdx.x * 256 + threadIdx.x;
    if (i < N) {
        int inc = iscan[i] + bsum[i >> 8];
        row_ptr[i + 1] = inc;
        cur[i] = inc - deg[i];
    }
    if (i == 0) row_ptr[0] = 0;
}

__global__ __launch_bounds__(256) void fill_kernel(
    const int* __restrict__ src, const int* __restrict__ dst,
    int* __restrict__ cur, int* __restrict__ eidx, int E)
{
    int e = blockIdx.x * 256 + threadIdx.x;
    if (e < E) {
        int pos = atomicAdd(&cur[dst[e]], 1);
        eidx[pos] = src[e];
    }
}

// ---- weights -> transposed bf16 hi/lo planes. 0-2: cw1, 3-5: cw2, 6:nmu,7:nlv,8:gmu,9:glv ----
__global__ __launch_bounds__(256) void convw_kernel(
    const float* __restrict__ cw1, const float* __restrict__ cw2,
    const float* __restrict__ nmu, const float* __restrict__ nlv,
    const float* __restrict__ gmu, const float* __restrict__ glv,
    ushortT* __restrict__ whi, ushortT* __restrict__ wlo)
{
    int tid = blockIdx.x * 256 + threadIdx.x; // 10*16384
    int mat = tid >> 14;
    int i   = tid & 16383;
    int n = i >> 7, k = i & 127;
    const float* Wm = (mat < 3) ? cw1 + (size_t)mat * 16384
                    : (mat < 6) ? cw2 + (size_t)(mat - 3) * 16384
                    : (mat == 6) ? nmu : (mat == 7) ? nlv
                    : (mat == 8) ? gmu : glv;
    float w = Wm[k * DIM + n];
    ushortT h = f2bf(w);
    whi[(size_t)mat * 16384 + i] = h;
    wlo[(size_t)mat * 16384 + i] = f2bf(w - bf2f(h));
}

// ---- x fp32 -> bf16 plane ----
__global__ __launch_bounds__(256) void convx_kernel(
    const float* __restrict__ x, ushortT* __restrict__ xb, int n8)
{
    int i = blockIdx.x * 256 + threadIdx.x;
    if (i >= n8) return;
    const float4* xp = (const float4*)x;
    float4 a = xp[2 * i], b = xp[2 * i + 1];
    uint4 o;
    o.x = (unsigned)f2bf(a.x) | ((unsigned)f2bf(a.y) << 16);
    o.y = (unsigned)f2bf(a.z) | ((unsigned)f2bf(a.w) << 16);
    o.z = (unsigned)f2bf(b.x) | ((unsigned)f2bf(b.y) << 16);
    o.w = (unsigned)f2bf(b.z) | ((unsigned)f2bf(b.w) << 16);
    ((uint4*)xb)[i] = o;
}

// ---- merge 32 stat stripes -> final [256] (sum | sq) ----
__global__ __launch_bounds__(256) void merge_stats_kernel(
    const float* __restrict__ sbuf, float* __restrict__ out)
{
    int t = threadIdx.x;
    float s = 0.f;
#pragma unroll
    for (int i = 0; i < NSTRIPE; ++i) s += sbuf[i * 256 + t];
    out[t] = s;
}

// ---- fused GIN layer: gather(CSR)+BNaffine -> LDS -> GEMM1 -> LDS -> GEMM2 -> bf16 out + striped stats.
//      Block = 32 rows; wave = 32 rows x 32 cols (2 M-tiles x 2 N-tiles). ----
__global__ __launch_bounds__(256) void layer_fused_kernel(
    const ushortT* __restrict__ Xb, const int* __restrict__ row_ptr,
    const int* __restrict__ eidx,
    const float* __restrict__ ssum, const float* __restrict__ ssq,
    const float* __restrict__ gamma, const float* __restrict__ beta,
    const ushortT* __restrict__ W1hi, const ushortT* __restrict__ W1lo,
    const float* __restrict__ b1,
    const ushortT* __restrict__ W2hi, const ushortT* __restrict__ W2lo,
    const float* __restrict__ b2,
    ushortT* __restrict__ rout, float* __restrict__ sdst,
    int M, float invM)
{
    __shared__ unsigned As[32][DIM + 4];
    __shared__ float ls[DIM], lsq[DIM];
    int t = threadIdx.x;
    int wave = t >> 6, lane = t & 63, quad = lane >> 4, l16 = lane & 15;
    int m0 = blockIdx.x * 32;

    // ---- gather phase: 8 lanes per node, 16 cols each ----
    {
        int nloc = t >> 3;
        int c0   = (t & 7) * 16;
        int node = m0 + nloc;
        float acc[16];
#pragma unroll
        for (int j = 0; j < 16; ++j) acc[j] = 0.f;
        if (node < M) {
            int b = row_ptr[node];
            int e = row_ptr[node + 1];
            const ushortT* xrow = Xb + (size_t)node * DIM + c0;
            acc8(&acc[0], *(const uint4*)(xrow));
            acc8(&acc[8], *(const uint4*)(xrow + 8));
            for (int i = b; i < e; ++i) {
                const ushortT* srow = Xb + (size_t)eidx[i] * DIM + c0;
                uint4 v0 = *(const uint4*)(srow);
                uint4 v1 = *(const uint4*)(srow + 8);
                acc8(&acc[0], v0);
                acc8(&acc[8], v1);
            }
            if (ssum) {
                float cnt = (float)(e - b + 1);
#pragma unroll
                for (int jq = 0; jq < 4; ++jq) {
                    int c = c0 + jq * 4;
                    float4 sm = *(const float4*)(ssum + c);
                    float4 sq = *(const float4*)(ssq + c);
                    float4 gm = *(const float4*)(gamma + c);
                    float4 bt = *(const float4*)(beta + c);
                    float m, sc;
                    m = sm.x * invM; sc = gm.x * rsqrtf(sq.x * invM - m * m + BN_EPS);
                    acc[jq * 4 + 0] = sc * acc[jq * 4 + 0] + cnt * (bt.x - sc * m);
                    m = sm.y * invM; sc = gm.y * rsqrtf(sq.y * invM - m * m + BN_EPS);
                    acc[jq * 4 + 1] = sc * acc[jq * 4 + 1] + cnt * (bt.y - sc * m);
                    m = sm.z * invM; sc = gm.z * rsqrtf(sq.z * invM - m * m + BN_EPS);
                    acc[jq * 4 + 2] = sc * acc[jq * 4 + 2] + cnt * (bt.z - sc * m);
                    m = sm.w * invM; sc = gm.w * rsqrtf(sq.w * invM - m * m + BN_EPS);
                    acc[jq * 4 + 3] = sc * acc[jq * 4 + 3] + cnt * (bt.w - sc * m);
                }
            }
        }
#pragma unroll
        for (int j = 0; j < 16; ++j) {
            ushortT h = f2bf(acc[j]);
            ushortT l = f2bf(acc[j] - bf2f(h));
            As[nloc][c0 + j] = ((unsigned)h << 16) | l;
        }
    }
    if (t < DIM) { ls[t] = 0.f; lsq[t] = 0.f; }
    __syncthreads();

    int cbase = wave * 32;
    floatx4 acc[2][2];
#pragma unroll
    for (int mt = 0; mt < 2; ++mt)
#pragma unroll
        for (int nt = 0; nt < 2; ++nt)
            acc[mt][nt] = (floatx4){0.f, 0.f, 0.f, 0.f};

    // ---- GEMM1: h1 = A @ W1, A from LDS ----
#pragma unroll
    for (int ks = 0; ks < 4; ++ks) {
        int k0 = ks * 32 + quad * 8;
        short8 bhi[2], blo[2];
#pragma unroll
        for (int nt = 0; nt < 2; ++nt) {
            const size_t woff = (size_t)(cbase + nt * 16 + l16) * DIM + k0;
            bhi[nt] = *(const short8*)(W1hi + woff);
            blo[nt] = *(const short8*)(W1lo + woff);
        }
#pragma unroll
        for (int mt = 0; mt < 2; ++mt) {
            int lr = mt * 16 + l16;
            unsigned ap[8];
            *(uint4*)&ap[0] = *(const uint4*)&As[lr][k0];
            *(uint4*)&ap[4] = *(const uint4*)&As[lr][k0 + 4];
            short8 ahi, alo;
            decode8(ap, ahi, alo);
#pragma unroll
            for (int nt = 0; nt < 2; ++nt) {
                acc[mt][nt] = __builtin_amdgcn_mfma_f32_16x16x32_bf16(ahi, bhi[nt], acc[mt][nt], 0, 0, 0);
                acc[mt][nt] = __builtin_amdgcn_mfma_f32_16x16x32_bf16(alo, bhi[nt], acc[mt][nt], 0, 0, 0);
                acc[mt][nt] = __builtin_amdgcn_mfma_f32_16x16x32_bf16(ahi, blo[nt], acc[mt][nt], 0, 0, 0);
            }
        }
    }
    __syncthreads(); // all waves done reading As as A-input

    // epilogue 1 -> LDS (packed, reuse As)
#pragma unroll
    for (int nt = 0; nt < 2; ++nt) {
        int col = cbase + nt * 16 + l16;
        float bcol = b1[col];
#pragma unroll
        for (int mt = 0; mt < 2; ++mt)
#pragma unroll
            for (int r = 0; r < 4; ++r) {
                int lr = mt * 16 + quad * 4 + r;
                float v = fmaxf(acc[mt][nt][r] + bcol, 0.f);
                ushortT hv = f2bf(v);
                ushortT lv = f2bf(v - bf2f(hv));
                As[lr][col] = ((unsigned)hv << 16) | lv;
            }
    }
    __syncthreads();

    // ---- GEMM2: r = h1 @ W2 ----
#pragma unroll
    for (int mt = 0; mt < 2; ++mt)
#pragma unroll
        for (int nt = 0; nt < 2; ++nt)
            acc[mt][nt] = (floatx4){0.f, 0.f, 0.f, 0.f};

#pragma unroll
    for (int ks = 0; ks < 4; ++ks) {
        int k0 = ks * 32 + quad * 8;
        short8 bhi[2], blo[2];
#pragma unroll
        for (int nt = 0; nt < 2; ++nt) {
            const size_t woff = (size_t)(cbase + nt * 16 + l16) * DIM + k0;
            bhi[nt] = *(const short8*)(W2hi + woff);
            blo[nt] = *(const short8*)(W2lo + woff);
        }
#pragma unroll
        for (int mt = 0; mt < 2; ++mt) {
            int lr = mt * 16 + l16;
            unsigned ap[8];
            *(uint4*)&ap[0] = *(const uint4*)&As[lr][k0];
            *(uint4*)&ap[4] = *(const uint4*)&As[lr][k0 + 4];
            short8 ahi, alo;
            decode8(ap, ahi, alo);
#pragma unroll
            for (int nt = 0; nt < 2; ++nt) {
                acc[mt][nt] = __builtin_amdgcn_mfma_f32_16x16x32_bf16(ahi, bhi[nt], acc[mt][nt], 0, 0, 0);
                acc[mt][nt] = __builtin_amdgcn_mfma_f32_16x16x32_bf16(alo, bhi[nt], acc[mt][nt], 0, 0, 0);
                acc[mt][nt] = __builtin_amdgcn_mfma_f32_16x16x32_bf16(ahi, blo[nt], acc[mt][nt], 0, 0, 0);
            }
        }
    }
    // epilogue 2: bf16 out + striped stats
#pragma unroll
    for (int nt = 0; nt < 2; ++nt) {
        int col = cbase + nt * 16 + l16;
        float bcol = b2[col];
        float s = 0.f, sq = 0.f;
#pragma unroll
        for (int mt = 0; mt < 2; ++mt)
#pragma unroll
            for (int r = 0; r < 4; ++r) {
                int gr = m0 + mt * 16 + quad * 4 + r;
                if (gr < M) {
                    float v = fmaxf(acc[mt][nt][r] + bcol, 0.f);
                    rout[(size_t)gr * DIM + col] = f2bf(v);
                    s += v;
                    sq += v * v;
                }
            }
        s  += __shfl_xor(s, 16);  s  += __shfl_xor(s, 32);
        sq += __shfl_xor(sq, 16); sq += __shfl_xor(sq, 32);
        if (quad == 0) {
            atomicAdd(&ls[col], s);
            atomicAdd(&lsq[col], sq);
        }
    }
    __syncthreads();
    float* dstp = sdst + (size_t)(blockIdx.x & (NSTRIPE - 1)) * 256;
    if (t < 128) atomicAdd(&dstp[t], ls[t]);
    else         atomicAdd(&dstp[t], lsq[t - 128]);
}

// ---- fused node heads: hA = relu(A@WA+bA), hB = relu(A@WB+bB) as bf16, striped stats ----
__global__ __launch_bounds__(256) void heads_kernel(
    const unsigned* __restrict__ AP,
    const ushortT* __restrict__ WAhi, const ushortT* __restrict__ WAlo,
    const float* __restrict__ bA, ushortT* __restrict__ hA, float* __restrict__ sdstA,
    const ushortT* __restrict__ WBhi, const ushortT* __restrict__ WBlo,
    const float* __restrict__ bB, ushortT* __restrict__ hB, float* __restrict__ sdstB,
    int M)
{
    __shared__ float lsA[DIM], lsqA[DIM], lsB[DIM], lsqB[DIM];
    int t = threadIdx.x;
    int wave = t >> 6, lane = t & 63, quad = lane >> 4, l16 = lane & 15;
    int m0 = blockIdx.x * 32;
    int cbase = wave * 32;

    if (t < DIM) { lsA[t] = 0.f; lsqA[t] = 0.f; lsB[t] = 0.f; lsqB[t] = 0.f; }
    __syncthreads();

    floatx4 accA[2][2], accB[2][2];
#pragma unroll
    for (int mt = 0; mt < 2; ++mt)
#pragma unroll
        for (int nt = 0; nt < 2; ++nt) {
            accA[mt][nt] = (floatx4){0.f, 0.f, 0.f, 0.f};
            accB[mt][nt] = (floatx4){0.f, 0.f, 0.f, 0.f};
        }

#pragma unroll
    for (int ks = 0; ks < 4; ++ks) {
        int k0 = ks * 32 + quad * 8;
        short8 bAhi[2], bAlo[2], bBhi[2], bBlo[2];
#pragma unroll
        for (int nt = 0; nt < 2; ++nt) {
            const size_t woff = (size_t)(cbase + nt * 16 + l16) * DIM + k0;
            bAhi[nt] = *(const short8*)(WAhi + woff);
            bAlo[nt] = *(const short8*)(WAlo + woff);
            bBhi[nt] = *(const short8*)(WBhi + woff);
            bBlo[nt] = *(const short8*)(WBlo + woff);
        }
#pragma unroll
        for (int mt = 0; mt < 2; ++mt) {
            int row = m0 + mt * 16 + l16;
            unsigned ap[8] = {0, 0, 0, 0, 0, 0, 0, 0};
            if (row < M) {
                *(uint4*)&ap[0] = *(const uint4*)(AP + (size_t)row * DIM + k0);
                *(uint4*)&ap[4] = *(const uint4*)(AP + (size_t)row * DIM + k0 + 4);
            }
            short8 ahi, alo;
            decode8(ap, ahi, alo);
#pragma unroll
            for (int nt = 0; nt < 2; ++nt) {
                accA[mt][nt] = __builtin_amdgcn_mfma_f32_16x16x32_bf16(ahi, bAhi[nt], accA[mt][nt], 0, 0, 0);
                accA[mt][nt] = __builtin_amdgcn_mfma_f32_16x16x32_bf16(alo, bAhi[nt], accA[mt][nt], 0, 0, 0);
                accA[mt][nt] = __builtin_amdgcn_mfma_f32_16x16x32_bf16(ahi, bAlo[nt], accA[mt][nt], 0, 0, 0);
                accB[mt][nt] = __builtin_amdgcn_mfma_f32_16x16x32_bf16(ahi, bBhi[nt], accB[mt][nt], 0, 0, 0);
                accB[mt][nt] = __builtin_amdgcn_mfma_f32_16x16x32_bf16(alo, bBhi[nt], accB[mt][nt], 0, 0, 0);
                accB[mt][nt] = __builtin_amdgcn_mfma_f32_16x16x32_bf16(ahi, bBlo[nt], accB[mt][nt], 0, 0, 0);
            }
        }
    }

#pragma unroll
    for (int nt = 0; nt < 2; ++nt) {
        int col = cbase + nt * 16 + l16;
        float bcA = bA[col], bcB = bB[col];
        float sA = 0.f, sqA = 0.f, sB = 0.f, sqB = 0.f;
#pragma unroll
        for (int mt = 0; mt < 2; ++mt)
#pragma unroll
            for (int r = 0; r < 4; ++r) {
                int gr = m0 + mt * 16 + quad * 4 + r;
                if (gr < M) {
                    size_t off = (size_t)gr * DIM + col;
                    float vA = fmaxf(accA[mt][nt][r] + bcA, 0.f);
                    float vB = fmaxf(accB[mt][nt][r] + bcB, 0.f);
                    hA[off] = f2bf(vA);
                    hB[off] = f2bf(vB);
                    sA += vA; sqA += vA * vA;
                    sB += vB; sqB += vB * vB;
                }
            }
        sA += __shfl_xor(sA, 16);  sA += __shfl_xor(sA, 32);
        sqA += __shfl_xor(sqA, 16); sqA += __shfl_xor(sqA, 32);
        sB += __shfl_xor(sB, 16);  sB += __shfl_xor(sB, 32);
        sqB += __shfl_xor(sqB, 16); sqB += __shfl_xor(sqB, 32);
        if (quad == 0) {
            atomicAdd(&lsA[col], sA);
            atomicAdd(&lsqA[col], sqA);
            atomicAdd(&lsB[col], sB);
            atomicAdd(&lsqB[col], sqB);
        }
    }
    __syncthreads();
    int stripe = blockIdx.x & (NSTRIPE - 1);
    float* dA = sdstA + (size_t)stripe * 256;
    float* dB = sdstB + (size_t)stripe * 256;
    if (t < 128) { atomicAdd(&dA[t], lsA[t]); atomicAdd(&dB[t], lsB[t]); }
    else         { atomicAdd(&dA[t], lsqA[t - 128]); atomicAdd(&dB[t], lsqB[t - 128]); }
}

// ---- generic split GEMM for graph heads (fp32 A, in-kernel decompose, direct stats) ----
__global__ __launch_bounds__(256) void gemm_graph_kernel(
    const float* __restrict__ A32,
    const ushortT* __restrict__ Whi, const ushortT* __restrict__ Wlo,
    const float* __restrict__ bias, float* __restrict__ C,
    float* __restrict__ ssum, float* __restrict__ ssq, int M)
{
    __shared__ float ls[DIM], lsq[DIM];
    int t     = threadIdx.x;
    int wave  = t >> 6;
    int lane  = t & 63;
    int quad  = lane >> 4;
    int l16   = lane & 15;
    int m0    = blockIdx.x * 64;
    int cbase = wave * 32;

    if (t < DIM) { ls[t] = 0.f; lsq[t] = 0.f; }
    __syncthreads();

    floatx4 acc[4][2];
#pragma unroll
    for (int mt = 0; mt < 4; ++mt)
#pragma unroll
        for (int nt = 0; nt < 2; ++nt)
            acc[mt][nt] = (floatx4){0.f, 0.f, 0.f, 0.f};

    for (int ks = 0; ks < 4; ++ks) {
        int k0 = ks * 32 + quad * 8;
        short8 bhi[2], blo[2];
#pragma unroll
        for (int nt = 0; nt < 2; ++nt) {
            const size_t woff = (size_t)(cbase + nt * 16 + l16) * DIM + k0;
            bhi[nt] = *(const short8*)(Whi + woff);
            blo[nt] = *(const short8*)(Wlo + woff);
        }
#pragma unroll
        for (int mt = 0; mt < 4; ++mt) {
            int row = m0 + mt * 16 + l16;
            short8 ahi = {0,0,0,0,0,0,0,0};
            short8 alo = {0,0,0,0,0,0,0,0};
            if (row < M) {
                float av[8];
                *(float4*)&av[0] = *(const float4*)(A32 + (size_t)row * DIM + k0);
                *(float4*)&av[4] = *(const float4*)(A32 + (size_t)row * DIM + k0 + 4);
#pragma unroll
                for (int j = 0; j < 8; ++j) {
                    ushortT hv = f2bf(av[j]);
                    ahi[j] = (short)hv;
                    alo[j] = (short)f2bf(av[j] - bf2f(hv));
                }
            }
#pragma unroll
            for (int nt = 0; nt < 2; ++nt) {
                acc[mt][nt] = __builtin_amdgcn_mfma_f32_16x16x32_bf16(ahi, bhi[nt], acc[mt][nt], 0, 0, 0);
                acc[mt][nt] = __builtin_amdgcn_mfma_f32_16x16x32_bf16(alo, bhi[nt], acc[mt][nt], 0, 0, 0);
                acc[mt][nt] = __builtin_amdgcn_mfma_f32_16x16x32_bf16(ahi, blo[nt], acc[mt][nt], 0, 0, 0);
            }
        }
    }

#pragma unroll
    for (int nt = 0; nt < 2; ++nt) {
        int col = cbase + nt * 16 + l16;
        float bcol = bias[col];
        float s = 0.f, sq = 0.f;
#pragma unroll
        for (int mt = 0; mt < 4; ++mt)
#pragma unroll
            for (int r = 0; r < 4; ++r) {
                int gr = m0 + mt * 16 + quad * 4 + r;
                if (gr < M) {
                    float v = fmaxf(acc[mt][nt][r] + bcol, 0.f);
                    C[(size_t)gr * DIM + col] = v;
                    s += v;
                    sq += v * v;
                }
            }
        s  += __shfl_xor(s, 16);  s  += __shfl_xor(s, 32);
        sq += __shfl_xor(sq, 16); sq += __shfl_xor(sq, 32);
        if (quad == 0) {
            atomicAdd(&ls[col], s);
            atomicAdd(&lsq[col], sq);
        }
    }
    __syncthreads();
    if (t < DIM) {
        atomicAdd(&ssum[t], ls[t]);
        atomicAdd(&ssq[t], lsq[t]);
    }
}

// ---- BN apply, fp32 in -> fp32 out ----
__global__ __launch_bounds__(256) void bn_apply_kernel(
    const float* __restrict__ R, float* __restrict__ O,
    const float* __restrict__ sums, const float* __restrict__ sqsums,
    const float* __restrict__ gamma, const float* __restrict__ beta, int M)
{
    int idx = blockIdx.x * 256 + threadIdx.x;
    if (idx >= M * 32) return;
    int c4 = idx & 31;
    float invM = 1.0f / (float)M;
    float4 v = ((const float4*)R)[idx];
    float o[4] = {v.x, v.y, v.z, v.w};
#pragma unroll
    for (int j = 0; j < 4; ++j) {
        int c = c4 * 4 + j;
        float m   = sums[c] * invM;
        float var = sqsums[c] * invM - m * m;
        float sc  = gamma[c] * rsqrtf(var + BN_EPS);
        o[j] = sc * (o[j] - m) + beta[c];
    }
    ((float4*)O)[idx] = make_float4(o[0], o[1], o[2], o[3]);
}

// ---- BN apply, bf16 in -> fp32 out ----
__global__ __launch_bounds__(256) void bn_apply_bf16_kernel(
    const ushortT* __restrict__ R, float* __restrict__ O,
    const float* __restrict__ sums, const float* __restrict__ sqsums,
    const float* __restrict__ gamma, const float* __restrict__ beta, int M)
{
    int idx = blockIdx.x * 256 + threadIdx.x; // over M*32 col-quads
    if (idx >= M * 32) return;
    int c4 = idx & 31;
    float invM = 1.0f / (float)M;
    uint2 u = ((const uint2*)R)[idx];
    float o[4] = {bflo(u.x), bfhi(u.x), bflo(u.y), bfhi(u.y)};
#pragma unroll
    for (int j = 0; j < 4; ++j) {
        int c = c4 * 4 + j;
        float m   = sums[c] * invM;
        float var = sqsums[c] * invM - m * m;
        float sc  = gamma[c] * rsqrtf(var + BN_EPS);
        o[j] = sc * (o[j] - m) + beta[c];
    }
    ((float4*)O)[idx] = make_float4(o[0], o[1], o[2], o[3]);
}

// ---- fused: w = sigmoid(bn(r)@sw+b); noisy = (1-w)*bn(r) packed; slots += w*bn(r) ----
__global__ __launch_bounds__(256) void weigh_split_kernel(
    const ushortT* __restrict__ R, const int* __restrict__ batch,
    const float* __restrict__ ssum, const float* __restrict__ ssq,
    const float* __restrict__ gamma, const float* __restrict__ beta,
    const float* __restrict__ sw_w, const float* __restrict__ sw_b,
    unsigned* __restrict__ noisyP, float* __restrict__ slots, int N, float invM)
{
    __shared__ float part[256];
    __shared__ float wsh[128];
    int t  = threadIdx.x;
    int r0 = blockIdx.x * 128;

    // phase A: per-row dot over 64 cols/thread
    {
        int row  = r0 + (t >> 1);
        int cs   = (t & 1) * 64;
        float d = 0.f;
        if (row < N) {
            for (int c = cs; c < cs + 64; c += 4) {
                uint2 u = *(const uint2*)(R + (size_t)row * DIM + c);
                float rv[4] = {bflo(u.x), bfhi(u.x), bflo(u.y), bfhi(u.y)};
                float4 sm = *(const float4*)(ssum + c);
                float4 sq = *(const float4*)(ssq + c);
                float4 gm = *(const float4*)(gamma + c);
                float4 bt = *(const float4*)(beta + c);
                float4 sw = *(const float4*)(sw_w + c);
                float m, sc;
                m = sm.x * invM; sc = gm.x * rsqrtf(sq.x * invM - m * m + BN_EPS);
                d += (sc * (rv[0] - m) + bt.x) * sw.x;
                m = sm.y * invM; sc = gm.y * rsqrtf(sq.y * invM - m * m + BN_EPS);
                d += (sc * (rv[1] - m) + bt.y) * sw.y;
                m = sm.z * invM; sc = gm.z * rsqrtf(sq.z * invM - m * m + BN_EPS);
                d += (sc * (rv[2] - m) + bt.z) * sw.z;
                m = sm.w * invM; sc = gm.w * rsqrtf(sq.w * invM - m * m + BN_EPS);
                d += (sc * (rv[3] - m) + bt.w) * sw.w;
            }
        }
        part[t] = d;
    }
    __syncthreads();
    if (t < 128) {
        float dd = part[2 * t] + part[2 * t + 1];
        wsh[t] = 1.0f / (1.0f + expf(-(dd + sw_b[0])));
    }
    __syncthreads();

    // phase B: split (segmented slots, sorted batch)
    int c    = t & 127;
    int half = t >> 7;
    int rend = r0 + 128;
    if (rend > N) rend = N;
    float m   = ssum[c] * invM;
    float var = ssq[c] * invM - m * m;
    float sc  = gamma[c] * rsqrtf(var + BN_EPS);
    float sh  = beta[c] - sc * m;
    int curg = -1;
    float acc = 0.f;
    for (int r = r0 + half; r < rend; r += 2) {
        float xv = sc * bf2f(R[(size_t)r * DIM + c]) + sh;
        float w  = wsh[r - r0];
        float nv = (1.f - w) * xv;
        ushortT hv = f2bf(nv);
        ushortT lv = f2bf(nv - bf2f(hv));
        noisyP[(size_t)r * DIM + c] = ((unsigned)hv << 16) | lv;
        int g = batch[r];
        if (g != curg) {
            if (curg >= 0) atomicAdd(&slots[(size_t)curg * DIM + c], acc);
            curg = g;
            acc = 0.f;
        }
        acc += w * xv;
    }
    if (curg >= 0) atomicAdd(&slots[(size_t)curg * DIM + c], acc);
}

extern "C" void kernel_launch(void* const* d_in, const int* in_sizes, int n_in,
                              void* d_out, int out_size, void* d_ws, size_t ws_size,
                              hipStream_t stream)
{
    const float* x      = (const float*)d_in[0];
    const int*   src    = (const int*)d_in[1];
    const int*   dst    = (const int*)d_in[2];
    const int*   batch  = (const int*)d_in[3];
    const float* cw1    = (const float*)d_in[5];
    const float* cb1    = (const float*)d_in[6];
    const float* cw2    = (const float*)d_in[7];
    const float* cb2    = (const float*)d_in[8];
    const float* bng    = (const float*)d_in[9];
    const float* bnb    = (const float*)d_in[10];
    const float* sw_w   = (const float*)d_in[11];
    const float* sw_b   = (const float*)d_in[12];
    const float* nmu_w  = (const float*)d_in[13];
    const float* nmu_b  = (const float*)d_in[14];
    const float* nlv_w  = (const float*)d_in[15];
    const float* nlv_b  = (const float*)d_in[16];
    const float* gmu_w  = (const float*)d_in[17];
    const float* gmu_b  = (const float*)d_in[18];
    const float* glv_w  = (const float*)d_in[19];
    const float* glv_b  = (const float*)d_in[20];
    const float* hgam   = (const float*)d_in[21];
    const float* hbet   = (const float*)d_in[22];

    const int N = in_sizes[0] / DIM;
    const int E = in_sizes[1];
    const int G = (out_size / DIM - 2 * N) / 2;

    float* out0 = (float*)d_out;
    float* out1 = out0 + (size_t)N * DIM;
    float* out2 = out1 + (size_t)N * DIM;
    float* out3 = out2 + (size_t)G * DIM;

    // ---- workspace layout ----
    char* wp = (char*)d_ws;
    auto alloc = [&](size_t bytes) {
        char* p = wp;
        wp += (bytes + 255) & ~(size_t)255;
        return p;
    };
    ushortT*  xbf   = (ushortT*)alloc((size_t)N * DIM * 2);  // layer-0 input; later hB
    ushortT*  rA    = (ushortT*)alloc((size_t)N * DIM * 2);  // layer ping; final r; later hA... (hA uses rB)
    ushortT*  rB    = (ushortT*)alloc((size_t)N * DIM * 2);  // layer pong
    unsigned* noisyP= (unsigned*)alloc((size_t)N * DIM * 4); // packed noisy; CSR temps overlay
    ushortT*  whi   = (ushortT*)alloc((size_t)10 * 16384 * 2);
    ushortT*  wlo   = (ushortT*)alloc((size_t)10 * 16384 * 2);
    float* slots    = (float*)alloc((size_t)G * DIM * 4);
    float* stats    = (float*)alloc((size_t)7 * 256 * 4);          // [sum|sq] x7
    float* sbuf     = (float*)alloc((size_t)5 * NSTRIPE * 256 * 4);// stripe bufs x5
    int* row_ptr    = (int*)alloc((size_t)(N + 2) * 4);
    int* eidx       = (int*)alloc((size_t)E * 4);
    // CSR temps overlay in noisyP (noisyP first written by weigh_split, long after CSR build)
    int* deg   = (int*)noisyP;
    int* iscan = deg + N;
    int* bsum  = iscan + N;
    int* cur   = bsum + 256;

    auto SS = [&](int i) { return stats + (size_t)i * 256; };
    auto SQ = [&](int i) { return stats + (size_t)i * 256 + 128; };
    auto SB = [&](int i) { return sbuf + (size_t)i * NSTRIPE * 256; };

    const int edge_blocks  = (E + 255) / 256;
    const int scan_blocks  = (N + 255) / 256;
    const int layer_blocks = (N + 31) / 32;
    const int g16_blocks   = (N * 16 + 255) / 256;
    const int g32_blocks   = (N * 32 + 255) / 256;
    const float invN = 1.0f / (float)N;

    hipMemsetAsync(stats, 0, (size_t)7 * 256 * 4, stream);
    hipMemsetAsync(sbuf, 0, (size_t)5 * NSTRIPE * 256 * 4, stream);
    hipMemsetAsync(slots, 0, (size_t)G * DIM * 4, stream);
    hipMemsetAsync(deg, 0, (size_t)N * 4, stream);

    convw_kernel<<<(10 * 16384) / 256, 256, 0, stream>>>(
        cw1, cw2, nmu_w, nlv_w, gmu_w, glv_w, whi, wlo);
    convx_kernel<<<g16_blocks, 256, 0, stream>>>(x, xbf, N * 16);

    hist_kernel<<<edge_blocks, 256, 0, stream>>>(dst, deg, E);
    scan1_kernel<<<scan_blocks, 256, 0, stream>>>(deg, iscan, bsum, N);
    scan2_kernel<<<1, 256, 0, stream>>>(bsum, scan_blocks);
    scan3_kernel<<<scan_blocks, 256, 0, stream>>>(iscan, bsum, deg, row_ptr, cur, N);
    fill_kernel<<<edge_blocks, 256, 0, stream>>>(src, dst, cur, eidx, E);

    // layers: l0 xbf->rA, l1 rA->rB, l2 rB->rA  (ping-pong: fused gather reads
    // random rows of the input plane, so in/out must differ)
    const ushortT* lin[3]  = {xbf, rA, rB};
    ushortT*       lout[3] = {rA, rB, rA};
    for (int l = 0; l < 3; ++l) {
        const float* sums_prev = (l == 0) ? nullptr : SS(l - 1);
        const float* sq_prev   = (l == 0) ? nullptr : SQ(l - 1);
        const float* g_prev    = (l == 0) ? nullptr : bng + (size_t)(l - 1) * DIM;
        const float* b_prev    = (l == 0) ? nullptr : bnb + (size_t)(l - 1) * DIM;
        layer_fused_kernel<<<layer_blocks, 256, 0, stream>>>(
            lin[l], row_ptr, eidx,
            sums_prev, sq_prev, g_prev, b_prev,
            whi + (size_t)l * 16384, wlo + (size_t)l * 16384, cb1 + (size_t)l * DIM,
            whi + (size_t)(3 + l) * 16384, wlo + (size_t)(3 + l) * 16384, cb2 + (size_t)l * DIM,
            lout[l], SB(l), N, invN);
        merge_stats_kernel<<<1, 256, 0, stream>>>(SB(l), SS(l));
    }
    ushortT* rfin = rA;   // layer-2 output
    ushortT* hA   = rB;   // free after layer 2
    ushortT* hB   = xbf;  // free after layer 0

    // fused weigh+split: BN(layer2) folded in
    weigh_split_kernel<<<(N + 127) / 128, 256, 0, stream>>>(
        rfin, batch, SS(2), SQ(2), bng + 2 * DIM, bnb + 2 * DIM,
        sw_w, sw_b, noisyP, slots, N, invN);

    // fused node heads -> bf16 pre-BN planes + striped stats
    heads_kernel<<<layer_blocks, 256, 0, stream>>>(
        noisyP,
        whi + (size_t)6 * 16384, wlo + (size_t)6 * 16384, nmu_b, hA, SB(3),
        whi + (size_t)7 * 16384, wlo + (size_t)7 * 16384, nlv_b, hB, SB(4), N);
    merge_stats_kernel<<<1, 256, 0, stream>>>(SB(3), SS(3));
    merge_stats_kernel<<<1, 256, 0, stream>>>(SB(4), SS(4));
    bn_apply_bf16_kernel<<<g32_blocks, 256, 0, stream>>>(
        hA, out0, SS(3), SQ(3), hgam + 0 * DIM, hbet + 0 * DIM, N);
    bn_apply_bf16_kernel<<<g32_blocks, 256, 0, stream>>>(
        hB, out1, SS(4), SQ(4), hgam + 1 * DIM, hbet + 1 * DIM, N);

    // graph heads (tiny)
    const int gemm_blocks_G = (G + 63) / 64;
    gemm_graph_kernel<<<gemm_blocks_G, 256, 0, stream>>>(
        slots, whi + (size_t)8 * 16384, wlo + (size_t)8 * 16384,
        gmu_b, out2, SS(5), SQ(5), G);
    gemm_graph_kernel<<<gemm_blocks_G, 256, 0, stream>>>(
        slots, whi + (size_t)9 * 16384, wlo + (size_t)9 * 16384,
        glv_b, out3, SS(6), SQ(6), G);
    bn_apply_kernel<<<(G * 32 + 255) / 256, 256, 0, stream>>>(
        out2, out2, SS(5), SQ(5), hgam + 2 * DIM, hbet + 2 * DIM, G);
    bn_apply_kernel<<<(G * 32 + 255) / 256, 256, 0, stream>>>(
        out3, out3, SS(6), SQ(6), hgam + 3 * DIM, hbet + 3 * DIM, G);
}

// Round 10
// 506.804 us; speedup vs baseline: 7.6274x; 1.0649x over previous
//
#include <hip/hip_runtime.h>
#include <hip/hip_bf16.h>

#define DIM 128
#define BN_EPS 1e-5f
#define NSTRIPE 32

typedef unsigned short ushortT;
typedef __attribute__((ext_vector_type(8))) short short8;
typedef __attribute__((ext_vector_type(4))) float floatx4;

__device__ __forceinline__ float bflo(unsigned u) { return __uint_as_float(u << 16); }
__device__ __forceinline__ float bfhi(unsigned u) { return __uint_as_float(u & 0xffff0000u); }
__device__ __forceinline__ float bf2f(ushortT h) { return __uint_as_float(((unsigned)h) << 16); }
__device__ __forceinline__ ushortT f2bf(float f) {
    unsigned x = __float_as_uint(f);
    unsigned r = (x + 0x7fff + ((x >> 16) & 1)) >> 16;
    return (ushortT)r;
}
__device__ __forceinline__ void decode8(const unsigned* ap, short8& hi, short8& lo) {
#pragma unroll
    for (int j = 0; j < 8; ++j) {
        hi[j] = (short)(ap[j] >> 16);
        lo[j] = (short)(ap[j] & 0xffffu);
    }
}
__device__ __forceinline__ void acc8(float* a, uint4 v) {
    a[0] += bflo(v.x); a[1] += bfhi(v.x);
    a[2] += bflo(v.y); a[3] += bfhi(v.y);
    a[4] += bflo(v.z); a[5] += bfhi(v.z);
    a[6] += bflo(v.w); a[7] += bfhi(v.w);
}

// ---------------- CSR build ----------------
__global__ __launch_bounds__(256) void hist_kernel(
    const int* __restrict__ dst, int* __restrict__ deg, int E)
{
    int e = blockIdx.x * 256 + threadIdx.x;
    if (e < E) atomicAdd(&deg[dst[e]], 1);
}

__global__ __launch_bounds__(256) void scan1_kernel(
    const int* __restrict__ deg, int* __restrict__ iscan,
    int* __restrict__ bsum, int N)
{
    __shared__ int s[256];
    int t = threadIdx.x;
    int i = blockIdx.x * 256 + t;
    int v = (i < N) ? deg[i] : 0;
    s[t] = v;
    __syncthreads();
#pragma unroll
    for (int off = 1; off < 256; off <<= 1) {
        int u = (t >= off) ? s[t - off] : 0;
        __syncthreads();
        s[t] += u;
        __syncthreads();
    }
    if (i < N) iscan[i] = s[t];
    if (t == 255) bsum[blockIdx.x] = s[255];
}

__global__ __launch_bounds__(256) void scan2_kernel(int* __restrict__ bsum, int nb)
{
    __shared__ int s[256];
    int t = threadIdx.x;
    int v = (t < nb) ? bsum[t] : 0;
    s[t] = v;
    __syncthreads();
#pragma unroll
    for (int off = 1; off < 256; off <<= 1) {
        int u = (t >= off) ? s[t - off] : 0;
        __syncthreads();
        s[t] += u;
        __syncthreads();
    }
    if (t < nb) bsum[t] = s[t] - v; // exclusive
}

__global__ __launch_bounds__(256) void scan3_kernel(
    const int* __restrict__ iscan, const int* __restrict__ bsum,
    const int* __restrict__ deg, int* __restrict__ row_ptr,
    int* __restrict__ cur, int N)
{
    int i = blockIdx.x * 256 + threadIdx.x;
    if (i < N) {
        int inc = iscan[i] + bsum[i >> 8];
        row_ptr[i + 1] = inc;
        cur[i] = inc - deg[i];
    }
    if (i == 0) row_ptr[0] = 0;
}

__global__ __launch_bounds__(256) void fill_kernel(
    const int* __restrict__ src, const int* __restrict__ dst,
    int* __restrict__ cur, int* __restrict__ eidx, int E)
{
    int e = blockIdx.x * 256 + threadIdx.x;
    if (e < E) {
        int pos = atomicAdd(&cur[dst[e]], 1);
        eidx[pos] = src[e];
    }
}

// ---- weights -> transposed bf16 hi/lo planes. 0-2: cw1, 3-5: cw2, 6:nmu,7:nlv,8:gmu,9:glv ----
__global__ __launch_bounds__(256) void convw_kernel(
    const float* __restrict__ cw1, const float* __restrict__ cw2,
    const float* __restrict__ nmu, const float* __restrict__ nlv,
    const float* __restrict__ gmu, const float* __restrict__ glv,
    ushortT* __restrict__ whi, ushortT* __restrict__ wlo)
{
    int tid = blockIdx.x * 256 + threadIdx.x; // 10*16384
    int mat = tid >> 14;
    int i   = tid & 16383;
    int n = i >> 7, k = i & 127;
    const float* Wm = (mat < 3) ? cw1 + (size_t)mat * 16384
                    : (mat < 6) ? cw2 + (size_t)(mat - 3) * 16384
                    : (mat == 6) ? nmu : (mat == 7) ? nlv
                    : (mat == 8) ? gmu : glv;
    float w = Wm[k * DIM + n];
    ushortT h = f2bf(w);
    whi[(size_t)mat * 16384 + i] = h;
    wlo[(size_t)mat * 16384 + i] = f2bf(w - bf2f(h));
}

// ---- x fp32 -> bf16 plane ----
__global__ __launch_bounds__(256) void convx_kernel(
    const float* __restrict__ x, ushortT* __restrict__ xb, int n8)
{
    int i = blockIdx.x * 256 + threadIdx.x;
    if (i >= n8) return;
    const float4* xp = (const float4*)x;
    float4 a = xp[2 * i], b = xp[2 * i + 1];
    uint4 o;
    o.x = (unsigned)f2bf(a.x) | ((unsigned)f2bf(a.y) << 16);
    o.y = (unsigned)f2bf(a.z) | ((unsigned)f2bf(a.w) << 16);
    o.z = (unsigned)f2bf(b.x) | ((unsigned)f2bf(b.y) << 16);
    o.w = (unsigned)f2bf(b.z) | ((unsigned)f2bf(b.w) << 16);
    ((uint4*)xb)[i] = o;
}

// ---- merge 32 stat stripes -> final [256] (sum | sq) ----
__global__ __launch_bounds__(256) void merge_stats_kernel(
    const float* __restrict__ sbuf, float* __restrict__ out)
{
    int t = threadIdx.x;
    float s = 0.f;
#pragma unroll
    for (int i = 0; i < NSTRIPE; ++i) s += sbuf[i * 256 + t];
    out[t] = s;
}

// ---- fused GIN layer: gather(CSR, unrolled x4)+BNaffine -> LDS -> GEMM1 -> LDS -> GEMM2 ----
__global__ __launch_bounds__(256) void layer_fused_kernel(
    const ushortT* __restrict__ Xb, const int* __restrict__ row_ptr,
    const int* __restrict__ eidx,
    const float* __restrict__ ssum, const float* __restrict__ ssq,
    const float* __restrict__ gamma, const float* __restrict__ beta,
    const ushortT* __restrict__ W1hi, const ushortT* __restrict__ W1lo,
    const float* __restrict__ b1,
    const ushortT* __restrict__ W2hi, const ushortT* __restrict__ W2lo,
    const float* __restrict__ b2,
    ushortT* __restrict__ rout, float* __restrict__ sdst,
    int M, float invM)
{
    __shared__ unsigned As[32][DIM + 4];
    __shared__ float ls[DIM], lsq[DIM];
    int t = threadIdx.x;
    int wave = t >> 6, lane = t & 63, quad = lane >> 4, l16 = lane & 15;
    int m0 = blockIdx.x * 32;

    // ---- gather phase: 8 lanes per node, 16 cols each; edge loop unrolled x4 ----
    {
        int nloc = t >> 3;
        int c0   = (t & 7) * 16;
        int node = m0 + nloc;
        float acc[16];
#pragma unroll
        for (int j = 0; j < 16; ++j) acc[j] = 0.f;
        if (node < M) {
            int b = row_ptr[node];
            int e = row_ptr[node + 1];
            const ushortT* xrow = Xb + (size_t)node * DIM + c0;
            acc8(&acc[0], *(const uint4*)(xrow));
            acc8(&acc[8], *(const uint4*)(xrow + 8));
            int i = b;
            for (; i + 4 <= e; i += 4) {
                int s0 = eidx[i], s1 = eidx[i + 1], s2 = eidx[i + 2], s3 = eidx[i + 3];
                const ushortT* p0 = Xb + (size_t)s0 * DIM + c0;
                const ushortT* p1 = Xb + (size_t)s1 * DIM + c0;
                const ushortT* p2 = Xb + (size_t)s2 * DIM + c0;
                const ushortT* p3 = Xb + (size_t)s3 * DIM + c0;
                uint4 v00 = *(const uint4*)(p0), v01 = *(const uint4*)(p0 + 8);
                uint4 v10 = *(const uint4*)(p1), v11 = *(const uint4*)(p1 + 8);
                uint4 v20 = *(const uint4*)(p2), v21 = *(const uint4*)(p2 + 8);
                uint4 v30 = *(const uint4*)(p3), v31 = *(const uint4*)(p3 + 8);
                acc8(&acc[0], v00); acc8(&acc[8], v01);
                acc8(&acc[0], v10); acc8(&acc[8], v11);
                acc8(&acc[0], v20); acc8(&acc[8], v21);
                acc8(&acc[0], v30); acc8(&acc[8], v31);
            }
            for (; i < e; ++i) {
                const ushortT* sp = Xb + (size_t)eidx[i] * DIM + c0;
                acc8(&acc[0], *(const uint4*)(sp));
                acc8(&acc[8], *(const uint4*)(sp + 8));
            }
            if (ssum) {
                float cnt = (float)(e - b + 1);
#pragma unroll
                for (int jq = 0; jq < 4; ++jq) {
                    int c = c0 + jq * 4;
                    float4 sm = *(const float4*)(ssum + c);
                    float4 sq = *(const float4*)(ssq + c);
                    float4 gm = *(const float4*)(gamma + c);
                    float4 bt = *(const float4*)(beta + c);
                    float m, sc;
                    m = sm.x * invM; sc = gm.x * rsqrtf(sq.x * invM - m * m + BN_EPS);
                    acc[jq * 4 + 0] = sc * acc[jq * 4 + 0] + cnt * (bt.x - sc * m);
                    m = sm.y * invM; sc = gm.y * rsqrtf(sq.y * invM - m * m + BN_EPS);
                    acc[jq * 4 + 1] = sc * acc[jq * 4 + 1] + cnt * (bt.y - sc * m);
                    m = sm.z * invM; sc = gm.z * rsqrtf(sq.z * invM - m * m + BN_EPS);
                    acc[jq * 4 + 2] = sc * acc[jq * 4 + 2] + cnt * (bt.z - sc * m);
                    m = sm.w * invM; sc = gm.w * rsqrtf(sq.w * invM - m * m + BN_EPS);
                    acc[jq * 4 + 3] = sc * acc[jq * 4 + 3] + cnt * (bt.w - sc * m);
                }
            }
        }
        unsigned pk[16];
#pragma unroll
        for (int j = 0; j < 16; ++j) {
            ushortT h = f2bf(acc[j]);
            ushortT l = f2bf(acc[j] - bf2f(h));
            pk[j] = ((unsigned)h << 16) | l;
        }
#pragma unroll
        for (int j4 = 0; j4 < 4; ++j4)
            *(uint4*)&As[nloc][c0 + j4 * 4] = *(uint4*)&pk[j4 * 4];
    }
    if (t < DIM) { ls[t] = 0.f; lsq[t] = 0.f; }
    __syncthreads();

    int cbase = wave * 32;
    floatx4 acc[2][2];
#pragma unroll
    for (int mt = 0; mt < 2; ++mt)
#pragma unroll
        for (int nt = 0; nt < 2; ++nt)
            acc[mt][nt] = (floatx4){0.f, 0.f, 0.f, 0.f};

    // ---- GEMM1: h1 = A @ W1, A from LDS ----
#pragma unroll
    for (int ks = 0; ks < 4; ++ks) {
        int k0 = ks * 32 + quad * 8;
        short8 bhi[2], blo[2];
#pragma unroll
        for (int nt = 0; nt < 2; ++nt) {
            const size_t woff = (size_t)(cbase + nt * 16 + l16) * DIM + k0;
            bhi[nt] = *(const short8*)(W1hi + woff);
            blo[nt] = *(const short8*)(W1lo + woff);
        }
#pragma unroll
        for (int mt = 0; mt < 2; ++mt) {
            int lr = mt * 16 + l16;
            unsigned ap[8];
            *(uint4*)&ap[0] = *(const uint4*)&As[lr][k0];
            *(uint4*)&ap[4] = *(const uint4*)&As[lr][k0 + 4];
            short8 ahi, alo;
            decode8(ap, ahi, alo);
#pragma unroll
            for (int nt = 0; nt < 2; ++nt) {
                acc[mt][nt] = __builtin_amdgcn_mfma_f32_16x16x32_bf16(ahi, bhi[nt], acc[mt][nt], 0, 0, 0);
                acc[mt][nt] = __builtin_amdgcn_mfma_f32_16x16x32_bf16(alo, bhi[nt], acc[mt][nt], 0, 0, 0);
                acc[mt][nt] = __builtin_amdgcn_mfma_f32_16x16x32_bf16(ahi, blo[nt], acc[mt][nt], 0, 0, 0);
            }
        }
    }
    __syncthreads(); // all waves done reading As as A-input

    // epilogue 1 -> LDS (packed, reuse As)
#pragma unroll
    for (int nt = 0; nt < 2; ++nt) {
        int col = cbase + nt * 16 + l16;
        float bcol = b1[col];
#pragma unroll
        for (int mt = 0; mt < 2; ++mt)
#pragma unroll
            for (int r = 0; r < 4; ++r) {
                int lr = mt * 16 + quad * 4 + r;
                float v = fmaxf(acc[mt][nt][r] + bcol, 0.f);
                ushortT hv = f2bf(v);
                ushortT lv = f2bf(v - bf2f(hv));
                As[lr][col] = ((unsigned)hv << 16) | lv;
            }
    }
    __syncthreads();

    // ---- GEMM2: r = h1 @ W2 ----
#pragma unroll
    for (int mt = 0; mt < 2; ++mt)
#pragma unroll
        for (int nt = 0; nt < 2; ++nt)
            acc[mt][nt] = (floatx4){0.f, 0.f, 0.f, 0.f};

#pragma unroll
    for (int ks = 0; ks < 4; ++ks) {
        int k0 = ks * 32 + quad * 8;
        short8 bhi[2], blo[2];
#pragma unroll
        for (int nt = 0; nt < 2; ++nt) {
            const size_t woff = (size_t)(cbase + nt * 16 + l16) * DIM + k0;
            bhi[nt] = *(const short8*)(W2hi + woff);
            blo[nt] = *(const short8*)(W2lo + woff);
        }
#pragma unroll
        for (int mt = 0; mt < 2; ++mt) {
            int lr = mt * 16 + l16;
            unsigned ap[8];
            *(uint4*)&ap[0] = *(const uint4*)&As[lr][k0];
            *(uint4*)&ap[4] = *(const uint4*)&As[lr][k0 + 4];
            short8 ahi, alo;
            decode8(ap, ahi, alo);
#pragma unroll
            for (int nt = 0; nt < 2; ++nt) {
                acc[mt][nt] = __builtin_amdgcn_mfma_f32_16x16x32_bf16(ahi, bhi[nt], acc[mt][nt], 0, 0, 0);
                acc[mt][nt] = __builtin_amdgcn_mfma_f32_16x16x32_bf16(alo, bhi[nt], acc[mt][nt], 0, 0, 0);
                acc[mt][nt] = __builtin_amdgcn_mfma_f32_16x16x32_bf16(ahi, blo[nt], acc[mt][nt], 0, 0, 0);
            }
        }
    }
    // epilogue 2: bf16 out + striped stats
#pragma unroll
    for (int nt = 0; nt < 2; ++nt) {
        int col = cbase + nt * 16 + l16;
        float bcol = b2[col];
        float s = 0.f, sq = 0.f;
#pragma unroll
        for (int mt = 0; mt < 2; ++mt)
#pragma unroll
            for (int r = 0; r < 4; ++r) {
                int gr = m0 + mt * 16 + quad * 4 + r;
                if (gr < M) {
                    float v = fmaxf(acc[mt][nt][r] + bcol, 0.f);
                    rout[(size_t)gr * DIM + col] = f2bf(v);
                    s += v;
                    sq += v * v;
                }
            }
        s  += __shfl_xor(s, 16);  s  += __shfl_xor(s, 32);
        sq += __shfl_xor(sq, 16); sq += __shfl_xor(sq, 32);
        if (quad == 0) {
            atomicAdd(&ls[col], s);
            atomicAdd(&lsq[col], sq);
        }
    }
    __syncthreads();
    float* dstp = sdst + (size_t)(blockIdx.x & (NSTRIPE - 1)) * 256;
    if (t < 128) atomicAdd(&dstp[t], ls[t]);
    else         atomicAdd(&dstp[t], lsq[t - 128]);
}

// ---- fused node heads, 64-row tiles: hA = relu(A@WA+bA), hB = relu(A@WB+bB) bf16 + stats ----
__global__ __launch_bounds__(256) void heads_kernel(
    const unsigned* __restrict__ AP,
    const ushortT* __restrict__ WAhi, const ushortT* __restrict__ WAlo,
    const float* __restrict__ bA, ushortT* __restrict__ hA, float* __restrict__ sdstA,
    const ushortT* __restrict__ WBhi, const ushortT* __restrict__ WBlo,
    const float* __restrict__ bB, ushortT* __restrict__ hB, float* __restrict__ sdstB,
    int M)
{
    __shared__ float lsA[DIM], lsqA[DIM], lsB[DIM], lsqB[DIM];
    int t = threadIdx.x;
    int wave = t >> 6, lane = t & 63, quad = lane >> 4, l16 = lane & 15;
    int m0 = blockIdx.x * 64;
    int cbase = wave * 32;

    if (t < DIM) { lsA[t] = 0.f; lsqA[t] = 0.f; lsB[t] = 0.f; lsqB[t] = 0.f; }
    __syncthreads();

    floatx4 accA[4][2], accB[4][2];
#pragma unroll
    for (int mt = 0; mt < 4; ++mt)
#pragma unroll
        for (int nt = 0; nt < 2; ++nt) {
            accA[mt][nt] = (floatx4){0.f, 0.f, 0.f, 0.f};
            accB[mt][nt] = (floatx4){0.f, 0.f, 0.f, 0.f};
        }

    for (int ks = 0; ks < 4; ++ks) {
        int k0 = ks * 32 + quad * 8;
        short8 bAhi[2], bAlo[2], bBhi[2], bBlo[2];
#pragma unroll
        for (int nt = 0; nt < 2; ++nt) {
            const size_t woff = (size_t)(cbase + nt * 16 + l16) * DIM + k0;
            bAhi[nt] = *(const short8*)(WAhi + woff);
            bAlo[nt] = *(const short8*)(WAlo + woff);
            bBhi[nt] = *(const short8*)(WBhi + woff);
            bBlo[nt] = *(const short8*)(WBlo + woff);
        }
#pragma unroll
        for (int mt = 0; mt < 4; ++mt) {
            int row = m0 + mt * 16 + l16;
            unsigned ap[8] = {0, 0, 0, 0, 0, 0, 0, 0};
            if (row < M) {
                *(uint4*)&ap[0] = *(const uint4*)(AP + (size_t)row * DIM + k0);
                *(uint4*)&ap[4] = *(const uint4*)(AP + (size_t)row * DIM + k0 + 4);
            }
            short8 ahi, alo;
            decode8(ap, ahi, alo);
#pragma unroll
            for (int nt = 0; nt < 2; ++nt) {
                accA[mt][nt] = __builtin_amdgcn_mfma_f32_16x16x32_bf16(ahi, bAhi[nt], accA[mt][nt], 0, 0, 0);
                accA[mt][nt] = __builtin_amdgcn_mfma_f32_16x16x32_bf16(alo, bAhi[nt], accA[mt][nt], 0, 0, 0);
                accA[mt][nt] = __builtin_amdgcn_mfma_f32_16x16x32_bf16(ahi, bAlo[nt], accA[mt][nt], 0, 0, 0);
                accB[mt][nt] = __builtin_amdgcn_mfma_f32_16x16x32_bf16(ahi, bBhi[nt], accB[mt][nt], 0, 0, 0);
                accB[mt][nt] = __builtin_amdgcn_mfma_f32_16x16x32_bf16(alo, bBhi[nt], accB[mt][nt], 0, 0, 0);
                accB[mt][nt] = __builtin_amdgcn_mfma_f32_16x16x32_bf16(ahi, bBlo[nt], accB[mt][nt], 0, 0, 0);
            }
        }
    }

#pragma unroll
    for (int nt = 0; nt < 2; ++nt) {
        int col = cbase + nt * 16 + l16;
        float bcA = bA[col], bcB = bB[col];
        float sA = 0.f, sqA = 0.f, sB = 0.f, sqB = 0.f;
#pragma unroll
        for (int mt = 0; mt < 4; ++mt)
#pragma unroll
            for (int r = 0; r < 4; ++r) {
                int gr = m0 + mt * 16 + quad * 4 + r;
                if (gr < M) {
                    size_t off = (size_t)gr * DIM + col;
                    float vA = fmaxf(accA[mt][nt][r] + bcA, 0.f);
                    float vB = fmaxf(accB[mt][nt][r] + bcB, 0.f);
                    hA[off] = f2bf(vA);
                    hB[off] = f2bf(vB);
                    sA += vA; sqA += vA * vA;
                    sB += vB; sqB += vB * vB;
                }
            }
        sA += __shfl_xor(sA, 16);  sA += __shfl_xor(sA, 32);
        sqA += __shfl_xor(sqA, 16); sqA += __shfl_xor(sqA, 32);
        sB += __shfl_xor(sB, 16);  sB += __shfl_xor(sB, 32);
        sqB += __shfl_xor(sqB, 16); sqB += __shfl_xor(sqB, 32);
        if (quad == 0) {
            atomicAdd(&lsA[col], sA);
            atomicAdd(&lsqA[col], sqA);
            atomicAdd(&lsB[col], sB);
            atomicAdd(&lsqB[col], sqB);
        }
    }
    __syncthreads();
    int stripe = blockIdx.x & (NSTRIPE - 1);
    float* dA = sdstA + (size_t)stripe * 256;
    float* dB = sdstB + (size_t)stripe * 256;
    if (t < 128) { atomicAdd(&dA[t], lsA[t]); atomicAdd(&dB[t], lsB[t]); }
    else         { atomicAdd(&dA[t], lsqA[t - 128]); atomicAdd(&dB[t], lsqB[t - 128]); }
}

// ---- generic split GEMM for graph heads (fp32 A, in-kernel decompose, direct stats) ----
__global__ __launch_bounds__(256) void gemm_graph_kernel(
    const float* __restrict__ A32,
    const ushortT* __restrict__ Whi, const ushortT* __restrict__ Wlo,
    const float* __restrict__ bias, float* __restrict__ C,
    float* __restrict__ ssum, float* __restrict__ ssq, int M)
{
    __shared__ float ls[DIM], lsq[DIM];
    int t     = threadIdx.x;
    int wave  = t >> 6;
    int lane  = t & 63;
    int quad  = lane >> 4;
    int l16   = lane & 15;
    int m0    = blockIdx.x * 64;
    int cbase = wave * 32;

    if (t < DIM) { ls[t] = 0.f; lsq[t] = 0.f; }
    __syncthreads();

    floatx4 acc[4][2];
#pragma unroll
    for (int mt = 0; mt < 4; ++mt)
#pragma unroll
        for (int nt = 0; nt < 2; ++nt)
            acc[mt][nt] = (floatx4){0.f, 0.f, 0.f, 0.f};

    for (int ks = 0; ks < 4; ++ks) {
        int k0 = ks * 32 + quad * 8;
        short8 bhi[2], blo[2];
#pragma unroll
        for (int nt = 0; nt < 2; ++nt) {
            const size_t woff = (size_t)(cbase + nt * 16 + l16) * DIM + k0;
            bhi[nt] = *(const short8*)(Whi + woff);
            blo[nt] = *(const short8*)(Wlo + woff);
        }
#pragma unroll
        for (int mt = 0; mt < 4; ++mt) {
            int row = m0 + mt * 16 + l16;
            short8 ahi = {0,0,0,0,0,0,0,0};
            short8 alo = {0,0,0,0,0,0,0,0};
            if (row < M) {
                float av[8];
                *(float4*)&av[0] = *(const float4*)(A32 + (size_t)row * DIM + k0);
                *(float4*)&av[4] = *(const float4*)(A32 + (size_t)row * DIM + k0 + 4);
#pragma unroll
                for (int j = 0; j < 8; ++j) {
                    ushortT hv = f2bf(av[j]);
                    ahi[j] = (short)hv;
                    alo[j] = (short)f2bf(av[j] - bf2f(hv));
                }
            }
#pragma unroll
            for (int nt = 0; nt < 2; ++nt) {
                acc[mt][nt] = __builtin_amdgcn_mfma_f32_16x16x32_bf16(ahi, bhi[nt], acc[mt][nt], 0, 0, 0);
                acc[mt][nt] = __builtin_amdgcn_mfma_f32_16x16x32_bf16(alo, bhi[nt], acc[mt][nt], 0, 0, 0);
                acc[mt][nt] = __builtin_amdgcn_mfma_f32_16x16x32_bf16(ahi, blo[nt], acc[mt][nt], 0, 0, 0);
            }
        }
    }

#pragma unroll
    for (int nt = 0; nt < 2; ++nt) {
        int col = cbase + nt * 16 + l16;
        float bcol = bias[col];
        float s = 0.f, sq = 0.f;
#pragma unroll
        for (int mt = 0; mt < 4; ++mt)
#pragma unroll
            for (int r = 0; r < 4; ++r) {
                int gr = m0 + mt * 16 + quad * 4 + r;
                if (gr < M) {
                    float v = fmaxf(acc[mt][nt][r] + bcol, 0.f);
                    C[(size_t)gr * DIM + col] = v;
                    s += v;
                    sq += v * v;
                }
            }
        s  += __shfl_xor(s, 16);  s  += __shfl_xor(s, 32);
        sq += __shfl_xor(sq, 16); sq += __shfl_xor(sq, 32);
        if (quad == 0) {
            atomicAdd(&ls[col], s);
            atomicAdd(&lsq[col], sq);
        }
    }
    __syncthreads();
    if (t < DIM) {
        atomicAdd(&ssum[t], ls[t]);
        atomicAdd(&ssq[t], lsq[t]);
    }
}

// ---- BN apply, fp32 in -> fp32 out ----
__global__ __launch_bounds__(256) void bn_apply_kernel(
    const float* __restrict__ R, float* __restrict__ O,
    const float* __restrict__ sums, const float* __restrict__ sqsums,
    const float* __restrict__ gamma, const float* __restrict__ beta, int M)
{
    int idx = blockIdx.x * 256 + threadIdx.x;
    if (idx >= M * 32) return;
    int c4 = idx & 31;
    float invM = 1.0f / (float)M;
    float4 v = ((const float4*)R)[idx];
    float o[4] = {v.x, v.y, v.z, v.w};
#pragma unroll
    for (int j = 0; j < 4; ++j) {
        int c = c4 * 4 + j;
        float m   = sums[c] * invM;
        float var = sqsums[c] * invM - m * m;
        float sc  = gamma[c] * rsqrtf(var + BN_EPS);
        o[j] = sc * (o[j] - m) + beta[c];
    }
    ((float4*)O)[idx] = make_float4(o[0], o[1], o[2], o[3]);
}

// ---- BN apply, bf16 in -> fp32 out ----
__global__ __launch_bounds__(256) void bn_apply_bf16_kernel(
    const ushortT* __restrict__ R, float* __restrict__ O,
    const float* __restrict__ sums, const float* __restrict__ sqsums,
    const float* __restrict__ gamma, const float* __restrict__ beta, int M)
{
    int idx = blockIdx.x * 256 + threadIdx.x; // over M*32 col-quads
    if (idx >= M * 32) return;
    int c4 = idx & 31;
    float invM = 1.0f / (float)M;
    uint2 u = ((const uint2*)R)[idx];
    float o[4] = {bflo(u.x), bfhi(u.x), bflo(u.y), bfhi(u.y)};
#pragma unroll
    for (int j = 0; j < 4; ++j) {
        int c = c4 * 4 + j;
        float m   = sums[c] * invM;
        float var = sqsums[c] * invM - m * m;
        float sc  = gamma[c] * rsqrtf(var + BN_EPS);
        o[j] = sc * (o[j] - m) + beta[c];
    }
    ((float4*)O)[idx] = make_float4(o[0], o[1], o[2], o[3]);
}

// ---- fused: w = sigmoid(bn(r)@sw+b); noisy = (1-w)*bn(r) packed; slots += w*bn(r) ----
__global__ __launch_bounds__(256) void weigh_split_kernel(
    const ushortT* __restrict__ R, const int* __restrict__ batch,
    const float* __restrict__ ssum, const float* __restrict__ ssq,
    const float* __restrict__ gamma, const float* __restrict__ beta,
    const float* __restrict__ sw_w, const float* __restrict__ sw_b,
    unsigned* __restrict__ noisyP, float* __restrict__ slots, int N, float invM)
{
    __shared__ float part[256];
    __shared__ float wsh[128];
    int t  = threadIdx.x;
    int r0 = blockIdx.x * 128;

    // phase A: per-row dot over 64 cols/thread
    {
        int row  = r0 + (t >> 1);
        int cs   = (t & 1) * 64;
        float d = 0.f;
        if (row < N) {
            for (int c = cs; c < cs + 64; c += 4) {
                uint2 u = *(const uint2*)(R + (size_t)row * DIM + c);
                float rv[4] = {bflo(u.x), bfhi(u.x), bflo(u.y), bfhi(u.y)};
                float4 sm = *(const float4*)(ssum + c);
                float4 sq = *(const float4*)(ssq + c);
                float4 gm = *(const float4*)(gamma + c);
                float4 bt = *(const float4*)(beta + c);
                float4 sw = *(const float4*)(sw_w + c);
                float m, sc;
                m = sm.x * invM; sc = gm.x * rsqrtf(sq.x * invM - m * m + BN_EPS);
                d += (sc * (rv[0] - m) + bt.x) * sw.x;
                m = sm.y * invM; sc = gm.y * rsqrtf(sq.y * invM - m * m + BN_EPS);
                d += (sc * (rv[1] - m) + bt.y) * sw.y;
                m = sm.z * invM; sc = gm.z * rsqrtf(sq.z * invM - m * m + BN_EPS);
                d += (sc * (rv[2] - m) + bt.z) * sw.z;
                m = sm.w * invM; sc = gm.w * rsqrtf(sq.w * invM - m * m + BN_EPS);
                d += (sc * (rv[3] - m) + bt.w) * sw.w;
            }
        }
        part[t] = d;
    }
    __syncthreads();
    if (t < 128) {
        float dd = part[2 * t] + part[2 * t + 1];
        wsh[t] = 1.0f / (1.0f + expf(-(dd + sw_b[0])));
    }
    __syncthreads();

    // phase B: split (segmented slots, sorted batch)
    int c    = t & 127;
    int half = t >> 7;
    int rend = r0 + 128;
    if (rend > N) rend = N;
    float m   = ssum[c] * invM;
    float var = ssq[c] * invM - m * m;
    float sc  = gamma[c] * rsqrtf(var + BN_EPS);
    float sh  = beta[c] - sc * m;
    int curg = -1;
    float acc = 0.f;
    for (int r = r0 + half; r < rend; r += 2) {
        float xv = sc * bf2f(R[(size_t)r * DIM + c]) + sh;
        float w  = wsh[r - r0];
        float nv = (1.f - w) * xv;
        ushortT hv = f2bf(nv);
        ushortT lv = f2bf(nv - bf2f(hv));
        noisyP[(size_t)r * DIM + c] = ((unsigned)hv << 16) | lv;
        int g = batch[r];
        if (g != curg) {
            if (curg >= 0) atomicAdd(&slots[(size_t)curg * DIM + c], acc);
            curg = g;
            acc = 0.f;
        }
        acc += w * xv;
    }
    if (curg >= 0) atomicAdd(&slots[(size_t)curg * DIM + c], acc);
}

extern "C" void kernel_launch(void* const* d_in, const int* in_sizes, int n_in,
                              void* d_out, int out_size, void* d_ws, size_t ws_size,
                              hipStream_t stream)
{
    const float* x      = (const float*)d_in[0];
    const int*   src    = (const int*)d_in[1];
    const int*   dst    = (const int*)d_in[2];
    const int*   batch  = (const int*)d_in[3];
    const float* cw1    = (const float*)d_in[5];
    const float* cb1    = (const float*)d_in[6];
    const float* cw2    = (const float*)d_in[7];
    const float* cb2    = (const float*)d_in[8];
    const float* bng    = (const float*)d_in[9];
    const float* bnb    = (const float*)d_in[10];
    const float* sw_w   = (const float*)d_in[11];
    const float* sw_b   = (const float*)d_in[12];
    const float* nmu_w  = (const float*)d_in[13];
    const float* nmu_b  = (const float*)d_in[14];
    const float* nlv_w  = (const float*)d_in[15];
    const float* nlv_b  = (const float*)d_in[16];
    const float* gmu_w  = (const float*)d_in[17];
    const float* gmu_b  = (const float*)d_in[18];
    const float* glv_w  = (const float*)d_in[19];
    const float* glv_b  = (const float*)d_in[20];
    const float* hgam   = (const float*)d_in[21];
    const float* hbet   = (const float*)d_in[22];

    const int N = in_sizes[0] / DIM;
    const int E = in_sizes[1];
    const int G = (out_size / DIM - 2 * N) / 2;

    float* out0 = (float*)d_out;
    float* out1 = out0 + (size_t)N * DIM;
    float* out2 = out1 + (size_t)N * DIM;
    float* out3 = out2 + (size_t)G * DIM;

    // ---- workspace layout ----
    char* wp = (char*)d_ws;
    auto alloc = [&](size_t bytes) {
        char* p = wp;
        wp += (bytes + 255) & ~(size_t)255;
        return p;
    };
    ushortT*  xbf   = (ushortT*)alloc((size_t)N * DIM * 2);  // layer-0 input; later hB
    ushortT*  rA    = (ushortT*)alloc((size_t)N * DIM * 2);  // layer ping; final r
    ushortT*  rB    = (ushortT*)alloc((size_t)N * DIM * 2);  // layer pong; later hA
    unsigned* noisyP= (unsigned*)alloc((size_t)N * DIM * 4); // packed noisy; CSR temps overlay
    ushortT*  whi   = (ushortT*)alloc((size_t)10 * 16384 * 2);
    ushortT*  wlo   = (ushortT*)alloc((size_t)10 * 16384 * 2);
    float* slots    = (float*)alloc((size_t)G * DIM * 4);
    float* stats    = (float*)alloc((size_t)7 * 256 * 4);          // [sum|sq] x7
    float* sbuf     = (float*)alloc((size_t)5 * NSTRIPE * 256 * 4);// stripe bufs x5
    int* row_ptr    = (int*)alloc((size_t)(N + 2) * 4);
    int* eidx       = (int*)alloc((size_t)E * 4);
    // CSR temps overlay in noisyP (noisyP first written by weigh_split, long after CSR build)
    int* deg   = (int*)noisyP;
    int* iscan = deg + N;
    int* bsum  = iscan + N;
    int* cur   = bsum + 256;

    auto SS = [&](int i) { return stats + (size_t)i * 256; };
    auto SQ = [&](int i) { return stats + (size_t)i * 256 + 128; };
    auto SB = [&](int i) { return sbuf + (size_t)i * NSTRIPE * 256; };

    const int edge_blocks  = (E + 255) / 256;
    const int scan_blocks  = (N + 255) / 256;
    const int layer_blocks = (N + 31) / 32;
    const int heads_blocks = (N + 63) / 64;
    const int g16_blocks   = (N * 16 + 255) / 256;
    const int g32_blocks   = (N * 32 + 255) / 256;
    const float invN = 1.0f / (float)N;

    hipMemsetAsync(stats, 0, (size_t)7 * 256 * 4, stream);
    hipMemsetAsync(sbuf, 0, (size_t)5 * NSTRIPE * 256 * 4, stream);
    hipMemsetAsync(slots, 0, (size_t)G * DIM * 4, stream);
    hipMemsetAsync(deg, 0, (size_t)N * 4, stream);

    convw_kernel<<<(10 * 16384) / 256, 256, 0, stream>>>(
        cw1, cw2, nmu_w, nlv_w, gmu_w, glv_w, whi, wlo);
    convx_kernel<<<g16_blocks, 256, 0, stream>>>(x, xbf, N * 16);

    hist_kernel<<<edge_blocks, 256, 0, stream>>>(dst, deg, E);
    scan1_kernel<<<scan_blocks, 256, 0, stream>>>(deg, iscan, bsum, N);
    scan2_kernel<<<1, 256, 0, stream>>>(bsum, scan_blocks);
    scan3_kernel<<<scan_blocks, 256, 0, stream>>>(iscan, bsum, deg, row_ptr, cur, N);
    fill_kernel<<<edge_blocks, 256, 0, stream>>>(src, dst, cur, eidx, E);

    // layers: l0 xbf->rA, l1 rA->rB, l2 rB->rA (ping-pong)
    const ushortT* lin[3]  = {xbf, rA, rB};
    ushortT*       lout[3] = {rA, rB, rA};
    for (int l = 0; l < 3; ++l) {
        const float* sums_prev = (l == 0) ? nullptr : SS(l - 1);
        const float* sq_prev   = (l == 0) ? nullptr : SQ(l - 1);
        const float* g_prev    = (l == 0) ? nullptr : bng + (size_t)(l - 1) * DIM;
        const float* b_prev    = (l == 0) ? nullptr : bnb + (size_t)(l - 1) * DIM;
        layer_fused_kernel<<<layer_blocks, 256, 0, stream>>>(
            lin[l], row_ptr, eidx,
            sums_prev, sq_prev, g_prev, b_prev,
            whi + (size_t)l * 16384, wlo + (size_t)l * 16384, cb1 + (size_t)l * DIM,
            whi + (size_t)(3 + l) * 16384, wlo + (size_t)(3 + l) * 16384, cb2 + (size_t)l * DIM,
            lout[l], SB(l), N, invN);
        merge_stats_kernel<<<1, 256, 0, stream>>>(SB(l), SS(l));
    }
    ushortT* rfin = rA;   // layer-2 output
    ushortT* hA   = rB;   // free after layer 2
    ushortT* hB   = xbf;  // free after layer 0

    // fused weigh+split: BN(layer2) folded in
    weigh_split_kernel<<<(N + 127) / 128, 256, 0, stream>>>(
        rfin, batch, SS(2), SQ(2), bng + 2 * DIM, bnb + 2 * DIM,
        sw_w, sw_b, noisyP, slots, N, invN);

    // fused node heads -> bf16 pre-BN planes + striped stats
    heads_kernel<<<heads_blocks, 256, 0, stream>>>(
        noisyP,
        whi + (size_t)6 * 16384, wlo + (size_t)6 * 16384, nmu_b, hA, SB(3),
        whi + (size_t)7 * 16384, wlo + (size_t)7 * 16384, nlv_b, hB, SB(4), N);
    merge_stats_kernel<<<1, 256, 0, stream>>>(SB(3), SS(3));
    merge_stats_kernel<<<1, 256, 0, stream>>>(SB(4), SS(4));
    bn_apply_bf16_kernel<<<g32_blocks, 256, 0, stream>>>(
        hA, out0, SS(3), SQ(3), hgam + 0 * DIM, hbet + 0 * DIM, N);
    bn_apply_bf16_kernel<<<g32_blocks, 256, 0, stream>>>(
        hB, out1, SS(4), SQ(4), hgam + 1 * DIM, hbet + 1 * DIM, N);

    // graph heads (tiny)
    const int gemm_blocks_G = (G + 63) / 64;
    gemm_graph_kernel<<<gemm_blocks_G, 256, 0, stream>>>(
        slots, whi + (size_t)8 * 16384, wlo + (size_t)8 * 16384,
        gmu_b, out2, SS(5), SQ(5), G);
    gemm_graph_kernel<<<gemm_blocks_G, 256, 0, stream>>>(
        slots, whi + (size_t)9 * 16384, wlo + (size_t)9 * 16384,
        glv_b, out3, SS(6), SQ(6), G);
    bn_apply_kernel<<<(G * 32 + 255) / 256, 256, 0, stream>>>(
        out2, out2, SS(5), SQ(5), hgam + 2 * DIM, hbet + 2 * DIM, G);
    bn_apply_kernel<<<(G * 32 + 255) / 256, 256, 0, stream>>>(
        out3, out3, SS(6), SQ(6), hgam + 3 * DIM, hbet + 3 * DIM, G);
}